// Round 10
// baseline (1958.956 us; speedup 1.0000x reference)
//
#include <hip/hip_runtime.h>
#include <math.h>

#define NEGV (-1e9f)

// ws layout (float offsets):
//   OUT [B*N][512] : cols 0..127 K1, 128..255 V, 256..383 U=K2@Wout,
//                    384..511 Qfull = QR + emb@Wq[:,2:]^T  (QR folded in GEMM)
//   M   [128][512], QR [B][128] (dead after gemm -> reused as work counter),
//   QI  [B][128], SOL [B][200]
#define OUT_F   0l
#define M_F     52428800l
#define QR_F    (M_F + 65536l)
#define QI_F    (QR_F + 65536l)
#define SOL_F   (QI_F + 65536l)
#define WS_FLOATS (SOL_F + 102400l)   // ~211 MB (known OK)

typedef float f32x4 __attribute__((ext_vector_type(4)));

// ---------------- DPP cross-lane helpers ----------------
#define DPPF(x, ctrl, oldv) __int_as_float(__builtin_amdgcn_update_dpp( \
      __float_as_int(oldv), __float_as_int(x), ctrl, 0xF, 0xF, false))

__device__ __forceinline__ float wave_max(float x) {
  x = fmaxf(x, DPPF(x, 0x111, -INFINITY));
  x = fmaxf(x, DPPF(x, 0x112, -INFINITY));
  x = fmaxf(x, DPPF(x, 0x114, -INFINITY));
  x = fmaxf(x, DPPF(x, 0x118, -INFINITY));
  x = fmaxf(x, DPPF(x, 0x142, -INFINITY));
  x = fmaxf(x, DPPF(x, 0x143, -INFINITY));
  return __int_as_float(__builtin_amdgcn_readlane(__float_as_int(x), 63));
}
__device__ __forceinline__ float wave_sum(float x) {
  x = x + DPPF(x, 0x111, 0.f);
  x = x + DPPF(x, 0x112, 0.f);
  x = x + DPPF(x, 0x114, 0.f);
  x = x + DPPF(x, 0x118, 0.f);
  x = x + DPPF(x, 0x142, 0.f);
  x = x + DPPF(x, 0x143, 0.f);
  return __int_as_float(__builtin_amdgcn_readlane(__float_as_int(x), 63));
}

// ---------------- static precompute ----------------
__global__ __launch_bounds__(256)
void build_M(const float* __restrict__ Wk1, const float* __restrict__ Wv,
             const float* __restrict__ Wk2, const float* __restrict__ Wout,
             const float* __restrict__ Wq, float* __restrict__ Mbuf) {
  int g = blockIdx.x * 256 + threadIdx.x;
  int j = g >> 9, c = g & 511;
  float val;
  if (c < 128) {
    val = Wk1[c * 128 + j];
  } else if (c < 256) {
    val = Wv[(c - 128) * 128 + j];
  } else if (c < 384) {
    int d = c - 256;
    float s = 0.f;
    for (int e = 0; e < 128; ++e) s += Wk2[e * 128 + j] * Wout[e * 128 + d];
    val = s;
  } else {
    val = Wq[(c - 384) * 130 + 2 + j];
  }
  Mbuf[j * 512 + c] = val;
}

__global__ __launch_bounds__(256)
void build_Q(const float* __restrict__ rf, const float* __restrict__ Wq,
             const float* __restrict__ initn, float* __restrict__ QR,
             float* __restrict__ QI) {
  int g = blockIdx.x * 256 + threadIdx.x;   // 65536 = 512*128
  int b = g >> 7, d = g & 127;
  float qr = Wq[d * 130 + 0] * rf[b * 2 + 0] + Wq[d * 130 + 1] * rf[b * 2 + 1];
  float qi = qr;
  for (int j = 0; j < 128; ++j) qi += Wq[d * 130 + 2 + j] * initn[j];
  QR[g] = qr;
  QI[g] = qi;
}

__global__ __launch_bounds__(256)
void gemm_static(const float* __restrict__ emb, const float* __restrict__ Mbuf,
                 const float* __restrict__ bk1, const float* __restrict__ QR,
                 float* __restrict__ OUT) {
  int bid = blockIdx.x;                 // 1600 row-tiles * 8 col-tiles
  int rt = bid >> 3, ct = bid & 7;
  int r0 = rt * 64, c0 = ct * 64;
  int t = threadIdx.x, ty = t >> 4, tx = t & 15;
  int row0 = r0 + ty * 4;
  int col  = c0 + tx * 4;
  float acc[4][4] = {};
  const float* mp = Mbuf + col;
  for (int kb = 0; kb < 32; ++kb) {
    int k = kb * 4;
    float4 b0 = *(const float4*)(mp + (long)(k + 0) * 512);
    float4 b1 = *(const float4*)(mp + (long)(k + 1) * 512);
    float4 b2 = *(const float4*)(mp + (long)(k + 2) * 512);
    float4 b3 = *(const float4*)(mp + (long)(k + 3) * 512);
    float bm[4][4] = {{b0.x,b0.y,b0.z,b0.w},{b1.x,b1.y,b1.z,b1.w},
                      {b2.x,b2.y,b2.z,b2.w},{b3.x,b3.y,b3.z,b3.w}};
    #pragma unroll
    for (int rr = 0; rr < 4; ++rr) {
      float4 a4 = *(const float4*)(emb + (long)(row0 + rr) * 128 + k);
      float av[4] = {a4.x, a4.y, a4.z, a4.w};
      #pragma unroll
      for (int i = 0; i < 4; ++i)
        #pragma unroll
        for (int cc = 0; cc < 4; ++cc)
          acc[rr][cc] += av[i] * bm[i][cc];
    }
  }
  float badd[4] = {0.f, 0.f, 0.f, 0.f};
  if (c0 < 128) {
    #pragma unroll
    for (int cc = 0; cc < 4; ++cc) badd[cc] = bk1[col + cc];
  }
  #pragma unroll
  for (int rr = 0; rr < 4; ++rr) {
    int row = row0 + rr;
    float v[4];
    #pragma unroll
    for (int cc = 0; cc < 4; ++cc) v[cc] = acc[rr][cc] + badd[cc];
    if (col >= 384) {
      int bb = row / 200;
      #pragma unroll
      for (int cc = 0; cc < 4; ++cc) v[cc] += QR[bb * 128 + (col - 384) + cc];
    }
    float4 v4; v4.x = v[0]; v4.y = v[1]; v4.z = v[2]; v4.w = v[3];
    *(float4*)(OUT + (long)row * 512 + col) = v4;
  }
}

__global__ void init_ctr(int* __restrict__ c) { *c = 0; }

// ---------------- decode: vectorized-LDS, persistent work-stealing ----------------
// K1 in LDS [n][128] XOR-block-swizzled (b128 reads, banks spread by n);
// q replicated x4 with per-copy block rotation (conflict-free b128 broadcast);
// V 25 + U-low 16 (pre-rotated) in regs; U-high 16 in LDS (round-9 scheme).
__global__ __attribute__((amdgpu_flat_work_group_size(1024, 1024)))
void decode(const float* __restrict__ OUT, const float* __restrict__ QI,
            int* __restrict__ ctr, float* __restrict__ sol,
            float* __restrict__ out) {
  __shared__ __align__(16) float k1s[25600];   // [n][128] swizzled, 102.4 KB
  __shared__ float satL[1608];                 // scores/attn [h][201], 6.4 KB
  __shared__ __align__(16) float mhal[128];
  __shared__ float lg[200];
  __shared__ __align__(16) float qvR[512];     // q x4 copies, block-rotated
  __shared__ float ul[12800];                  // U-high [m][64] rot-5m, 51.2 KB
  __shared__ int   bci;
  __shared__ int   bsel;

  const int t = threadIdx.x;
  const int lane = t & 63, wave = t >> 6;
  const int o = t >> 3, q8 = t & 7;
  const int m4 = t >> 2, j4 = t & 3;

  for (;;) {
    if (t == 0) bsel = atomicAdd(ctr, 1);
    __syncthreads();
    const int b = bsel;
    if (b >= 512) break;
    const float* outb = OUT + (long)b * 200 * 512;

    // K1 -> LDS [n][128], block-XOR swizzle: phys_blk = (j>>2) ^ (n&7)
    for (int p = 0; p < 25; ++p) {
      int f = p * 1024 + t;
      int n = f >> 7, j = f & 127;
      int ph = ((j >> 2) ^ (n & 7));
      k1s[n * 128 + ph * 4 + (j & 3)] = outb[n * 512 + j];
    }
    // U-high -> LDS: ul[m][(c + 5m)&63] = U[m][(c>>4)*32 + 16 + (c&15)]
    for (int f = t; f < 12800; f += 1024) {
      int m = f >> 6, c = f & 63;
      ul[m * 64 + ((c + 5 * m) & 63)] =
          outb[m * 512 + 256 + (c >> 4) * 32 + 16 + (c & 15)];
    }
    // V: thread (o, q8) holds V[q8*25+i][o], i<25
    f32x4 vr0 = {}, vr1 = {}, vr2 = {}, vr3 = {}, vr4 = {}, vr5 = {};
    float v24;
    {
      const float* vp = outb + 128 + o;
      #pragma unroll
      for (int e = 0; e < 4; ++e) vr0[e] = vp[(q8 * 25 + e) * 512];
      #pragma unroll
      for (int e = 0; e < 4; ++e) vr1[e] = vp[(q8 * 25 + 4 + e) * 512];
      #pragma unroll
      for (int e = 0; e < 4; ++e) vr2[e] = vp[(q8 * 25 + 8 + e) * 512];
      #pragma unroll
      for (int e = 0; e < 4; ++e) vr3[e] = vp[(q8 * 25 + 12 + e) * 512];
      #pragma unroll
      for (int e = 0; e < 4; ++e) vr4[e] = vp[(q8 * 25 + 16 + e) * 512];
      #pragma unroll
      for (int e = 0; e < 4; ++e) vr5[e] = vp[(q8 * 25 + 20 + e) * 512];
      v24 = vp[(q8 * 25 + 24) * 512];
    }
    // U-low pre-rotated: urR[c] = U[m4][j4*32 + 4*((c+j4)&3) .. +3]
    f32x4 urR0 = {}, urR1 = {}, urR2 = {}, urR3 = {};
    if (t < 800) {
      const float* up = outb + m4 * 512 + 256 + j4 * 32;
      urR0 = *(const f32x4*)(up + 4 * ((0 + j4) & 3));
      urR1 = *(const f32x4*)(up + 4 * ((1 + j4) & 3));
      urR2 = *(const f32x4*)(up + 4 * ((2 + j4) & 3));
      urR3 = *(const f32x4*)(up + 4 * ((3 + j4) & 3));
    }
    // step-0 query -> qvR (4 rotated copies)
    if (t < 128) {
      float qval = QI[b * 128 + t];
      int Lb = t >> 2, e = t & 3;
      #pragma unroll
      for (int jc = 0; jc < 4; ++jc)
        qvR[jc * 128 + ((Lb + jc) & 31) * 4 + e] = qval;
    }

    bool cm = false;   // node m4 visited (threads < 800)
    bool live = true, picked0 = false;
    float llsum = 0.f, chose = 0.f;

    __syncthreads();

    for (int st = 0; st < 200; ++st) {
      // ---- A1: scores by owner-thread (n = m4), heads 2j4 & 2j4+1 ----
      if (t < 800) {
        const int sig = m4 & 7;
        const float* kb = k1s + m4 * 128;
        const float* qb = qvR + j4 * 128;
        float a0 = 0.f, a1 = 0.f;
        #pragma unroll
        for (int c = 0; c < 4; ++c) {           // head 2j4: d = 4c+e ascending
          int L = j4 * 8 + c;
          f32x4 kk = *(const f32x4*)(kb + (L ^ sig) * 4);
          f32x4 qq = *(const f32x4*)(qb + ((L + j4) & 31) * 4);
          a0 += qq[0] * kk[0]; a0 += qq[1] * kk[1];
          a0 += qq[2] * kk[2]; a0 += qq[3] * kk[3];
        }
        #pragma unroll
        for (int c = 0; c < 4; ++c) {           // head 2j4+1
          int L = j4 * 8 + 4 + c;
          f32x4 kk = *(const f32x4*)(kb + (L ^ sig) * 4);
          f32x4 qq = *(const f32x4*)(qb + ((L + j4) & 31) * 4);
          a1 += qq[0] * kk[0]; a1 += qq[1] * kk[1];
          a1 += qq[2] * kk[2]; a1 += qq[3] * kk[3];
        }
        satL[(2 * j4) * 201 + m4]     = cm ? NEGV : a0 * 0.25f;
        satL[(2 * j4 + 1) * 201 + m4] = cm ? NEGV : a1 * 0.25f;
      }
      __syncthreads();

      // ---- A2: softmax per head (wave h), identical to round-9 pass ----
      if (wave < 8) {
        float sv[4];
        float mx = -INFINITY;
        #pragma unroll
        for (int k = 0; k < 4; ++k) {
          int n = lane + 64 * k;
          float s = (n < 200) ? satL[wave * 201 + n] : -INFINITY;
          sv[k] = s;
          mx = fmaxf(mx, s);
        }
        float vmax = wave_max(mx);
        float ls = 0.f;
        #pragma unroll
        for (int k = 0; k < 4; ++k) { sv[k] = expf(sv[k] - vmax); ls += sv[k]; }
        ls = wave_sum(ls);
        #pragma unroll
        for (int k = 0; k < 4; ++k) {
          int n = lane + 64 * k;
          if (n < 200) satL[wave * 201 + n] = sv[k] / ls;
        }
      }
      __syncthreads();

      // ---- B: mha[o] = sum_n attn[h][n] * V[n][o] ----
      {
        const int h2 = t >> 7;
        const float* ap = satL + h2 * 201 + q8 * 25;
        float a = 0.f;
        #pragma unroll
        for (int e = 0; e < 4; ++e) a += ap[e] * vr0[e];
        #pragma unroll
        for (int e = 0; e < 4; ++e) a += ap[4 + e] * vr1[e];
        #pragma unroll
        for (int e = 0; e < 4; ++e) a += ap[8 + e] * vr2[e];
        #pragma unroll
        for (int e = 0; e < 4; ++e) a += ap[12 + e] * vr3[e];
        #pragma unroll
        for (int e = 0; e < 4; ++e) a += ap[16 + e] * vr4[e];
        #pragma unroll
        for (int e = 0; e < 4; ++e) a += ap[20 + e] * vr5[e];
        a += ap[24] * v24;
        a += DPPF(a, 0xB1, 0.f);
        a += DPPF(a, 0x4E, 0.f);
        a += DPPF(a, 0x141, 0.f);
        if (q8 == 0) mhal[o] = a;
      }
      __syncthreads();

      // ---- C: logits[m] = 10*tanh((mha . U[m]) / sqrt(128)) ----
      if (t < 800) {
        float a = 0.f;
        // low half d 0..15: rotated b128 mhal + pre-rotated U-low regs
        {
          f32x4 ml;
          ml = *(const f32x4*)&mhal[j4 * 32 + ((0 + j4) & 3) * 4];
          a += ml[0]*urR0[0]; a += ml[1]*urR0[1]; a += ml[2]*urR0[2]; a += ml[3]*urR0[3];
          ml = *(const f32x4*)&mhal[j4 * 32 + ((1 + j4) & 3) * 4];
          a += ml[0]*urR1[0]; a += ml[1]*urR1[1]; a += ml[2]*urR1[2]; a += ml[3]*urR1[3];
          ml = *(const f32x4*)&mhal[j4 * 32 + ((2 + j4) & 3) * 4];
          a += ml[0]*urR2[0]; a += ml[1]*urR2[1]; a += ml[2]*urR2[2]; a += ml[3]*urR2[3];
          ml = *(const f32x4*)&mhal[j4 * 32 + ((3 + j4) & 3) * 4];
          a += ml[0]*urR3[0]; a += ml[1]*urR3[1]; a += ml[2]*urR3[2]; a += ml[3]*urR3[3];
        }
        // high half d 16..31: rotated b128 mhal + ul (round-9 rot-5m scheme)
        const int ubase = m4 * 64;
        const int rot = 5 * m4;
        #pragma unroll
        for (int c = 0; c < 4; ++c) {
          int ci = (c + j4) & 3;
          f32x4 mh = *(const f32x4*)&mhal[j4 * 32 + 16 + ci * 4];
          #pragma unroll
          for (int e = 0; e < 4; ++e)
            a += mh[e] * ul[ubase + ((j4 * 16 + ci * 4 + e + rot) & 63)];
        }
        a += DPPF(a, 0xB1, 0.f);
        a += DPPF(a, 0x4E, 0.f);
        if (j4 == 0) {
          float l = 10.f * tanhf(a / 11.313708498984761f);
          lg[m4] = cm ? NEGV : l;
        }
      }
      __syncthreads();

      // ---- D: argmax -> issue q-row load -> lse (overlaps load) ----
      if (wave < 8) {
        float lv[4];
        float mx = -INFINITY;
        #pragma unroll
        for (int k = 0; k < 4; ++k) {
          int n = lane + 64 * k;
          lv[k] = (n < 200) ? lg[n] : -INFINITY;
          mx = fmaxf(mx, lv[k]);
        }
        float vmax = wave_max(mx);
        int bidx = -1;
        #pragma unroll
        for (int k = 0; k < 4; ++k) {
          unsigned long long bm =
              __ballot((lane + 64 * k < 200) && (lv[k] == vmax));
          if (bidx < 0 && bm != 0ull) bidx = k * 64 + (int)__builtin_ctzll(bm);
        }
        int nxt = live ? bidx : 0;
        if (t < 128) {
          float qval = outb[(long)nxt * 512 + 384 + t];
          int Lb = t >> 2, e = t & 3;
          #pragma unroll
          for (int jc = 0; jc < 4; ++jc)
            qvR[jc * 128 + ((Lb + jc) & 31) * 4 + e] = qval;
        }
        float e = 0.f;
        #pragma unroll
        for (int k = 0; k < 4; ++k) e += expf(lv[k] - vmax);
        float se_ = wave_sum(e);
        float lse = logf(se_);
        if (t == 0) {
          chose = live ? (-lse) : ((lv[0] - vmax) - lse);
          out[2048 + (long)b * 200 + st] = (float)nxt;
          bci = nxt;
        }
      }
      __syncthreads();

      int nxt = bci;
      if (!live) {
        if (t == 0) llsum += chose * (float)(200 - st);
        for (int s2 = st + 1 + t; s2 < 200; s2 += 1024)
          out[2048 + (long)b * 200 + s2] = 0.f;
        break;
      }
      if (t == 0) llsum += chose;
      if (t < 800 && nxt == m4) cm = true;
      if (nxt == 0) { live = false; picked0 = true; }
    }

    if (t == 0) out[1536 + b] = picked0 ? llsum : 0.f;
    if (t < 800 && j4 == 0) {
      float s = (m4 == 0) ? 1.f : ((picked0 && cm) ? 1.f : 0.f);
      sol[(long)b * 200 + m4] = s;
    }
    __syncthreads();   // protect LDS reuse before next grab
  }
}

// ---------------- cost ----------------
__global__ __launch_bounds__(256)
void cost_kernel(const float* __restrict__ x, const float* __restrict__ rf,
                 const float* __restrict__ sol, float* __restrict__ out) {
  __shared__ float solL[256];
  __shared__ float red[8];
  const int b = blockIdx.x, t = threadIdx.x;
  solL[t] = (t < 200) ? sol[b * 200 + t] : 0.f;
  __syncthreads();
  const float* x0 = x + (long)b * 40000;
  const float* x1 = x + 20480000l + (long)b * 40000;
  float a1 = 0.f, a2 = 0.f;
  if (t < 200) {
    for (int i = 0; i < 200; ++i) {
      if (solL[i] != 0.f) {
        a1 += x0[i * 200 + t];
        a2 += x1[i * 200 + t];
      }
    }
    float w = solL[t];
    a1 *= w; a2 *= w;
  }
  #pragma unroll
  for (int off = 32; off > 0; off >>= 1) {
    a1 += __shfl_xor(a1, off);
    a2 += __shfl_xor(a2, off);
  }
  if ((t & 63) == 0) { red[(t >> 6) * 2] = a1; red[(t >> 6) * 2 + 1] = a2; }
  __syncthreads();
  if (t == 0) {
    float f1 = red[0] + red[2] + red[4] + red[6];
    float f2 = red[1] + red[3] + red[5] + red[7];
    out[b]        = -(f1 * rf[0] + f2 * rf[1]);
    out[512 + b]  = f1;
    out[1024 + b] = f2;
  }
}

extern "C" void kernel_launch(void* const* d_in, const int* in_sizes, int n_in,
                              void* d_out, int out_size, void* d_ws, size_t ws_size,
                              hipStream_t stream) {
  const float* x     = (const float*)d_in[0];
  const float* rf    = (const float*)d_in[1];
  const float* emb   = (const float*)d_in[2];
  const float* Wk1   = (const float*)d_in[4];
  const float* bk1   = (const float*)d_in[5];
  const float* Wv    = (const float*)d_in[6];
  const float* Wk2   = (const float*)d_in[7];
  const float* Wout  = (const float*)d_in[8];
  const float* Wq    = (const float*)d_in[9];
  const float* initn = (const float*)d_in[10];
  float* out = (float*)d_out;
  float* ws  = (float*)d_ws;

  if (ws_size < (size_t)WS_FLOATS * 4) return;

  float* OUTb = ws + OUT_F;
  float* Mb   = ws + M_F;
  float* QRb  = ws + QR_F;   // dead after gemm; first 4 bytes reused as counter
  float* QIb  = ws + QI_F;
  float* solb = ws + SOL_F;

  build_M<<<256, 256, 0, stream>>>(Wk1, Wv, Wk2, Wout, Wq, Mb);
  build_Q<<<256, 256, 0, stream>>>(rf, Wq, initn, QRb, QIb);
  gemm_static<<<12800, 256, 0, stream>>>(emb, Mb, bk1, QRb, OUTb);
  init_ctr<<<1, 1, 0, stream>>>((int*)QRb);
  decode<<<256, 1024, 0, stream>>>(OUTb, QIb, (int*)QRb, solb, out);
  cost_kernel<<<512, 256, 0, stream>>>(x, rf, solb, out);
}

// Round 11
// 1771.042 us; speedup vs baseline: 1.1061x; 1.1061x over previous
//
#include <hip/hip_runtime.h>
#include <math.h>

#define NEGV (-1e9f)

// ws layout (float offsets):
//   OUT [B*N][512] : cols 0..127 K1, 128..255 V, 256..383 U=K2@Wout,
//                    384..511 Qfull = QR + emb@Wq[:,2:]^T  (QR folded in GEMM)
//   M   [128][512], QR [B][128] (dead after gemm -> reused as work counter),
//   QI  [B][128], SOL [B][200]
#define OUT_F   0l
#define M_F     52428800l
#define QR_F    (M_F + 65536l)
#define QI_F    (QR_F + 65536l)
#define SOL_F   (QI_F + 65536l)
#define WS_FLOATS (SOL_F + 102400l)   // ~211 MB (known OK)

typedef float f32x4 __attribute__((ext_vector_type(4)));

// ---------------- DPP cross-lane helpers ----------------
#define DPPF(x, ctrl, oldv) __int_as_float(__builtin_amdgcn_update_dpp( \
      __float_as_int(oldv), __float_as_int(x), ctrl, 0xF, 0xF, false))

__device__ __forceinline__ float wave_max(float x) {
  x = fmaxf(x, DPPF(x, 0x111, -INFINITY));
  x = fmaxf(x, DPPF(x, 0x112, -INFINITY));
  x = fmaxf(x, DPPF(x, 0x114, -INFINITY));
  x = fmaxf(x, DPPF(x, 0x118, -INFINITY));
  x = fmaxf(x, DPPF(x, 0x142, -INFINITY));
  x = fmaxf(x, DPPF(x, 0x143, -INFINITY));
  return __int_as_float(__builtin_amdgcn_readlane(__float_as_int(x), 63));
}
__device__ __forceinline__ float wave_sum(float x) {
  x = x + DPPF(x, 0x111, 0.f);
  x = x + DPPF(x, 0x112, 0.f);
  x = x + DPPF(x, 0x114, 0.f);
  x = x + DPPF(x, 0x118, 0.f);
  x = x + DPPF(x, 0x142, 0.f);
  x = x + DPPF(x, 0x143, 0.f);
  return __int_as_float(__builtin_amdgcn_readlane(__float_as_int(x), 63));
}

// ---------------- static precompute ----------------
__global__ __launch_bounds__(256)
void build_M(const float* __restrict__ Wk1, const float* __restrict__ Wv,
             const float* __restrict__ Wk2, const float* __restrict__ Wout,
             const float* __restrict__ Wq, float* __restrict__ Mbuf) {
  int g = blockIdx.x * 256 + threadIdx.x;
  int j = g >> 9, c = g & 511;
  float val;
  if (c < 128) {
    val = Wk1[c * 128 + j];
  } else if (c < 256) {
    val = Wv[(c - 128) * 128 + j];
  } else if (c < 384) {
    int d = c - 256;
    float s = 0.f;
    for (int e = 0; e < 128; ++e) s += Wk2[e * 128 + j] * Wout[e * 128 + d];
    val = s;
  } else {
    val = Wq[(c - 384) * 130 + 2 + j];
  }
  Mbuf[j * 512 + c] = val;
}

__global__ __launch_bounds__(256)
void build_Q(const float* __restrict__ rf, const float* __restrict__ Wq,
             const float* __restrict__ initn, float* __restrict__ QR,
             float* __restrict__ QI) {
  int g = blockIdx.x * 256 + threadIdx.x;   // 65536 = 512*128
  int b = g >> 7, d = g & 127;
  float qr = Wq[d * 130 + 0] * rf[b * 2 + 0] + Wq[d * 130 + 1] * rf[b * 2 + 1];
  float qi = qr;
  for (int j = 0; j < 128; ++j) qi += Wq[d * 130 + 2 + j] * initn[j];
  QR[g] = qr;
  QI[g] = qi;
}

__global__ __launch_bounds__(256)
void gemm_static(const float* __restrict__ emb, const float* __restrict__ Mbuf,
                 const float* __restrict__ bk1, const float* __restrict__ QR,
                 float* __restrict__ OUT) {
  int bid = blockIdx.x;                 // 1600 row-tiles * 8 col-tiles
  int rt = bid >> 3, ct = bid & 7;
  int r0 = rt * 64, c0 = ct * 64;
  int t = threadIdx.x, ty = t >> 4, tx = t & 15;
  int row0 = r0 + ty * 4;
  int col  = c0 + tx * 4;
  float acc[4][4] = {};
  const float* mp = Mbuf + col;
  for (int kb = 0; kb < 32; ++kb) {
    int k = kb * 4;
    float4 b0 = *(const float4*)(mp + (long)(k + 0) * 512);
    float4 b1 = *(const float4*)(mp + (long)(k + 1) * 512);
    float4 b2 = *(const float4*)(mp + (long)(k + 2) * 512);
    float4 b3 = *(const float4*)(mp + (long)(k + 3) * 512);
    float bm[4][4] = {{b0.x,b0.y,b0.z,b0.w},{b1.x,b1.y,b1.z,b1.w},
                      {b2.x,b2.y,b2.z,b2.w},{b3.x,b3.y,b3.z,b3.w}};
    #pragma unroll
    for (int rr = 0; rr < 4; ++rr) {
      float4 a4 = *(const float4*)(emb + (long)(row0 + rr) * 128 + k);
      float av[4] = {a4.x, a4.y, a4.z, a4.w};
      #pragma unroll
      for (int i = 0; i < 4; ++i)
        #pragma unroll
        for (int cc = 0; cc < 4; ++cc)
          acc[rr][cc] += av[i] * bm[i][cc];
    }
  }
  float badd[4] = {0.f, 0.f, 0.f, 0.f};
  if (c0 < 128) {
    #pragma unroll
    for (int cc = 0; cc < 4; ++cc) badd[cc] = bk1[col + cc];
  }
  #pragma unroll
  for (int rr = 0; rr < 4; ++rr) {
    int row = row0 + rr;
    float v[4];
    #pragma unroll
    for (int cc = 0; cc < 4; ++cc) v[cc] = acc[rr][cc] + badd[cc];
    if (col >= 384) {
      int bb = row / 200;
      #pragma unroll
      for (int cc = 0; cc < 4; ++cc) v[cc] += QR[bb * 128 + (col - 384) + cc];
    }
    float4 v4; v4.x = v[0]; v4.y = v[1]; v4.z = v[2]; v4.w = v[3];
    *(float4*)(OUT + (long)row * 512 + col) = v4;
  }
}

__global__ void init_ctr(int* __restrict__ c) { *c = 0; }

// ---------------- decode: persistent work-stealing ----------------
// Round-9 structure; B reads `at` via quad-aligned b128 (24/28 split, distinct
// banks), C reads mhal via rotated b128 (conflict-free) + pre-rotated U-low.
__global__ __attribute__((amdgpu_flat_work_group_size(1024, 1024)))
void decode(const float* __restrict__ OUT, const float* __restrict__ QI,
            int* __restrict__ ctr, float* __restrict__ sol,
            float* __restrict__ out) {
  __shared__ float k1t[25600];                 // [d][n]  102.4 KB
  __shared__ __align__(16) float at[1600];     // attn [h][200]  6.4 KB
  __shared__ __align__(16) float mhal[128];
  __shared__ float lg[200];
  __shared__ float qv[128];
  __shared__ float ul[12800];                  // U-high [m][64] rot-5m, 51.2 KB
  __shared__ int   bci;
  __shared__ int   bsel;

  const int t = threadIdx.x;
  const int lane = t & 63, wave = t >> 6;
  const int o = t >> 3, q8 = t & 7;
  const int m4 = t >> 2, j4 = t & 3;
  // B-phase quad-aligned n-split: starts {0,24,48,72,100,124,148,172}
  const int stq = (q8 * 25) & ~3;
  const int cq  = ((((q8 + 1) * 25) & ~3) - stq) >> 2;   // 6 or 7 quads

  for (;;) {
    if (t == 0) bsel = atomicAdd(ctr, 1);
    __syncthreads();
    const int b = bsel;
    if (b >= 512) break;
    const float* outb = OUT + (long)b * 200 * 512;

    // K1 -> LDS (transpose to [d][n])
    for (int k = 0; k < 25; ++k) {
      int f = k * 1024 + t;
      int n = f >> 7, d = f & 127;
      k1t[d * 200 + n] = outb[n * 512 + d];
    }
    // U-high -> LDS: ul[m][(c + 5m)&63] = U[m][(c>>4)*32 + 16 + (c&15)]
    for (int f = t; f < 12800; f += 1024) {
      int m = f >> 6, c = f & 63;
      ul[m * 64 + ((c + 5 * m) & 63)] =
          outb[m * 512 + 256 + (c >> 4) * 32 + 16 + (c & 15)];
    }
    // V: thread (o, q8) holds V[stq + c*4 + e][o] as 7 guarded vectors
    f32x4 vA = {}, vB = {}, vC = {}, vD = {}, vE = {}, vF = {}, vG = {};
    {
      const float* vp = outb + 128 + o;
      #pragma unroll
      for (int e = 0; e < 4; ++e) vA[e] = vp[(stq + 0 + e) * 512];
      #pragma unroll
      for (int e = 0; e < 4; ++e) vB[e] = vp[(stq + 4 + e) * 512];
      #pragma unroll
      for (int e = 0; e < 4; ++e) vC[e] = vp[(stq + 8 + e) * 512];
      #pragma unroll
      for (int e = 0; e < 4; ++e) vD[e] = vp[(stq + 12 + e) * 512];
      #pragma unroll
      for (int e = 0; e < 4; ++e) vE[e] = vp[(stq + 16 + e) * 512];
      #pragma unroll
      for (int e = 0; e < 4; ++e) vF[e] = vp[(stq + 20 + e) * 512];
      if (cq == 7) {
        #pragma unroll
        for (int e = 0; e < 4; ++e) vG[e] = vp[(stq + 24 + e) * 512];
      }
    }
    // U-low pre-rotated: urR[c] = U[m4][j4*32 + 4*((c+j4)&3) .. +3]
    f32x4 urR0 = {}, urR1 = {}, urR2 = {}, urR3 = {};
    if (t < 800) {
      const float* up = outb + m4 * 512 + 256 + j4 * 32;
      urR0 = *(const f32x4*)(up + 4 * ((0 + j4) & 3));
      urR1 = *(const f32x4*)(up + 4 * ((1 + j4) & 3));
      urR2 = *(const f32x4*)(up + 4 * ((2 + j4) & 3));
      urR3 = *(const f32x4*)(up + 4 * ((3 + j4) & 3));
    }
    if (t < 128) qv[t] = QI[b * 128 + t];   // step-0 query

    int mk = 0;        // per-lane mask bits (node = lane + 64k), waves 0-7
    bool cm = false;   // node m4 masked, threads < 800
    bool live = true, picked0 = false;
    float llsum = 0.f, chose = 0.f;

    __syncthreads();

    for (int st = 0; st < 200; ++st) {
      // ---- A: scores + softmax (wave h = head h); q in 2x8 chunks ----
      if (wave < 8) {
        float acc[4] = {};
        #pragma unroll
        for (int half = 0; half < 2; ++half) {
          float q8v[8];
          #pragma unroll
          for (int d = 0; d < 8; ++d) q8v[d] = qv[wave * 16 + half * 8 + d];
          #pragma unroll
          for (int k = 0; k < 4; ++k) {
            int n = lane + 64 * k;
            if (n < 200) {
              float a = 0.f;
              #pragma unroll
              for (int d = 0; d < 8; ++d)
                a += q8v[d] * k1t[(wave * 16 + half * 8 + d) * 200 + n];
              acc[k] += a;
            }
          }
        }
        float sv[4];
        float mx = -INFINITY;
        #pragma unroll
        for (int k = 0; k < 4; ++k) {
          int n = lane + 64 * k;
          float s = -INFINITY;
          if (n < 200) {
            s = acc[k] * 0.25f;
            if (mk & (1 << k)) s = NEGV;
          }
          sv[k] = s;
          mx = fmaxf(mx, s);
        }
        float vmax = wave_max(mx);
        float ls = 0.f;
        #pragma unroll
        for (int k = 0; k < 4; ++k) { sv[k] = expf(sv[k] - vmax); ls += sv[k]; }
        ls = wave_sum(ls);
        #pragma unroll
        for (int k = 0; k < 4; ++k) {
          int n = lane + 64 * k;
          if (n < 200) at[wave * 200 + n] = sv[k] / ls;
        }
      }
      __syncthreads();

      // ---- B: mha[o] = sum_n attn[h][n] * V[n][o]  (b128 at-reads) ----
      {
        const int h2 = t >> 7;
        const float* ap = at + h2 * 200 + stq;
        float a = 0.f;
        f32x4 av;
        av = *(const f32x4*)(ap + 0);
        a += av[0]*vA[0]; a += av[1]*vA[1]; a += av[2]*vA[2]; a += av[3]*vA[3];
        av = *(const f32x4*)(ap + 4);
        a += av[0]*vB[0]; a += av[1]*vB[1]; a += av[2]*vB[2]; a += av[3]*vB[3];
        av = *(const f32x4*)(ap + 8);
        a += av[0]*vC[0]; a += av[1]*vC[1]; a += av[2]*vC[2]; a += av[3]*vC[3];
        av = *(const f32x4*)(ap + 12);
        a += av[0]*vD[0]; a += av[1]*vD[1]; a += av[2]*vD[2]; a += av[3]*vD[3];
        av = *(const f32x4*)(ap + 16);
        a += av[0]*vE[0]; a += av[1]*vE[1]; a += av[2]*vE[2]; a += av[3]*vE[3];
        av = *(const f32x4*)(ap + 20);
        a += av[0]*vF[0]; a += av[1]*vF[1]; a += av[2]*vF[2]; a += av[3]*vF[3];
        if (cq == 7) {
          av = *(const f32x4*)(ap + 24);
          a += av[0]*vG[0]; a += av[1]*vG[1]; a += av[2]*vG[2]; a += av[3]*vG[3];
        }
        a += DPPF(a, 0xB1, 0.f);
        a += DPPF(a, 0x4E, 0.f);
        a += DPPF(a, 0x141, 0.f);
        if (q8 == 0) mhal[o] = a;
      }
      __syncthreads();

      // ---- C: logits[m] = 10*tanh((mha . U[m]) / sqrt(128)) ----
      if (t < 800) {
        float a = 0.f;
        // low half d 0..15: rotated b128 mhal + pre-rotated U-low regs
        {
          f32x4 ml;
          ml = *(const f32x4*)&mhal[j4 * 32 + ((0 + j4) & 3) * 4];
          a += ml[0]*urR0[0]; a += ml[1]*urR0[1]; a += ml[2]*urR0[2]; a += ml[3]*urR0[3];
          ml = *(const f32x4*)&mhal[j4 * 32 + ((1 + j4) & 3) * 4];
          a += ml[0]*urR1[0]; a += ml[1]*urR1[1]; a += ml[2]*urR1[2]; a += ml[3]*urR1[3];
          ml = *(const f32x4*)&mhal[j4 * 32 + ((2 + j4) & 3) * 4];
          a += ml[0]*urR2[0]; a += ml[1]*urR2[1]; a += ml[2]*urR2[2]; a += ml[3]*urR2[3];
          ml = *(const f32x4*)&mhal[j4 * 32 + ((3 + j4) & 3) * 4];
          a += ml[0]*urR3[0]; a += ml[1]*urR3[1]; a += ml[2]*urR3[2]; a += ml[3]*urR3[3];
        }
        // high half d 16..31: rotated b128 mhal + ul (rot-5m scheme)
        const int ubase = m4 * 64;
        const int rot = 5 * m4;
        #pragma unroll
        for (int c = 0; c < 4; ++c) {
          int ci = (c + j4) & 3;
          f32x4 mh = *(const f32x4*)&mhal[j4 * 32 + 16 + ci * 4];
          #pragma unroll
          for (int e = 0; e < 4; ++e)
            a += mh[e] * ul[ubase + ((j4 * 16 + ci * 4 + e + rot) & 63)];
        }
        a += DPPF(a, 0xB1, 0.f);
        a += DPPF(a, 0x4E, 0.f);
        if (j4 == 0) {
          float l = 10.f * tanhf(a / 11.313708498984761f);
          lg[m4] = cm ? NEGV : l;
        }
      }
      __syncthreads();

      // ---- D: argmax -> issue q-row load -> lse (overlaps load) ----
      if (wave < 8) {
        float lv[4];
        float mx = -INFINITY;
        #pragma unroll
        for (int k = 0; k < 4; ++k) {
          int n = lane + 64 * k;
          lv[k] = (n < 200) ? lg[n] : -INFINITY;
          mx = fmaxf(mx, lv[k]);
        }
        float vmax = wave_max(mx);
        int bidx = -1;
        #pragma unroll
        for (int k = 0; k < 4; ++k) {
          unsigned long long bm =
              __ballot((lane + 64 * k < 200) && (lv[k] == vmax));
          if (bidx < 0 && bm != 0ull) bidx = k * 64 + (int)__builtin_ctzll(bm);
        }
        int nxt = live ? bidx : 0;
        if (t < 128) qv[t] = outb[(long)nxt * 512 + 384 + t];
        float e = 0.f;
        #pragma unroll
        for (int k = 0; k < 4; ++k) e += expf(lv[k] - vmax);
        float se_ = wave_sum(e);
        float lse = logf(se_);
        if (t == 0) {
          chose = live ? (-lse) : ((lv[0] - vmax) - lse);
          out[2048 + (long)b * 200 + st] = (float)nxt;
          bci = nxt;
        }
      }
      __syncthreads();

      int nxt = bci;
      if (!live) {
        if (t == 0) llsum += chose * (float)(200 - st);
        for (int s2 = st + 1 + t; s2 < 200; s2 += 1024)
          out[2048 + (long)b * 200 + s2] = 0.f;
        break;
      }
      if (t == 0) llsum += chose;
      if (wave < 8 && (nxt & 63) == lane) mk |= 1 << (nxt >> 6);
      if (t < 800 && nxt == m4) cm = true;
      if (nxt == 0) { live = false; picked0 = true; }
    }

    if (t == 0) out[1536 + b] = picked0 ? llsum : 0.f;
    if (t < 800 && j4 == 0) {
      float s = (m4 == 0) ? 1.f : ((picked0 && cm) ? 1.f : 0.f);
      sol[(long)b * 200 + m4] = s;
    }
    __syncthreads();   // protect LDS reuse before next grab
  }
}

// ---------------- cost ----------------
__global__ __launch_bounds__(256)
void cost_kernel(const float* __restrict__ x, const float* __restrict__ rf,
                 const float* __restrict__ sol, float* __restrict__ out) {
  __shared__ float solL[256];
  __shared__ float red[8];
  const int b = blockIdx.x, t = threadIdx.x;
  solL[t] = (t < 200) ? sol[b * 200 + t] : 0.f;
  __syncthreads();
  const float* x0 = x + (long)b * 40000;
  const float* x1 = x + 20480000l + (long)b * 40000;
  float a1 = 0.f, a2 = 0.f;
  if (t < 200) {
    for (int i = 0; i < 200; ++i) {
      if (solL[i] != 0.f) {
        a1 += x0[i * 200 + t];
        a2 += x1[i * 200 + t];
      }
    }
    float w = solL[t];
    a1 *= w; a2 *= w;
  }
  #pragma unroll
  for (int off = 32; off > 0; off >>= 1) {
    a1 += __shfl_xor(a1, off);
    a2 += __shfl_xor(a2, off);
  }
  if ((t & 63) == 0) { red[(t >> 6) * 2] = a1; red[(t >> 6) * 2 + 1] = a2; }
  __syncthreads();
  if (t == 0) {
    float f1 = red[0] + red[2] + red[4] + red[6];
    float f2 = red[1] + red[3] + red[5] + red[7];
    out[b]        = -(f1 * rf[0] + f2 * rf[1]);
    out[512 + b]  = f1;
    out[1024 + b] = f2;
  }
}

extern "C" void kernel_launch(void* const* d_in, const int* in_sizes, int n_in,
                              void* d_out, int out_size, void* d_ws, size_t ws_size,
                              hipStream_t stream) {
  const float* x     = (const float*)d_in[0];
  const float* rf    = (const float*)d_in[1];
  const float* emb   = (const float*)d_in[2];
  const float* Wk1   = (const float*)d_in[4];
  const float* bk1   = (const float*)d_in[5];
  const float* Wv    = (const float*)d_in[6];
  const float* Wk2   = (const float*)d_in[7];
  const float* Wout  = (const float*)d_in[8];
  const float* Wq    = (const float*)d_in[9];
  const float* initn = (const float*)d_in[10];
  float* out = (float*)d_out;
  float* ws  = (float*)d_ws;

  if (ws_size < (size_t)WS_FLOATS * 4) return;

  float* OUTb = ws + OUT_F;
  float* Mb   = ws + M_F;
  float* QRb  = ws + QR_F;   // dead after gemm; first 4 bytes reused as counter
  float* QIb  = ws + QI_F;
  float* solb = ws + SOL_F;

  build_M<<<256, 256, 0, stream>>>(Wk1, Wv, Wk2, Wout, Wq, Mb);
  build_Q<<<256, 256, 0, stream>>>(rf, Wq, initn, QRb, QIb);
  gemm_static<<<12800, 256, 0, stream>>>(emb, Mb, bk1, QRb, OUTb);
  init_ctr<<<1, 1, 0, stream>>>((int*)QRb);
  decode<<<256, 1024, 0, stream>>>(OUTb, QIb, (int*)QRb, solb, out);
  cost_kernel<<<512, 256, 0, stream>>>(x, rf, solb, out);
}

// Round 12
// 1623.939 us; speedup vs baseline: 1.2063x; 1.0906x over previous
//
#include <hip/hip_runtime.h>
#include <math.h>

#define NEGV (-1e9f)

// ws layout (float offsets):
//   OUT [B*N][512] : cols 0..127 K1, 128..255 V, 256..383 U=K2@Wout,
//                    384..511 Qfull = QR + emb@Wq[:,2:]^T  (QR folded in GEMM)
//   M   [128][512], QR [B][128] (dead after gemm -> reused as work counter),
//   QI  [B][128], SOL [B][200]
#define OUT_F   0l
#define M_F     52428800l
#define QR_F    (M_F + 65536l)
#define QI_F    (QR_F + 65536l)
#define SOL_F   (QI_F + 65536l)
#define WS_FLOATS (SOL_F + 102400l)   // ~211 MB (known OK)

typedef float f32x4 __attribute__((ext_vector_type(4)));

// ---------------- DPP cross-lane helpers ----------------
#define DPPF(x, ctrl, oldv) __int_as_float(__builtin_amdgcn_update_dpp( \
      __float_as_int(oldv), __float_as_int(x), ctrl, 0xF, 0xF, false))

__device__ __forceinline__ float wave_max(float x) {
  x = fmaxf(x, DPPF(x, 0x111, -INFINITY));
  x = fmaxf(x, DPPF(x, 0x112, -INFINITY));
  x = fmaxf(x, DPPF(x, 0x114, -INFINITY));
  x = fmaxf(x, DPPF(x, 0x118, -INFINITY));
  x = fmaxf(x, DPPF(x, 0x142, -INFINITY));
  x = fmaxf(x, DPPF(x, 0x143, -INFINITY));
  return __int_as_float(__builtin_amdgcn_readlane(__float_as_int(x), 63));
}
__device__ __forceinline__ float wave_sum(float x) {
  x = x + DPPF(x, 0x111, 0.f);
  x = x + DPPF(x, 0x112, 0.f);
  x = x + DPPF(x, 0x114, 0.f);
  x = x + DPPF(x, 0x118, 0.f);
  x = x + DPPF(x, 0x142, 0.f);
  x = x + DPPF(x, 0x143, 0.f);
  return __int_as_float(__builtin_amdgcn_readlane(__float_as_int(x), 63));
}

// ---------------- static precompute ----------------
__global__ __launch_bounds__(256)
void build_M(const float* __restrict__ Wk1, const float* __restrict__ Wv,
             const float* __restrict__ Wk2, const float* __restrict__ Wout,
             const float* __restrict__ Wq, float* __restrict__ Mbuf) {
  int g = blockIdx.x * 256 + threadIdx.x;
  int j = g >> 9, c = g & 511;
  float val;
  if (c < 128) {
    val = Wk1[c * 128 + j];
  } else if (c < 256) {
    val = Wv[(c - 128) * 128 + j];
  } else if (c < 384) {
    int d = c - 256;
    float s = 0.f;
    for (int e = 0; e < 128; ++e) s += Wk2[e * 128 + j] * Wout[e * 128 + d];
    val = s;
  } else {
    val = Wq[(c - 384) * 130 + 2 + j];
  }
  Mbuf[j * 512 + c] = val;
}

__global__ __launch_bounds__(256)
void build_Q(const float* __restrict__ rf, const float* __restrict__ Wq,
             const float* __restrict__ initn, float* __restrict__ QR,
             float* __restrict__ QI) {
  int g = blockIdx.x * 256 + threadIdx.x;   // 65536 = 512*128
  int b = g >> 7, d = g & 127;
  float qr = Wq[d * 130 + 0] * rf[b * 2 + 0] + Wq[d * 130 + 1] * rf[b * 2 + 1];
  float qi = qr;
  for (int j = 0; j < 128; ++j) qi += Wq[d * 130 + 2 + j] * initn[j];
  QR[g] = qr;
  QI[g] = qi;
}

__global__ __launch_bounds__(256)
void gemm_static(const float* __restrict__ emb, const float* __restrict__ Mbuf,
                 const float* __restrict__ bk1, const float* __restrict__ QR,
                 float* __restrict__ OUT) {
  int bid = blockIdx.x;                 // 1600 row-tiles * 8 col-tiles
  int rt = bid >> 3, ct = bid & 7;
  int r0 = rt * 64, c0 = ct * 64;
  int t = threadIdx.x, ty = t >> 4, tx = t & 15;
  int row0 = r0 + ty * 4;
  int col  = c0 + tx * 4;
  float acc[4][4] = {};
  const float* mp = Mbuf + col;
  for (int kb = 0; kb < 32; ++kb) {
    int k = kb * 4;
    float4 b0 = *(const float4*)(mp + (long)(k + 0) * 512);
    float4 b1 = *(const float4*)(mp + (long)(k + 1) * 512);
    float4 b2 = *(const float4*)(mp + (long)(k + 2) * 512);
    float4 b3 = *(const float4*)(mp + (long)(k + 3) * 512);
    float bm[4][4] = {{b0.x,b0.y,b0.z,b0.w},{b1.x,b1.y,b1.z,b1.w},
                      {b2.x,b2.y,b2.z,b2.w},{b3.x,b3.y,b3.z,b3.w}};
    #pragma unroll
    for (int rr = 0; rr < 4; ++rr) {
      float4 a4 = *(const float4*)(emb + (long)(row0 + rr) * 128 + k);
      float av[4] = {a4.x, a4.y, a4.z, a4.w};
      #pragma unroll
      for (int i = 0; i < 4; ++i)
        #pragma unroll
        for (int cc = 0; cc < 4; ++cc)
          acc[rr][cc] += av[i] * bm[i][cc];
    }
  }
  float badd[4] = {0.f, 0.f, 0.f, 0.f};
  if (c0 < 128) {
    #pragma unroll
    for (int cc = 0; cc < 4; ++cc) badd[cc] = bk1[col + cc];
  }
  #pragma unroll
  for (int rr = 0; rr < 4; ++rr) {
    int row = row0 + rr;
    float v[4];
    #pragma unroll
    for (int cc = 0; cc < 4; ++cc) v[cc] = acc[rr][cc] + badd[cc];
    if (col >= 384) {
      int bb = row / 200;
      #pragma unroll
      for (int cc = 0; cc < 4; ++cc) v[cc] += QR[bb * 128 + (col - 384) + cc];
    }
    float4 v4; v4.x = v[0]; v4.y = v[1]; v4.z = v[2]; v4.w = v[3];
    *(float4*)(OUT + (long)row * 512 + col) = v4;
  }
}

__global__ void init_ctr(int* __restrict__ c) { *c = 0; }

// ---------------- decode: persistent work-stealing ----------------
// LDS-pipe-optimized: K1 stored [n][d] rotated by 4n (A reads 16 b128/lane,
// conflict-optimal); qv read as b128 broadcasts; ul rotated by 4m (C reads
// 4 b128). FLOP orders identical to the round-11 passing kernel.
__global__ __attribute__((amdgpu_flat_work_group_size(1024, 1024)))
void decode(const float* __restrict__ OUT, const float* __restrict__ QI,
            int* __restrict__ ctr, float* __restrict__ sol,
            float* __restrict__ out) {
  __shared__ __align__(16) float k1r[25600];   // [n][128] rot-4n, 102.4 KB
  __shared__ __align__(16) float at[1600];     // attn [h][200]  6.4 KB
  __shared__ __align__(16) float mhal[128];
  __shared__ float lg[200];
  __shared__ __align__(16) float qv[128];
  __shared__ __align__(16) float ul[12800];    // U-high [m][64] rot-4m, 51.2 KB
  __shared__ int   bci;
  __shared__ int   bsel;

  const int t = threadIdx.x;
  const int lane = t & 63, wave = t >> 6;
  const int o = t >> 3, q8 = t & 7;
  const int m4 = t >> 2, j4 = t & 3;
  // B-phase quad-aligned n-split: starts {0,24,48,72,100,124,148,172}
  const int stq = (q8 * 25) & ~3;
  const int cq  = ((((q8 + 1) * 25) & ~3) - stq) >> 2;   // 6 or 7 quads

  for (;;) {
    if (t == 0) bsel = atomicAdd(ctr, 1);
    __syncthreads();
    const int b = bsel;
    if (b >= 512) break;
    const float* outb = OUT + (long)b * 200 * 512;

    // K1 -> LDS [n][d] rotated: k1r[n][ (d+4n)&127 ] = K1[n][d]
    for (int p = 0; p < 25; ++p) {
      int f = p * 1024 + t;
      int n = f >> 7, d = f & 127;
      k1r[n * 128 + ((d + 4 * n) & 127)] = outb[n * 512 + d];
    }
    // U-high -> LDS: ul[m][(c + 4m)&63] = U[m][(c>>4)*32 + 16 + (c&15)]
    for (int f = t; f < 12800; f += 1024) {
      int m = f >> 6, c = f & 63;
      ul[m * 64 + ((c + 4 * m) & 63)] =
          outb[m * 512 + 256 + (c >> 4) * 32 + 16 + (c & 15)];
    }
    // V: thread (o, q8) holds V[stq + c*4 + e][o] as 7 guarded vectors
    f32x4 vA = {}, vB = {}, vC = {}, vD = {}, vE = {}, vF = {}, vG = {};
    {
      const float* vp = outb + 128 + o;
      #pragma unroll
      for (int e = 0; e < 4; ++e) vA[e] = vp[(stq + 0 + e) * 512];
      #pragma unroll
      for (int e = 0; e < 4; ++e) vB[e] = vp[(stq + 4 + e) * 512];
      #pragma unroll
      for (int e = 0; e < 4; ++e) vC[e] = vp[(stq + 8 + e) * 512];
      #pragma unroll
      for (int e = 0; e < 4; ++e) vD[e] = vp[(stq + 12 + e) * 512];
      #pragma unroll
      for (int e = 0; e < 4; ++e) vE[e] = vp[(stq + 16 + e) * 512];
      #pragma unroll
      for (int e = 0; e < 4; ++e) vF[e] = vp[(stq + 20 + e) * 512];
      if (cq == 7) {
        #pragma unroll
        for (int e = 0; e < 4; ++e) vG[e] = vp[(stq + 24 + e) * 512];
      }
    }
    // U-low pre-rotated: urR[c] = U[m4][j4*32 + 4*((c+j4)&3) .. +3]
    f32x4 urR0 = {}, urR1 = {}, urR2 = {}, urR3 = {};
    if (t < 800) {
      const float* up = outb + m4 * 512 + 256 + j4 * 32;
      urR0 = *(const f32x4*)(up + 4 * ((0 + j4) & 3));
      urR1 = *(const f32x4*)(up + 4 * ((1 + j4) & 3));
      urR2 = *(const f32x4*)(up + 4 * ((2 + j4) & 3));
      urR3 = *(const f32x4*)(up + 4 * ((3 + j4) & 3));
    }
    if (t < 128) qv[t] = QI[b * 128 + t];   // step-0 query

    int mk = 0;        // per-lane mask bits (node = lane + 64k), waves 0-7
    bool cm = false;   // node m4 masked, threads < 800
    bool live = true, picked0 = false;
    float llsum = 0.f, chose = 0.f;

    __syncthreads();

    for (int st = 0; st < 200; ++st) {
      // ---- A: scores + softmax (wave h = head h); 2x8 half-chain order ----
      if (wave < 8) {
        const int hb = wave * 16;
        float acc[4] = {};
        #pragma unroll
        for (int hf = 0; hf < 2; ++hf) {
          f32x4 qa = *(const f32x4*)&qv[hb + hf * 8];       // broadcast b128
          f32x4 qb2 = *(const f32x4*)&qv[hb + hf * 8 + 4];
          #pragma unroll
          for (int k = 0; k < 4; ++k) {
            int n = lane + 64 * k;
            if (n < 200) {
              const float* kb = k1r + n * 128;
              int off  = (hb + hf * 8 + 4 * n) & 127;
              int off2 = (hb + hf * 8 + 4 + 4 * n) & 127;
              f32x4 kA = *(const f32x4*)(kb + off);
              f32x4 kB = *(const f32x4*)(kb + off2);
              float ah = qa[0] * kA[0];
              ah += qa[1] * kA[1]; ah += qa[2] * kA[2]; ah += qa[3] * kA[3];
              ah += qb2[0] * kB[0]; ah += qb2[1] * kB[1];
              ah += qb2[2] * kB[2]; ah += qb2[3] * kB[3];
              acc[k] += ah;
            }
          }
        }
        float sv[4];
        float mx = -INFINITY;
        #pragma unroll
        for (int k = 0; k < 4; ++k) {
          int n = lane + 64 * k;
          float s = -INFINITY;
          if (n < 200) {
            s = acc[k] * 0.25f;
            if (mk & (1 << k)) s = NEGV;
          }
          sv[k] = s;
          mx = fmaxf(mx, s);
        }
        float vmax = wave_max(mx);
        float ls = 0.f;
        #pragma unroll
        for (int k = 0; k < 4; ++k) { sv[k] = expf(sv[k] - vmax); ls += sv[k]; }
        ls = wave_sum(ls);
        #pragma unroll
        for (int k = 0; k < 4; ++k) {
          int n = lane + 64 * k;
          if (n < 200) at[wave * 200 + n] = sv[k] / ls;
        }
      }
      __syncthreads();

      // ---- B: mha[o] = sum_n attn[h][n] * V[n][o]  (b128 at-reads) ----
      {
        const int h2 = t >> 7;
        const float* ap = at + h2 * 200 + stq;
        float a = 0.f;
        f32x4 av;
        av = *(const f32x4*)(ap + 0);
        a += av[0]*vA[0]; a += av[1]*vA[1]; a += av[2]*vA[2]; a += av[3]*vA[3];
        av = *(const f32x4*)(ap + 4);
        a += av[0]*vB[0]; a += av[1]*vB[1]; a += av[2]*vB[2]; a += av[3]*vB[3];
        av = *(const f32x4*)(ap + 8);
        a += av[0]*vC[0]; a += av[1]*vC[1]; a += av[2]*vC[2]; a += av[3]*vC[3];
        av = *(const f32x4*)(ap + 12);
        a += av[0]*vD[0]; a += av[1]*vD[1]; a += av[2]*vD[2]; a += av[3]*vD[3];
        av = *(const f32x4*)(ap + 16);
        a += av[0]*vE[0]; a += av[1]*vE[1]; a += av[2]*vE[2]; a += av[3]*vE[3];
        av = *(const f32x4*)(ap + 20);
        a += av[0]*vF[0]; a += av[1]*vF[1]; a += av[2]*vF[2]; a += av[3]*vF[3];
        if (cq == 7) {
          av = *(const f32x4*)(ap + 24);
          a += av[0]*vG[0]; a += av[1]*vG[1]; a += av[2]*vG[2]; a += av[3]*vG[3];
        }
        a += DPPF(a, 0xB1, 0.f);
        a += DPPF(a, 0x4E, 0.f);
        a += DPPF(a, 0x141, 0.f);
        if (q8 == 0) mhal[o] = a;
      }
      __syncthreads();

      // ---- C: logits[m] = 10*tanh((mha . U[m]) / sqrt(128)) ----
      if (t < 800) {
        float a = 0.f;
        // low half d 0..15: rotated b128 mhal + pre-rotated U-low regs
        {
          f32x4 ml;
          ml = *(const f32x4*)&mhal[j4 * 32 + ((0 + j4) & 3) * 4];
          a += ml[0]*urR0[0]; a += ml[1]*urR0[1]; a += ml[2]*urR0[2]; a += ml[3]*urR0[3];
          ml = *(const f32x4*)&mhal[j4 * 32 + ((1 + j4) & 3) * 4];
          a += ml[0]*urR1[0]; a += ml[1]*urR1[1]; a += ml[2]*urR1[2]; a += ml[3]*urR1[3];
          ml = *(const f32x4*)&mhal[j4 * 32 + ((2 + j4) & 3) * 4];
          a += ml[0]*urR2[0]; a += ml[1]*urR2[1]; a += ml[2]*urR2[2]; a += ml[3]*urR2[3];
          ml = *(const f32x4*)&mhal[j4 * 32 + ((3 + j4) & 3) * 4];
          a += ml[0]*urR3[0]; a += ml[1]*urR3[1]; a += ml[2]*urR3[2]; a += ml[3]*urR3[3];
        }
        // high half d 16..31: rotated b128 mhal + ul b128 (rot-4m layout)
        const int ubase = m4 * 64;
        #pragma unroll
        for (int c = 0; c < 4; ++c) {
          int ci = (c + j4) & 3;
          f32x4 mh = *(const f32x4*)&mhal[j4 * 32 + 16 + ci * 4];
          f32x4 uu = *(const f32x4*)&ul[ubase + ((j4 * 16 + ci * 4 + 4 * m4) & 63)];
          a += mh[0]*uu[0]; a += mh[1]*uu[1]; a += mh[2]*uu[2]; a += mh[3]*uu[3];
        }
        a += DPPF(a, 0xB1, 0.f);
        a += DPPF(a, 0x4E, 0.f);
        if (j4 == 0) {
          float l = 10.f * tanhf(a / 11.313708498984761f);
          lg[m4] = cm ? NEGV : l;
        }
      }
      __syncthreads();

      // ---- D: argmax -> issue q-row load -> lse (overlaps load) ----
      if (wave < 8) {
        float lv[4];
        float mx = -INFINITY;
        #pragma unroll
        for (int k = 0; k < 4; ++k) {
          int n = lane + 64 * k;
          lv[k] = (n < 200) ? lg[n] : -INFINITY;
          mx = fmaxf(mx, lv[k]);
        }
        float vmax = wave_max(mx);
        int bidx = -1;
        #pragma unroll
        for (int k = 0; k < 4; ++k) {
          unsigned long long bm =
              __ballot((lane + 64 * k < 200) && (lv[k] == vmax));
          if (bidx < 0 && bm != 0ull) bidx = k * 64 + (int)__builtin_ctzll(bm);
        }
        int nxt = live ? bidx : 0;
        if (t < 128) qv[t] = outb[(long)nxt * 512 + 384 + t];
        float e = 0.f;
        #pragma unroll
        for (int k = 0; k < 4; ++k) e += expf(lv[k] - vmax);
        float se_ = wave_sum(e);
        float lse = logf(se_);
        if (t == 0) {
          chose = live ? (-lse) : ((lv[0] - vmax) - lse);
          out[2048 + (long)b * 200 + st] = (float)nxt;
          bci = nxt;
        }
      }
      __syncthreads();

      int nxt = bci;
      if (!live) {
        if (t == 0) llsum += chose * (float)(200 - st);
        for (int s2 = st + 1 + t; s2 < 200; s2 += 1024)
          out[2048 + (long)b * 200 + s2] = 0.f;
        break;
      }
      if (t == 0) llsum += chose;
      if (wave < 8 && (nxt & 63) == lane) mk |= 1 << (nxt >> 6);
      if (t < 800 && nxt == m4) cm = true;
      if (nxt == 0) { live = false; picked0 = true; }
    }

    if (t == 0) out[1536 + b] = picked0 ? llsum : 0.f;
    if (t < 800 && j4 == 0) {
      float s = (m4 == 0) ? 1.f : ((picked0 && cm) ? 1.f : 0.f);
      sol[(long)b * 200 + m4] = s;
    }
    __syncthreads();   // protect LDS reuse before next grab
  }
}

// ---------------- cost ----------------
__global__ __launch_bounds__(256)
void cost_kernel(const float* __restrict__ x, const float* __restrict__ rf,
                 const float* __restrict__ sol, float* __restrict__ out) {
  __shared__ float solL[256];
  __shared__ float red[8];
  const int b = blockIdx.x, t = threadIdx.x;
  solL[t] = (t < 200) ? sol[b * 200 + t] : 0.f;
  __syncthreads();
  const float* x0 = x + (long)b * 40000;
  const float* x1 = x + 20480000l + (long)b * 40000;
  float a1 = 0.f, a2 = 0.f;
  if (t < 200) {
    for (int i = 0; i < 200; ++i) {
      if (solL[i] != 0.f) {
        a1 += x0[i * 200 + t];
        a2 += x1[i * 200 + t];
      }
    }
    float w = solL[t];
    a1 *= w; a2 *= w;
  }
  #pragma unroll
  for (int off = 32; off > 0; off >>= 1) {
    a1 += __shfl_xor(a1, off);
    a2 += __shfl_xor(a2, off);
  }
  if ((t & 63) == 0) { red[(t >> 6) * 2] = a1; red[(t >> 6) * 2 + 1] = a2; }
  __syncthreads();
  if (t == 0) {
    float f1 = red[0] + red[2] + red[4] + red[6];
    float f2 = red[1] + red[3] + red[5] + red[7];
    out[b]        = -(f1 * rf[0] + f2 * rf[1]);
    out[512 + b]  = f1;
    out[1024 + b] = f2;
  }
}

extern "C" void kernel_launch(void* const* d_in, const int* in_sizes, int n_in,
                              void* d_out, int out_size, void* d_ws, size_t ws_size,
                              hipStream_t stream) {
  const float* x     = (const float*)d_in[0];
  const float* rf    = (const float*)d_in[1];
  const float* emb   = (const float*)d_in[2];
  const float* Wk1   = (const float*)d_in[4];
  const float* bk1   = (const float*)d_in[5];
  const float* Wv    = (const float*)d_in[6];
  const float* Wk2   = (const float*)d_in[7];
  const float* Wout  = (const float*)d_in[8];
  const float* Wq    = (const float*)d_in[9];
  const float* initn = (const float*)d_in[10];
  float* out = (float*)d_out;
  float* ws  = (float*)d_ws;

  if (ws_size < (size_t)WS_FLOATS * 4) return;

  float* OUTb = ws + OUT_F;
  float* Mb   = ws + M_F;
  float* QRb  = ws + QR_F;   // dead after gemm; first 4 bytes reused as counter
  float* QIb  = ws + QI_F;
  float* solb = ws + SOL_F;

  build_M<<<256, 256, 0, stream>>>(Wk1, Wv, Wk2, Wout, Wq, Mb);
  build_Q<<<256, 256, 0, stream>>>(rf, Wq, initn, QRb, QIb);
  gemm_static<<<12800, 256, 0, stream>>>(emb, Mb, bk1, QRb, OUTb);
  init_ctr<<<1, 1, 0, stream>>>((int*)QRb);
  decode<<<256, 1024, 0, stream>>>(OUTb, QIb, (int*)QRb, solb, out);
  cost_kernel<<<512, 256, 0, stream>>>(x, rf, solb, out);
}

// Round 13
// 1425.776 us; speedup vs baseline: 1.3740x; 1.1390x over previous
//
#include <hip/hip_runtime.h>
#include <math.h>

#define NEGV (-1e9f)

// ws layout (float offsets):
//   OUT [B*N][512] : cols 0..127 K1, 128..255 V, 256..383 U=K2@Wout,
//                    384..511 Qfull = QR + emb@Wq[:,2:]^T  (QR folded in GEMM)
//   M   [128][512], QR [B][128] (dead after gemm -> reused as work counter),
//   QI  [B][128], SOL [B][200]
#define OUT_F   0l
#define M_F     52428800l
#define QR_F    (M_F + 65536l)
#define QI_F    (QR_F + 65536l)
#define SOL_F   (QI_F + 65536l)
#define WS_FLOATS (SOL_F + 102400l)   // ~211 MB (known OK)

typedef float f32x4 __attribute__((ext_vector_type(4)));

// ---------------- DPP cross-lane helpers ----------------
#define DPPF(x, ctrl, oldv) __int_as_float(__builtin_amdgcn_update_dpp( \
      __float_as_int(oldv), __float_as_int(x), ctrl, 0xF, 0xF, false))

__device__ __forceinline__ float wave_max(float x) {
  x = fmaxf(x, DPPF(x, 0x111, -INFINITY));
  x = fmaxf(x, DPPF(x, 0x112, -INFINITY));
  x = fmaxf(x, DPPF(x, 0x114, -INFINITY));
  x = fmaxf(x, DPPF(x, 0x118, -INFINITY));
  x = fmaxf(x, DPPF(x, 0x142, -INFINITY));
  x = fmaxf(x, DPPF(x, 0x143, -INFINITY));
  return __int_as_float(__builtin_amdgcn_readlane(__float_as_int(x), 63));
}
__device__ __forceinline__ float wave_sum(float x) {
  x = x + DPPF(x, 0x111, 0.f);
  x = x + DPPF(x, 0x112, 0.f);
  x = x + DPPF(x, 0x114, 0.f);
  x = x + DPPF(x, 0x118, 0.f);
  x = x + DPPF(x, 0x142, 0.f);
  x = x + DPPF(x, 0x143, 0.f);
  return __int_as_float(__builtin_amdgcn_readlane(__float_as_int(x), 63));
}

// ---------------- static precompute ----------------
__global__ __launch_bounds__(256)
void build_M(const float* __restrict__ Wk1, const float* __restrict__ Wv,
             const float* __restrict__ Wk2, const float* __restrict__ Wout,
             const float* __restrict__ Wq, float* __restrict__ Mbuf) {
  int g = blockIdx.x * 256 + threadIdx.x;
  int j = g >> 9, c = g & 511;
  float val;
  if (c < 128) {
    val = Wk1[c * 128 + j];
  } else if (c < 256) {
    val = Wv[(c - 128) * 128 + j];
  } else if (c < 384) {
    int d = c - 256;
    float s = 0.f;
    for (int e = 0; e < 128; ++e) s += Wk2[e * 128 + j] * Wout[e * 128 + d];
    val = s;
  } else {
    val = Wq[(c - 384) * 130 + 2 + j];
  }
  Mbuf[j * 512 + c] = val;
}

__global__ __launch_bounds__(256)
void build_Q(const float* __restrict__ rf, const float* __restrict__ Wq,
             const float* __restrict__ initn, float* __restrict__ QR,
             float* __restrict__ QI) {
  int g = blockIdx.x * 256 + threadIdx.x;   // 65536 = 512*128
  int b = g >> 7, d = g & 127;
  float qr = Wq[d * 130 + 0] * rf[b * 2 + 0] + Wq[d * 130 + 1] * rf[b * 2 + 1];
  float qi = qr;
  for (int j = 0; j < 128; ++j) qi += Wq[d * 130 + 2 + j] * initn[j];
  QR[g] = qr;
  QI[g] = qi;
}

__global__ __launch_bounds__(256)
void gemm_static(const float* __restrict__ emb, const float* __restrict__ Mbuf,
                 const float* __restrict__ bk1, const float* __restrict__ QR,
                 float* __restrict__ OUT) {
  int bid = blockIdx.x;                 // 1600 row-tiles * 8 col-tiles
  int rt = bid >> 3, ct = bid & 7;
  int r0 = rt * 64, c0 = ct * 64;
  int t = threadIdx.x, ty = t >> 4, tx = t & 15;
  int row0 = r0 + ty * 4;
  int col  = c0 + tx * 4;
  float acc[4][4] = {};
  const float* mp = Mbuf + col;
  for (int kb = 0; kb < 32; ++kb) {
    int k = kb * 4;
    float4 b0 = *(const float4*)(mp + (long)(k + 0) * 512);
    float4 b1 = *(const float4*)(mp + (long)(k + 1) * 512);
    float4 b2 = *(const float4*)(mp + (long)(k + 2) * 512);
    float4 b3 = *(const float4*)(mp + (long)(k + 3) * 512);
    float bm[4][4] = {{b0.x,b0.y,b0.z,b0.w},{b1.x,b1.y,b1.z,b1.w},
                      {b2.x,b2.y,b2.z,b2.w},{b3.x,b3.y,b3.z,b3.w}};
    #pragma unroll
    for (int rr = 0; rr < 4; ++rr) {
      float4 a4 = *(const float4*)(emb + (long)(row0 + rr) * 128 + k);
      float av[4] = {a4.x, a4.y, a4.z, a4.w};
      #pragma unroll
      for (int i = 0; i < 4; ++i)
        #pragma unroll
        for (int cc = 0; cc < 4; ++cc)
          acc[rr][cc] += av[i] * bm[i][cc];
    }
  }
  float badd[4] = {0.f, 0.f, 0.f, 0.f};
  if (c0 < 128) {
    #pragma unroll
    for (int cc = 0; cc < 4; ++cc) badd[cc] = bk1[col + cc];
  }
  #pragma unroll
  for (int rr = 0; rr < 4; ++rr) {
    int row = row0 + rr;
    float v[4];
    #pragma unroll
    for (int cc = 0; cc < 4; ++cc) v[cc] = acc[rr][cc] + badd[cc];
    if (col >= 384) {
      int bb = row / 200;
      #pragma unroll
      for (int cc = 0; cc < 4; ++cc) v[cc] += QR[bb * 128 + (col - 384) + cc];
    }
    float4 v4; v4.x = v[0]; v4.y = v[1]; v4.z = v[2]; v4.w = v[3];
    *(float4*)(OUT + (long)row * 512 + col) = v4;
  }
}

__global__ void init_ctr(int* __restrict__ c) { *c = 0; }

// ---------------- decode512: all-register K1/U/V, broadcast-only LDS ----------------
// 512 threads. t<400: (n = t>>1, half = t&1) owns K1[n][64h..+63] and
// U[n][64h..+63] in regs; all t: (o = t>>2, r4 = t&3) owns a quad-aligned
// V slice (48/52 rows). Per-step LDS = broadcasts only. Used only if the
// allocator grants a big VGPR file (runtime numRegs check in the launcher).
__global__ __attribute__((amdgpu_flat_work_group_size(512, 512), amdgpu_waves_per_eu(2, 2)))
void decode512(const float* __restrict__ OUT, const float* __restrict__ QI,
               int* __restrict__ ctr, float* __restrict__ sol,
               float* __restrict__ out) {
  __shared__ float sc[1600];                   // scores -> attn [h][200]
  __shared__ __align__(16) float mhal[128];
  __shared__ float lg[200];
  __shared__ __align__(16) float qv[128];
  __shared__ int bci, bsel;

  const int t = threadIdx.x;
  const int lane = t & 63, wave = t >> 6;
  const int o = t >> 2, r4 = t & 3;
  const int mn = t >> 1, half = t & 1;
  const int vst  = (r4 == 0) ? 0 : (r4 == 1 ? 48 : (r4 == 2 ? 100 : 152));
  const bool mid = (r4 == 1) || (r4 == 2);     // 52-row slices

  float kreg[64], ureg[64], vreg[52];

  for (;;) {
    if (t == 0) bsel = atomicAdd(ctr, 1);
    __syncthreads();
    const int b = bsel;
    if (b >= 512) break;
    const float* outb = OUT + (long)b * 200 * 512;

    // K1, U rows -> regs (t < 400)
    if (t < 400) {
      const float* kp = outb + mn * 512 + 64 * half;
      const float* up = outb + mn * 512 + 256 + 64 * half;
      #pragma unroll
      for (int c = 0; c < 16; ++c)
        *(f32x4*)&kreg[c * 4] = *(const f32x4*)(kp + c * 4);
      #pragma unroll
      for (int c = 0; c < 16; ++c)
        *(f32x4*)&ureg[c * 4] = *(const f32x4*)(up + c * 4);
    }
    // V slice -> regs (all t)
    {
      const float* vp = outb + 128 + o;
      #pragma unroll
      for (int i = 0; i < 48; ++i) vreg[i] = vp[(vst + i) * 512];
      vreg[48] = mid ? vp[(vst + 48) * 512] : 0.f;
      vreg[49] = mid ? vp[(vst + 49) * 512] : 0.f;
      vreg[50] = mid ? vp[(vst + 50) * 512] : 0.f;
      vreg[51] = mid ? vp[(vst + 51) * 512] : 0.f;
    }
    if (t < 128) qv[t] = QI[b * 128 + t];   // step-0 query

    bool cmb = false;   // node mn visited (t < 400)
    bool live = true, picked0 = false;
    float llsum = 0.f, chose = 0.f;

    __syncthreads();

    for (int st = 0; st < 200; ++st) {
      // ---- A1: scores from registers (owner thread = (n, half)) ----
      if (t < 400) {
        #pragma unroll
        for (int hh = 0; hh < 4; ++hh) {
          float s = 0.f;
          #pragma unroll
          for (int c = 0; c < 4; ++c) {
            f32x4 q4 = *(const f32x4*)&qv[64 * half + hh * 16 + c * 4];
            s += q4[0] * kreg[hh * 16 + c * 4 + 0];
            s += q4[1] * kreg[hh * 16 + c * 4 + 1];
            s += q4[2] * kreg[hh * 16 + c * 4 + 2];
            s += q4[3] * kreg[hh * 16 + c * 4 + 3];
          }
          sc[(4 * half + hh) * 200 + mn] = cmb ? NEGV : s * 0.25f;
        }
      }
      __syncthreads();

      // ---- A2: softmax per head (wave h), in place ----
      {
        float sv[4];
        float mx = -INFINITY;
        #pragma unroll
        for (int k = 0; k < 4; ++k) {
          int n = lane + 64 * k;
          float s = (n < 200) ? sc[wave * 200 + n] : -INFINITY;
          sv[k] = s;
          mx = fmaxf(mx, s);
        }
        float vmax = wave_max(mx);
        float ls = 0.f;
        #pragma unroll
        for (int k = 0; k < 4; ++k) { sv[k] = expf(sv[k] - vmax); ls += sv[k]; }
        ls = wave_sum(ls);
        #pragma unroll
        for (int k = 0; k < 4; ++k) {
          int n = lane + 64 * k;
          if (n < 200) sc[wave * 200 + n] = sv[k] / ls;
        }
      }
      __syncthreads();

      // ---- B: mha[o] = sum_n attn[h][n] * V[n][o]  (h = wave) ----
      {
        const float* ap = sc + wave * 200 + vst;
        float a = 0.f;
        #pragma unroll
        for (int c = 0; c < 12; ++c) {
          f32x4 av = *(const f32x4*)(ap + c * 4);
          a += av[0] * vreg[c * 4 + 0];
          a += av[1] * vreg[c * 4 + 1];
          a += av[2] * vreg[c * 4 + 2];
          a += av[3] * vreg[c * 4 + 3];
        }
        if (mid) {
          f32x4 av = *(const f32x4*)(ap + 48);
          a += av[0] * vreg[48]; a += av[1] * vreg[49];
          a += av[2] * vreg[50]; a += av[3] * vreg[51];
        }
        a += DPPF(a, 0xB1, 0.f);
        a += DPPF(a, 0x4E, 0.f);
        if (r4 == 0) mhal[o] = a;
      }
      __syncthreads();

      // ---- C: logits[m] = 10*tanh((mha . U[m]) / sqrt(128)) ----
      if (t < 400) {
        float a = 0.f;
        #pragma unroll
        for (int c = 0; c < 16; ++c) {
          f32x4 mh = *(const f32x4*)&mhal[64 * half + c * 4];
          a += mh[0] * ureg[c * 4 + 0];
          a += mh[1] * ureg[c * 4 + 1];
          a += mh[2] * ureg[c * 4 + 2];
          a += mh[3] * ureg[c * 4 + 3];
        }
        a += DPPF(a, 0xB1, 0.f);   // (half 0) + (half 1)
        if (half == 0) {
          float l = 10.f * tanhf(a / 11.313708498984761f);
          lg[mn] = cmb ? NEGV : l;
        }
      }
      __syncthreads();

      // ---- D: argmax -> issue q-row load -> lse ----
      {
        float lv[4];
        float mx = -INFINITY;
        #pragma unroll
        for (int k = 0; k < 4; ++k) {
          int n = lane + 64 * k;
          lv[k] = (n < 200) ? lg[n] : -INFINITY;
          mx = fmaxf(mx, lv[k]);
        }
        float vmax = wave_max(mx);
        int bidx = -1;
        #pragma unroll
        for (int k = 0; k < 4; ++k) {
          unsigned long long bm =
              __ballot((lane + 64 * k < 200) && (lv[k] == vmax));
          if (bidx < 0 && bm != 0ull) bidx = k * 64 + (int)__builtin_ctzll(bm);
        }
        int nxt = live ? bidx : 0;
        if (t < 128) qv[t] = outb[(long)nxt * 512 + 384 + t];
        float e = 0.f;
        #pragma unroll
        for (int k = 0; k < 4; ++k) e += expf(lv[k] - vmax);
        float se_ = wave_sum(e);
        float lse = logf(se_);
        if (t == 0) {
          chose = live ? (-lse) : ((lv[0] - vmax) - lse);
          out[2048 + (long)b * 200 + st] = (float)nxt;
          bci = nxt;
        }
      }
      __syncthreads();

      int nxt = bci;
      if (!live) {
        if (t == 0) llsum += chose * (float)(200 - st);
        for (int s2 = st + 1 + t; s2 < 200; s2 += 512)
          out[2048 + (long)b * 200 + s2] = 0.f;
        break;
      }
      if (t == 0) llsum += chose;
      if (t < 400 && nxt == mn) cmb = true;
      if (nxt == 0) { live = false; picked0 = true; }
    }

    if (t == 0) out[1536 + b] = picked0 ? llsum : 0.f;
    if (t < 400 && half == 0) {
      float s = (mn == 0) ? 1.f : ((picked0 && cmb) ? 1.f : 0.f);
      sol[(long)b * 200 + mn] = s;
    }
    __syncthreads();   // protect LDS reuse before next grab
  }
}

// ---------------- decode (round-12 fallback, unchanged) ----------------
__global__ __attribute__((amdgpu_flat_work_group_size(1024, 1024)))
void decode(const float* __restrict__ OUT, const float* __restrict__ QI,
            int* __restrict__ ctr, float* __restrict__ sol,
            float* __restrict__ out) {
  __shared__ __align__(16) float k1r[25600];   // [n][128] rot-4n, 102.4 KB
  __shared__ __align__(16) float at[1600];     // attn [h][200]  6.4 KB
  __shared__ __align__(16) float mhal[128];
  __shared__ float lg[200];
  __shared__ __align__(16) float qv[128];
  __shared__ __align__(16) float ul[12800];    // U-high [m][64] rot-4m, 51.2 KB
  __shared__ int   bci;
  __shared__ int   bsel;

  const int t = threadIdx.x;
  const int lane = t & 63, wave = t >> 6;
  const int o = t >> 3, q8 = t & 7;
  const int m4 = t >> 2, j4 = t & 3;
  const int stq = (q8 * 25) & ~3;
  const int cq  = ((((q8 + 1) * 25) & ~3) - stq) >> 2;   // 6 or 7 quads

  for (;;) {
    if (t == 0) bsel = atomicAdd(ctr, 1);
    __syncthreads();
    const int b = bsel;
    if (b >= 512) break;
    const float* outb = OUT + (long)b * 200 * 512;

    for (int p = 0; p < 25; ++p) {
      int f = p * 1024 + t;
      int n = f >> 7, d = f & 127;
      k1r[n * 128 + ((d + 4 * n) & 127)] = outb[n * 512 + d];
    }
    for (int f = t; f < 12800; f += 1024) {
      int m = f >> 6, c = f & 63;
      ul[m * 64 + ((c + 4 * m) & 63)] =
          outb[m * 512 + 256 + (c >> 4) * 32 + 16 + (c & 15)];
    }
    f32x4 vA = {}, vB = {}, vC = {}, vD = {}, vE = {}, vF = {}, vG = {};
    {
      const float* vp = outb + 128 + o;
      #pragma unroll
      for (int e = 0; e < 4; ++e) vA[e] = vp[(stq + 0 + e) * 512];
      #pragma unroll
      for (int e = 0; e < 4; ++e) vB[e] = vp[(stq + 4 + e) * 512];
      #pragma unroll
      for (int e = 0; e < 4; ++e) vC[e] = vp[(stq + 8 + e) * 512];
      #pragma unroll
      for (int e = 0; e < 4; ++e) vD[e] = vp[(stq + 12 + e) * 512];
      #pragma unroll
      for (int e = 0; e < 4; ++e) vE[e] = vp[(stq + 16 + e) * 512];
      #pragma unroll
      for (int e = 0; e < 4; ++e) vF[e] = vp[(stq + 20 + e) * 512];
      if (cq == 7) {
        #pragma unroll
        for (int e = 0; e < 4; ++e) vG[e] = vp[(stq + 24 + e) * 512];
      }
    }
    f32x4 urR0 = {}, urR1 = {}, urR2 = {}, urR3 = {};
    if (t < 800) {
      const float* up = outb + m4 * 512 + 256 + j4 * 32;
      urR0 = *(const f32x4*)(up + 4 * ((0 + j4) & 3));
      urR1 = *(const f32x4*)(up + 4 * ((1 + j4) & 3));
      urR2 = *(const f32x4*)(up + 4 * ((2 + j4) & 3));
      urR3 = *(const f32x4*)(up + 4 * ((3 + j4) & 3));
    }
    if (t < 128) qv[t] = QI[b * 128 + t];

    int mk = 0;
    bool cm = false;
    bool live = true, picked0 = false;
    float llsum = 0.f, chose = 0.f;

    __syncthreads();

    for (int st = 0; st < 200; ++st) {
      if (wave < 8) {
        const int hb = wave * 16;
        float acc[4] = {};
        #pragma unroll
        for (int hf = 0; hf < 2; ++hf) {
          f32x4 qa = *(const f32x4*)&qv[hb + hf * 8];
          f32x4 qb2 = *(const f32x4*)&qv[hb + hf * 8 + 4];
          #pragma unroll
          for (int k = 0; k < 4; ++k) {
            int n = lane + 64 * k;
            if (n < 200) {
              const float* kb = k1r + n * 128;
              int off  = (hb + hf * 8 + 4 * n) & 127;
              int off2 = (hb + hf * 8 + 4 + 4 * n) & 127;
              f32x4 kA = *(const f32x4*)(kb + off);
              f32x4 kB = *(const f32x4*)(kb + off2);
              float ah = qa[0] * kA[0];
              ah += qa[1] * kA[1]; ah += qa[2] * kA[2]; ah += qa[3] * kA[3];
              ah += qb2[0] * kB[0]; ah += qb2[1] * kB[1];
              ah += qb2[2] * kB[2]; ah += qb2[3] * kB[3];
              acc[k] += ah;
            }
          }
        }
        float sv[4];
        float mx = -INFINITY;
        #pragma unroll
        for (int k = 0; k < 4; ++k) {
          int n = lane + 64 * k;
          float s = -INFINITY;
          if (n < 200) {
            s = acc[k] * 0.25f;
            if (mk & (1 << k)) s = NEGV;
          }
          sv[k] = s;
          mx = fmaxf(mx, s);
        }
        float vmax = wave_max(mx);
        float ls = 0.f;
        #pragma unroll
        for (int k = 0; k < 4; ++k) { sv[k] = expf(sv[k] - vmax); ls += sv[k]; }
        ls = wave_sum(ls);
        #pragma unroll
        for (int k = 0; k < 4; ++k) {
          int n = lane + 64 * k;
          if (n < 200) at[wave * 200 + n] = sv[k] / ls;
        }
      }
      __syncthreads();

      {
        const int h2 = t >> 7;
        const float* ap = at + h2 * 200 + stq;
        float a = 0.f;
        f32x4 av;
        av = *(const f32x4*)(ap + 0);
        a += av[0]*vA[0]; a += av[1]*vA[1]; a += av[2]*vA[2]; a += av[3]*vA[3];
        av = *(const f32x4*)(ap + 4);
        a += av[0]*vB[0]; a += av[1]*vB[1]; a += av[2]*vB[2]; a += av[3]*vB[3];
        av = *(const f32x4*)(ap + 8);
        a += av[0]*vC[0]; a += av[1]*vC[1]; a += av[2]*vC[2]; a += av[3]*vC[3];
        av = *(const f32x4*)(ap + 12);
        a += av[0]*vD[0]; a += av[1]*vD[1]; a += av[2]*vD[2]; a += av[3]*vD[3];
        av = *(const f32x4*)(ap + 16);
        a += av[0]*vE[0]; a += av[1]*vE[1]; a += av[2]*vE[2]; a += av[3]*vE[3];
        av = *(const f32x4*)(ap + 20);
        a += av[0]*vF[0]; a += av[1]*vF[1]; a += av[2]*vF[2]; a += av[3]*vF[3];
        if (cq == 7) {
          av = *(const f32x4*)(ap + 24);
          a += av[0]*vG[0]; a += av[1]*vG[1]; a += av[2]*vG[2]; a += av[3]*vG[3];
        }
        a += DPPF(a, 0xB1, 0.f);
        a += DPPF(a, 0x4E, 0.f);
        a += DPPF(a, 0x141, 0.f);
        if (q8 == 0) mhal[o] = a;
      }
      __syncthreads();

      if (t < 800) {
        float a = 0.f;
        {
          f32x4 ml;
          ml = *(const f32x4*)&mhal[j4 * 32 + ((0 + j4) & 3) * 4];
          a += ml[0]*urR0[0]; a += ml[1]*urR0[1]; a += ml[2]*urR0[2]; a += ml[3]*urR0[3];
          ml = *(const f32x4*)&mhal[j4 * 32 + ((1 + j4) & 3) * 4];
          a += ml[0]*urR1[0]; a += ml[1]*urR1[1]; a += ml[2]*urR1[2]; a += ml[3]*urR1[3];
          ml = *(const f32x4*)&mhal[j4 * 32 + ((2 + j4) & 3) * 4];
          a += ml[0]*urR2[0]; a += ml[1]*urR2[1]; a += ml[2]*urR2[2]; a += ml[3]*urR2[3];
          ml = *(const f32x4*)&mhal[j4 * 32 + ((3 + j4) & 3) * 4];
          a += ml[0]*urR3[0]; a += ml[1]*urR3[1]; a += ml[2]*urR3[2]; a += ml[3]*urR3[3];
        }
        const int ubase = m4 * 64;
        #pragma unroll
        for (int c = 0; c < 4; ++c) {
          int ci = (c + j4) & 3;
          f32x4 mh = *(const f32x4*)&mhal[j4 * 32 + 16 + ci * 4];
          f32x4 uu = *(const f32x4*)&ul[ubase + ((j4 * 16 + ci * 4 + 4 * m4) & 63)];
          a += mh[0]*uu[0]; a += mh[1]*uu[1]; a += mh[2]*uu[2]; a += mh[3]*uu[3];
        }
        a += DPPF(a, 0xB1, 0.f);
        a += DPPF(a, 0x4E, 0.f);
        if (j4 == 0) {
          float l = 10.f * tanhf(a / 11.313708498984761f);
          lg[m4] = cm ? NEGV : l;
        }
      }
      __syncthreads();

      if (wave < 8) {
        float lv[4];
        float mx = -INFINITY;
        #pragma unroll
        for (int k = 0; k < 4; ++k) {
          int n = lane + 64 * k;
          lv[k] = (n < 200) ? lg[n] : -INFINITY;
          mx = fmaxf(mx, lv[k]);
        }
        float vmax = wave_max(mx);
        int bidx = -1;
        #pragma unroll
        for (int k = 0; k < 4; ++k) {
          unsigned long long bm =
              __ballot((lane + 64 * k < 200) && (lv[k] == vmax));
          if (bidx < 0 && bm != 0ull) bidx = k * 64 + (int)__builtin_ctzll(bm);
        }
        int nxt = live ? bidx : 0;
        if (t < 128) qv[t] = outb[(long)nxt * 512 + 384 + t];
        float e = 0.f;
        #pragma unroll
        for (int k = 0; k < 4; ++k) e += expf(lv[k] - vmax);
        float se_ = wave_sum(e);
        float lse = logf(se_);
        if (t == 0) {
          chose = live ? (-lse) : ((lv[0] - vmax) - lse);
          out[2048 + (long)b * 200 + st] = (float)nxt;
          bci = nxt;
        }
      }
      __syncthreads();

      int nxt = bci;
      if (!live) {
        if (t == 0) llsum += chose * (float)(200 - st);
        for (int s2 = st + 1 + t; s2 < 200; s2 += 1024)
          out[2048 + (long)b * 200 + s2] = 0.f;
        break;
      }
      if (t == 0) llsum += chose;
      if (wave < 8 && (nxt & 63) == lane) mk |= 1 << (nxt >> 6);
      if (t < 800 && nxt == m4) cm = true;
      if (nxt == 0) { live = false; picked0 = true; }
    }

    if (t == 0) out[1536 + b] = picked0 ? llsum : 0.f;
    if (t < 800 && j4 == 0) {
      float s = (m4 == 0) ? 1.f : ((picked0 && cm) ? 1.f : 0.f);
      sol[(long)b * 200 + m4] = s;
    }
    __syncthreads();
  }
}

// ---------------- cost ----------------
__global__ __launch_bounds__(256)
void cost_kernel(const float* __restrict__ x, const float* __restrict__ rf,
                 const float* __restrict__ sol, float* __restrict__ out) {
  __shared__ float solL[256];
  __shared__ float red[8];
  const int b = blockIdx.x, t = threadIdx.x;
  solL[t] = (t < 200) ? sol[b * 200 + t] : 0.f;
  __syncthreads();
  const float* x0 = x + (long)b * 40000;
  const float* x1 = x + 20480000l + (long)b * 40000;
  float a1 = 0.f, a2 = 0.f;
  if (t < 200) {
    for (int i = 0; i < 200; ++i) {
      if (solL[i] != 0.f) {
        a1 += x0[i * 200 + t];
        a2 += x1[i * 200 + t];
      }
    }
    float w = solL[t];
    a1 *= w; a2 *= w;
  }
  #pragma unroll
  for (int off = 32; off > 0; off >>= 1) {
    a1 += __shfl_xor(a1, off);
    a2 += __shfl_xor(a2, off);
  }
  if ((t & 63) == 0) { red[(t >> 6) * 2] = a1; red[(t >> 6) * 2 + 1] = a2; }
  __syncthreads();
  if (t == 0) {
    float f1 = red[0] + red[2] + red[4] + red[6];
    float f2 = red[1] + red[3] + red[5] + red[7];
    out[b]        = -(f1 * rf[0] + f2 * rf[1]);
    out[512 + b]  = f1;
    out[1024 + b] = f2;
  }
}

extern "C" void kernel_launch(void* const* d_in, const int* in_sizes, int n_in,
                              void* d_out, int out_size, void* d_ws, size_t ws_size,
                              hipStream_t stream) {
  const float* x     = (const float*)d_in[0];
  const float* rf    = (const float*)d_in[1];
  const float* emb   = (const float*)d_in[2];
  const float* Wk1   = (const float*)d_in[4];
  const float* bk1   = (const float*)d_in[5];
  const float* Wv    = (const float*)d_in[6];
  const float* Wk2   = (const float*)d_in[7];
  const float* Wout  = (const float*)d_in[8];
  const float* Wq    = (const float*)d_in[9];
  const float* initn = (const float*)d_in[10];
  float* out = (float*)d_out;
  float* ws  = (float*)d_ws;

  if (ws_size < (size_t)WS_FLOATS * 4) return;

  float* OUTb = ws + OUT_F;
  float* Mb   = ws + M_F;
  float* QRb  = ws + QR_F;   // dead after gemm; first 4 bytes reused as counter
  float* QIb  = ws + QI_F;
  float* solb = ws + SOL_F;

  build_M<<<256, 256, 0, stream>>>(Wk1, Wv, Wk2, Wout, Wq, Mb);
  build_Q<<<256, 256, 0, stream>>>(rf, Wq, initn, QRb, QIb);
  gemm_static<<<12800, 256, 0, stream>>>(emb, Mb, bk1, QRb, OUTb);
  init_ctr<<<1, 1, 0, stream>>>((int*)QRb);

  // Use the all-register decode512 only if the allocator granted a big file;
  // otherwise it would spill 180 floats/thread (round-4 disaster) -> fallback.
  hipFuncAttributes fa;
  bool big = false;
  if (hipFuncGetAttributes(&fa, (const void*)decode512) == hipSuccess)
    big = (fa.numRegs >= 160);
  if (big)
    decode512<<<256, 512, 0, stream>>>(OUTb, QIb, (int*)QRb, solb, out);
  else
    decode<<<256, 1024, 0, stream>>>(OUTb, QIb, (int*)QRb, solb, out);

  cost_kernel<<<512, 256, 0, stream>>>(x, rf, solb, out);
}

// Round 14
// 1392.745 us; speedup vs baseline: 1.4065x; 1.0237x over previous
//
#include <hip/hip_runtime.h>
#include <math.h>

#define NEGV (-1e9f)

// ws layout (float offsets):
//   OUT [B*N][512] : cols 0..127 K1, 128..255 V, 256..383 U=K2@Wout,
//                    384..511 Qfull = QR + emb@Wq[:,2:]^T  (QR folded in GEMM)
//   M   [128][512], QR [B][128] (dead after gemm -> reused as work counter),
//   QI  [B][128], SOL [B][200]
#define OUT_F   0l
#define M_F     52428800l
#define QR_F    (M_F + 65536l)
#define QI_F    (QR_F + 65536l)
#define SOL_F   (QI_F + 65536l)
#define WS_FLOATS (SOL_F + 102400l)   // ~211 MB (known OK)

typedef float f32x4 __attribute__((ext_vector_type(4)));

// ---------------- DPP cross-lane helpers ----------------
#define DPPF(x, ctrl, oldv) __int_as_float(__builtin_amdgcn_update_dpp( \
      __float_as_int(oldv), __float_as_int(x), ctrl, 0xF, 0xF, false))

__device__ __forceinline__ float wave_max(float x) {
  x = fmaxf(x, DPPF(x, 0x111, -INFINITY));
  x = fmaxf(x, DPPF(x, 0x112, -INFINITY));
  x = fmaxf(x, DPPF(x, 0x114, -INFINITY));
  x = fmaxf(x, DPPF(x, 0x118, -INFINITY));
  x = fmaxf(x, DPPF(x, 0x142, -INFINITY));
  x = fmaxf(x, DPPF(x, 0x143, -INFINITY));
  return __int_as_float(__builtin_amdgcn_readlane(__float_as_int(x), 63));
}
__device__ __forceinline__ float wave_sum(float x) {
  x = x + DPPF(x, 0x111, 0.f);
  x = x + DPPF(x, 0x112, 0.f);
  x = x + DPPF(x, 0x114, 0.f);
  x = x + DPPF(x, 0x118, 0.f);
  x = x + DPPF(x, 0x142, 0.f);
  x = x + DPPF(x, 0x143, 0.f);
  return __int_as_float(__builtin_amdgcn_readlane(__float_as_int(x), 63));
}

// ---------------- static precompute ----------------
__global__ __launch_bounds__(256)
void build_M(const float* __restrict__ Wk1, const float* __restrict__ Wv,
             const float* __restrict__ Wk2, const float* __restrict__ Wout,
             const float* __restrict__ Wq, float* __restrict__ Mbuf) {
  int g = blockIdx.x * 256 + threadIdx.x;
  int j = g >> 9, c = g & 511;
  float val;
  if (c < 128) {
    val = Wk1[c * 128 + j];
  } else if (c < 256) {
    val = Wv[(c - 128) * 128 + j];
  } else if (c < 384) {
    int d = c - 256;
    float s = 0.f;
    for (int e = 0; e < 128; ++e) s += Wk2[e * 128 + j] * Wout[e * 128 + d];
    val = s;
  } else {
    val = Wq[(c - 384) * 130 + 2 + j];
  }
  Mbuf[j * 512 + c] = val;
}

__global__ __launch_bounds__(256)
void build_Q(const float* __restrict__ rf, const float* __restrict__ Wq,
             const float* __restrict__ initn, float* __restrict__ QR,
             float* __restrict__ QI) {
  int g = blockIdx.x * 256 + threadIdx.x;   // 65536 = 512*128
  int b = g >> 7, d = g & 127;
  float qr = Wq[d * 130 + 0] * rf[b * 2 + 0] + Wq[d * 130 + 1] * rf[b * 2 + 1];
  float qi = qr;
  for (int j = 0; j < 128; ++j) qi += Wq[d * 130 + 2 + j] * initn[j];
  QR[g] = qr;
  QI[g] = qi;
}

__global__ __launch_bounds__(256)
void gemm_static(const float* __restrict__ emb, const float* __restrict__ Mbuf,
                 const float* __restrict__ bk1, const float* __restrict__ QR,
                 float* __restrict__ OUT) {
  int bid = blockIdx.x;                 // 1600 row-tiles * 8 col-tiles
  int rt = bid >> 3, ct = bid & 7;
  int r0 = rt * 64, c0 = ct * 64;
  int t = threadIdx.x, ty = t >> 4, tx = t & 15;
  int row0 = r0 + ty * 4;
  int col  = c0 + tx * 4;
  float acc[4][4] = {};
  const float* mp = Mbuf + col;
  for (int kb = 0; kb < 32; ++kb) {
    int k = kb * 4;
    float4 b0 = *(const float4*)(mp + (long)(k + 0) * 512);
    float4 b1 = *(const float4*)(mp + (long)(k + 1) * 512);
    float4 b2 = *(const float4*)(mp + (long)(k + 2) * 512);
    float4 b3 = *(const float4*)(mp + (long)(k + 3) * 512);
    float bm[4][4] = {{b0.x,b0.y,b0.z,b0.w},{b1.x,b1.y,b1.z,b1.w},
                      {b2.x,b2.y,b2.z,b2.w},{b3.x,b3.y,b3.z,b3.w}};
    #pragma unroll
    for (int rr = 0; rr < 4; ++rr) {
      float4 a4 = *(const float4*)(emb + (long)(row0 + rr) * 128 + k);
      float av[4] = {a4.x, a4.y, a4.z, a4.w};
      #pragma unroll
      for (int i = 0; i < 4; ++i)
        #pragma unroll
        for (int cc = 0; cc < 4; ++cc)
          acc[rr][cc] += av[i] * bm[i][cc];
    }
  }
  float badd[4] = {0.f, 0.f, 0.f, 0.f};
  if (c0 < 128) {
    #pragma unroll
    for (int cc = 0; cc < 4; ++cc) badd[cc] = bk1[col + cc];
  }
  #pragma unroll
  for (int rr = 0; rr < 4; ++rr) {
    int row = row0 + rr;
    float v[4];
    #pragma unroll
    for (int cc = 0; cc < 4; ++cc) v[cc] = acc[rr][cc] + badd[cc];
    if (col >= 384) {
      int bb = row / 200;
      #pragma unroll
      for (int cc = 0; cc < 4; ++cc) v[cc] += QR[bb * 128 + (col - 384) + cc];
    }
    float4 v4; v4.x = v[0]; v4.y = v[1]; v4.z = v[2]; v4.w = v[3];
    *(float4*)(OUT + (long)row * 512 + col) = v4;
  }
}

__global__ void init_ctr(int* __restrict__ c) { *c = 0; }

// ---------------- decode512: register K1/U/V + LDS-resident Q rows ----------------
// t<400: (n = t>>1, half = t&1) owns K1/U row-halves in regs; all t: (o,r4)
// owns a quad-aligned V slice. All 201 q-rows cached in LDS at claim setup:
// no per-step global loads on the critical path.
__global__ __attribute__((amdgpu_flat_work_group_size(512, 512), amdgpu_waves_per_eu(2, 2)))
void decode512(const float* __restrict__ OUT, const float* __restrict__ QI,
               int* __restrict__ ctr, float* __restrict__ sol,
               float* __restrict__ out) {
  __shared__ __align__(16) float qall[201 * 128];  // q rows (+row 200 = QI), 103 KB
  __shared__ float sc[1600];                       // scores -> attn [h][200]
  __shared__ __align__(16) float mhal[128];
  __shared__ float lg[200];
  __shared__ int bci, bsel;

  const int t = threadIdx.x;
  const int lane = t & 63, wave = t >> 6;
  const int o = t >> 2, r4 = t & 3;
  const int mn = t >> 1, half = t & 1;
  const int vst  = (r4 == 0) ? 0 : (r4 == 1 ? 48 : (r4 == 2 ? 100 : 152));
  const bool mid = (r4 == 1) || (r4 == 2);     // 52-row slices

  float kreg[64], ureg[64], vreg[52];

  for (;;) {
    if (t == 0) bsel = atomicAdd(ctr, 1);
    __syncthreads();
    const int b = bsel;
    if (b >= 512) break;
    const float* outb = OUT + (long)b * 200 * 512;

    // q rows -> LDS (row 200 = QI)
    for (int f = t; f < 25728; f += 512) {
      int row = f >> 7, d = f & 127;
      qall[f] = (row < 200) ? outb[row * 512 + 384 + d] : QI[b * 128 + d];
    }
    // K1, U rows -> regs (t < 400)
    if (t < 400) {
      const float* kp = outb + mn * 512 + 64 * half;
      const float* up = outb + mn * 512 + 256 + 64 * half;
      #pragma unroll
      for (int c = 0; c < 16; ++c)
        *(f32x4*)&kreg[c * 4] = *(const f32x4*)(kp + c * 4);
      #pragma unroll
      for (int c = 0; c < 16; ++c)
        *(f32x4*)&ureg[c * 4] = *(const f32x4*)(up + c * 4);
    }
    // V slice -> regs (all t)
    {
      const float* vp = outb + 128 + o;
      #pragma unroll
      for (int i = 0; i < 48; ++i) vreg[i] = vp[(vst + i) * 512];
      vreg[48] = mid ? vp[(vst + 48) * 512] : 0.f;
      vreg[49] = mid ? vp[(vst + 49) * 512] : 0.f;
      vreg[50] = mid ? vp[(vst + 50) * 512] : 0.f;
      vreg[51] = mid ? vp[(vst + 51) * 512] : 0.f;
    }

    int cur = 200;      // q row index (200 = step-0 / QI row)
    bool cmb = false;   // node mn visited (t < 400)
    bool live = true, picked0 = false;
    float llsum = 0.f, chose = 0.f;

    __syncthreads();

    for (int st = 0; st < 200; ++st) {
      // ---- A1: scores from registers (owner thread = (n, half)) ----
      if (t < 400) {
        const float* qb = qall + cur * 128 + 64 * half;
        #pragma unroll
        for (int hh = 0; hh < 4; ++hh) {
          float s = 0.f;
          #pragma unroll
          for (int c = 0; c < 4; ++c) {
            f32x4 q4 = *(const f32x4*)(qb + hh * 16 + c * 4);
            s += q4[0] * kreg[hh * 16 + c * 4 + 0];
            s += q4[1] * kreg[hh * 16 + c * 4 + 1];
            s += q4[2] * kreg[hh * 16 + c * 4 + 2];
            s += q4[3] * kreg[hh * 16 + c * 4 + 3];
          }
          sc[(4 * half + hh) * 200 + mn] = cmb ? NEGV : s * 0.25f;
        }
      }
      __syncthreads();

      // ---- A2: softmax per head (wave h), in place ----
      {
        float sv[4];
        float mx = -INFINITY;
        #pragma unroll
        for (int k = 0; k < 4; ++k) {
          int n = lane + 64 * k;
          float s = (n < 200) ? sc[wave * 200 + n] : -INFINITY;
          sv[k] = s;
          mx = fmaxf(mx, s);
        }
        float vmax = wave_max(mx);
        float ls = 0.f;
        #pragma unroll
        for (int k = 0; k < 4; ++k) { sv[k] = expf(sv[k] - vmax); ls += sv[k]; }
        ls = wave_sum(ls);
        #pragma unroll
        for (int k = 0; k < 4; ++k) {
          int n = lane + 64 * k;
          if (n < 200) sc[wave * 200 + n] = sv[k] / ls;
        }
      }
      __syncthreads();

      // ---- B: mha[o] = sum_n attn[h][n] * V[n][o]  (h = wave, 4 accs) ----
      {
        const float* ap = sc + wave * 200 + vst;
        float ac[4] = {0.f, 0.f, 0.f, 0.f};
        #pragma unroll
        for (int c = 0; c < 12; ++c) {
          f32x4 av = *(const f32x4*)(ap + c * 4);
          float s = av[0] * vreg[c * 4 + 0];
          s += av[1] * vreg[c * 4 + 1];
          s += av[2] * vreg[c * 4 + 2];
          s += av[3] * vreg[c * 4 + 3];
          ac[c & 3] += s;
        }
        if (mid) {
          f32x4 av = *(const f32x4*)(ap + 48);
          float s = av[0] * vreg[48];
          s += av[1] * vreg[49]; s += av[2] * vreg[50]; s += av[3] * vreg[51];
          ac[0] += s;
        }
        float a = (ac[0] + ac[1]) + (ac[2] + ac[3]);
        a += DPPF(a, 0xB1, 0.f);
        a += DPPF(a, 0x4E, 0.f);
        if (r4 == 0) mhal[o] = a;
      }
      __syncthreads();

      // ---- C: logits[m] = 10*tanh((mha . U[m]) / sqrt(128))  (4 accs) ----
      if (t < 400) {
        float ac[4] = {0.f, 0.f, 0.f, 0.f};
        #pragma unroll
        for (int c = 0; c < 16; ++c) {
          f32x4 mh = *(const f32x4*)&mhal[64 * half + c * 4];
          float s = mh[0] * ureg[c * 4 + 0];
          s += mh[1] * ureg[c * 4 + 1];
          s += mh[2] * ureg[c * 4 + 2];
          s += mh[3] * ureg[c * 4 + 3];
          ac[c & 3] += s;
        }
        float a = (ac[0] + ac[1]) + (ac[2] + ac[3]);
        a += DPPF(a, 0xB1, 0.f);   // (half 0) + (half 1)
        if (half == 0) {
          float l = 10.f * tanhf(a / 11.313708498984761f);
          lg[mn] = cmb ? NEGV : l;
        }
      }
      __syncthreads();

      // ---- D: argmax + lse (all LDS/reg, no global on path) ----
      {
        float lv[4];
        float mx = -INFINITY;
        #pragma unroll
        for (int k = 0; k < 4; ++k) {
          int n = lane + 64 * k;
          lv[k] = (n < 200) ? lg[n] : -INFINITY;
          mx = fmaxf(mx, lv[k]);
        }
        float vmax = wave_max(mx);
        int bidx = -1;
        #pragma unroll
        for (int k = 0; k < 4; ++k) {
          unsigned long long bm =
              __ballot((lane + 64 * k < 200) && (lv[k] == vmax));
          if (bidx < 0 && bm != 0ull) bidx = k * 64 + (int)__builtin_ctzll(bm);
        }
        int nxt = live ? bidx : 0;
        float e = 0.f;
        #pragma unroll
        for (int k = 0; k < 4; ++k) e += expf(lv[k] - vmax);
        float se_ = wave_sum(e);
        float lse = logf(se_);
        if (t == 0) {
          chose = live ? (-lse) : ((lv[0] - vmax) - lse);
          out[2048 + (long)b * 200 + st] = (float)nxt;
          bci = nxt;
        }
      }
      __syncthreads();

      int nxt = bci;
      if (!live) {
        if (t == 0) llsum += chose * (float)(200 - st);
        for (int s2 = st + 1 + t; s2 < 200; s2 += 512)
          out[2048 + (long)b * 200 + s2] = 0.f;
        break;
      }
      if (t == 0) llsum += chose;
      if (t < 400 && nxt == mn) cmb = true;
      cur = nxt;
      if (nxt == 0) { live = false; picked0 = true; }
    }

    if (t == 0) out[1536 + b] = picked0 ? llsum : 0.f;
    if (t < 400 && half == 0) {
      float s = (mn == 0) ? 1.f : ((picked0 && cmb) ? 1.f : 0.f);
      sol[(long)b * 200 + mn] = s;
    }
    __syncthreads();   // protect LDS reuse before next grab
  }
}

// ---------------- decode (round-12 fallback, unchanged) ----------------
__global__ __attribute__((amdgpu_flat_work_group_size(1024, 1024)))
void decode(const float* __restrict__ OUT, const float* __restrict__ QI,
            int* __restrict__ ctr, float* __restrict__ sol,
            float* __restrict__ out) {
  __shared__ __align__(16) float k1r[25600];   // [n][128] rot-4n, 102.4 KB
  __shared__ __align__(16) float at[1600];     // attn [h][200]  6.4 KB
  __shared__ __align__(16) float mhal[128];
  __shared__ float lg[200];
  __shared__ __align__(16) float qv[128];
  __shared__ __align__(16) float ul[12800];    // U-high [m][64] rot-4m, 51.2 KB
  __shared__ int   bci;
  __shared__ int   bsel;

  const int t = threadIdx.x;
  const int lane = t & 63, wave = t >> 6;
  const int o = t >> 3, q8 = t & 7;
  const int m4 = t >> 2, j4 = t & 3;
  const int stq = (q8 * 25) & ~3;
  const int cq  = ((((q8 + 1) * 25) & ~3) - stq) >> 2;   // 6 or 7 quads

  for (;;) {
    if (t == 0) bsel = atomicAdd(ctr, 1);
    __syncthreads();
    const int b = bsel;
    if (b >= 512) break;
    const float* outb = OUT + (long)b * 200 * 512;

    for (int p = 0; p < 25; ++p) {
      int f = p * 1024 + t;
      int n = f >> 7, d = f & 127;
      k1r[n * 128 + ((d + 4 * n) & 127)] = outb[n * 512 + d];
    }
    for (int f = t; f < 12800; f += 1024) {
      int m = f >> 6, c = f & 63;
      ul[m * 64 + ((c + 4 * m) & 63)] =
          outb[m * 512 + 256 + (c >> 4) * 32 + 16 + (c & 15)];
    }
    f32x4 vA = {}, vB = {}, vC = {}, vD = {}, vE = {}, vF = {}, vG = {};
    {
      const float* vp = outb + 128 + o;
      #pragma unroll
      for (int e = 0; e < 4; ++e) vA[e] = vp[(stq + 0 + e) * 512];
      #pragma unroll
      for (int e = 0; e < 4; ++e) vB[e] = vp[(stq + 4 + e) * 512];
      #pragma unroll
      for (int e = 0; e < 4; ++e) vC[e] = vp[(stq + 8 + e) * 512];
      #pragma unroll
      for (int e = 0; e < 4; ++e) vD[e] = vp[(stq + 12 + e) * 512];
      #pragma unroll
      for (int e = 0; e < 4; ++e) vE[e] = vp[(stq + 16 + e) * 512];
      #pragma unroll
      for (int e = 0; e < 4; ++e) vF[e] = vp[(stq + 20 + e) * 512];
      if (cq == 7) {
        #pragma unroll
        for (int e = 0; e < 4; ++e) vG[e] = vp[(stq + 24 + e) * 512];
      }
    }
    f32x4 urR0 = {}, urR1 = {}, urR2 = {}, urR3 = {};
    if (t < 800) {
      const float* up = outb + m4 * 512 + 256 + j4 * 32;
      urR0 = *(const f32x4*)(up + 4 * ((0 + j4) & 3));
      urR1 = *(const f32x4*)(up + 4 * ((1 + j4) & 3));
      urR2 = *(const f32x4*)(up + 4 * ((2 + j4) & 3));
      urR3 = *(const f32x4*)(up + 4 * ((3 + j4) & 3));
    }
    if (t < 128) qv[t] = QI[b * 128 + t];

    int mk = 0;
    bool cm = false;
    bool live = true, picked0 = false;
    float llsum = 0.f, chose = 0.f;

    __syncthreads();

    for (int st = 0; st < 200; ++st) {
      if (wave < 8) {
        const int hb = wave * 16;
        float acc[4] = {};
        #pragma unroll
        for (int hf = 0; hf < 2; ++hf) {
          f32x4 qa = *(const f32x4*)&qv[hb + hf * 8];
          f32x4 qb2 = *(const f32x4*)&qv[hb + hf * 8 + 4];
          #pragma unroll
          for (int k = 0; k < 4; ++k) {
            int n = lane + 64 * k;
            if (n < 200) {
              const float* kb = k1r + n * 128;
              int off  = (hb + hf * 8 + 4 * n) & 127;
              int off2 = (hb + hf * 8 + 4 + 4 * n) & 127;
              f32x4 kA = *(const f32x4*)(kb + off);
              f32x4 kB = *(const f32x4*)(kb + off2);
              float ah = qa[0] * kA[0];
              ah += qa[1] * kA[1]; ah += qa[2] * kA[2]; ah += qa[3] * kA[3];
              ah += qb2[0] * kB[0]; ah += qb2[1] * kB[1];
              ah += qb2[2] * kB[2]; ah += qb2[3] * kB[3];
              acc[k] += ah;
            }
          }
        }
        float sv[4];
        float mx = -INFINITY;
        #pragma unroll
        for (int k = 0; k < 4; ++k) {
          int n = lane + 64 * k;
          float s = -INFINITY;
          if (n < 200) {
            s = acc[k] * 0.25f;
            if (mk & (1 << k)) s = NEGV;
          }
          sv[k] = s;
          mx = fmaxf(mx, s);
        }
        float vmax = wave_max(mx);
        float ls = 0.f;
        #pragma unroll
        for (int k = 0; k < 4; ++k) { sv[k] = expf(sv[k] - vmax); ls += sv[k]; }
        ls = wave_sum(ls);
        #pragma unroll
        for (int k = 0; k < 4; ++k) {
          int n = lane + 64 * k;
          if (n < 200) at[wave * 200 + n] = sv[k] / ls;
        }
      }
      __syncthreads();

      {
        const int h2 = t >> 7;
        const float* ap = at + h2 * 200 + stq;
        float a = 0.f;
        f32x4 av;
        av = *(const f32x4*)(ap + 0);
        a += av[0]*vA[0]; a += av[1]*vA[1]; a += av[2]*vA[2]; a += av[3]*vA[3];
        av = *(const f32x4*)(ap + 4);
        a += av[0]*vB[0]; a += av[1]*vB[1]; a += av[2]*vB[2]; a += av[3]*vB[3];
        av = *(const f32x4*)(ap + 8);
        a += av[0]*vC[0]; a += av[1]*vC[1]; a += av[2]*vC[2]; a += av[3]*vC[3];
        av = *(const f32x4*)(ap + 12);
        a += av[0]*vD[0]; a += av[1]*vD[1]; a += av[2]*vD[2]; a += av[3]*vD[3];
        av = *(const f32x4*)(ap + 16);
        a += av[0]*vE[0]; a += av[1]*vE[1]; a += av[2]*vE[2]; a += av[3]*vE[3];
        av = *(const f32x4*)(ap + 20);
        a += av[0]*vF[0]; a += av[1]*vF[1]; a += av[2]*vF[2]; a += av[3]*vF[3];
        if (cq == 7) {
          av = *(const f32x4*)(ap + 24);
          a += av[0]*vG[0]; a += av[1]*vG[1]; a += av[2]*vG[2]; a += av[3]*vG[3];
        }
        a += DPPF(a, 0xB1, 0.f);
        a += DPPF(a, 0x4E, 0.f);
        a += DPPF(a, 0x141, 0.f);
        if (q8 == 0) mhal[o] = a;
      }
      __syncthreads();

      if (t < 800) {
        float a = 0.f;
        {
          f32x4 ml;
          ml = *(const f32x4*)&mhal[j4 * 32 + ((0 + j4) & 3) * 4];
          a += ml[0]*urR0[0]; a += ml[1]*urR0[1]; a += ml[2]*urR0[2]; a += ml[3]*urR0[3];
          ml = *(const f32x4*)&mhal[j4 * 32 + ((1 + j4) & 3) * 4];
          a += ml[0]*urR1[0]; a += ml[1]*urR1[1]; a += ml[2]*urR1[2]; a += ml[3]*urR1[3];
          ml = *(const f32x4*)&mhal[j4 * 32 + ((2 + j4) & 3) * 4];
          a += ml[0]*urR2[0]; a += ml[1]*urR2[1]; a += ml[2]*urR2[2]; a += ml[3]*urR2[3];
          ml = *(const f32x4*)&mhal[j4 * 32 + ((3 + j4) & 3) * 4];
          a += ml[0]*urR3[0]; a += ml[1]*urR3[1]; a += ml[2]*urR3[2]; a += ml[3]*urR3[3];
        }
        const int ubase = m4 * 64;
        #pragma unroll
        for (int c = 0; c < 4; ++c) {
          int ci = (c + j4) & 3;
          f32x4 mh = *(const f32x4*)&mhal[j4 * 32 + 16 + ci * 4];
          f32x4 uu = *(const f32x4*)&ul[ubase + ((j4 * 16 + ci * 4 + 4 * m4) & 63)];
          a += mh[0]*uu[0]; a += mh[1]*uu[1]; a += mh[2]*uu[2]; a += mh[3]*uu[3];
        }
        a += DPPF(a, 0xB1, 0.f);
        a += DPPF(a, 0x4E, 0.f);
        if (j4 == 0) {
          float l = 10.f * tanhf(a / 11.313708498984761f);
          lg[m4] = cm ? NEGV : l;
        }
      }
      __syncthreads();

      if (wave < 8) {
        float lv[4];
        float mx = -INFINITY;
        #pragma unroll
        for (int k = 0; k < 4; ++k) {
          int n = lane + 64 * k;
          lv[k] = (n < 200) ? lg[n] : -INFINITY;
          mx = fmaxf(mx, lv[k]);
        }
        float vmax = wave_max(mx);
        int bidx = -1;
        #pragma unroll
        for (int k = 0; k < 4; ++k) {
          unsigned long long bm =
              __ballot((lane + 64 * k < 200) && (lv[k] == vmax));
          if (bidx < 0 && bm != 0ull) bidx = k * 64 + (int)__builtin_ctzll(bm);
        }
        int nxt = live ? bidx : 0;
        if (t < 128) qv[t] = outb[(long)nxt * 512 + 384 + t];
        float e = 0.f;
        #pragma unroll
        for (int k = 0; k < 4; ++k) e += expf(lv[k] - vmax);
        float se_ = wave_sum(e);
        float lse = logf(se_);
        if (t == 0) {
          chose = live ? (-lse) : ((lv[0] - vmax) - lse);
          out[2048 + (long)b * 200 + st] = (float)nxt;
          bci = nxt;
        }
      }
      __syncthreads();

      int nxt = bci;
      if (!live) {
        if (t == 0) llsum += chose * (float)(200 - st);
        for (int s2 = st + 1 + t; s2 < 200; s2 += 1024)
          out[2048 + (long)b * 200 + s2] = 0.f;
        break;
      }
      if (t == 0) llsum += chose;
      if (wave < 8 && (nxt & 63) == lane) mk |= 1 << (nxt >> 6);
      if (t < 800 && nxt == m4) cm = true;
      if (nxt == 0) { live = false; picked0 = true; }
    }

    if (t == 0) out[1536 + b] = picked0 ? llsum : 0.f;
    if (t < 800 && j4 == 0) {
      float s = (m4 == 0) ? 1.f : ((picked0 && cm) ? 1.f : 0.f);
      sol[(long)b * 200 + m4] = s;
    }
    __syncthreads();
  }
}

// ---------------- cost ----------------
__global__ __launch_bounds__(256)
void cost_kernel(const float* __restrict__ x, const float* __restrict__ rf,
                 const float* __restrict__ sol, float* __restrict__ out) {
  __shared__ float solL[256];
  __shared__ float red[8];
  const int b = blockIdx.x, t = threadIdx.x;
  solL[t] = (t < 200) ? sol[b * 200 + t] : 0.f;
  __syncthreads();
  const float* x0 = x + (long)b * 40000;
  const float* x1 = x + 20480000l + (long)b * 40000;
  float a1 = 0.f, a2 = 0.f;
  if (t < 200) {
    for (int i = 0; i < 200; ++i) {
      if (solL[i] != 0.f) {
        a1 += x0[i * 200 + t];
        a2 += x1[i * 200 + t];
      }
    }
    float w = solL[t];
    a1 *= w; a2 *= w;
  }
  #pragma unroll
  for (int off = 32; off > 0; off >>= 1) {
    a1 += __shfl_xor(a1, off);
    a2 += __shfl_xor(a2, off);
  }
  if ((t & 63) == 0) { red[(t >> 6) * 2] = a1; red[(t >> 6) * 2 + 1] = a2; }
  __syncthreads();
  if (t == 0) {
    float f1 = red[0] + red[2] + red[4] + red[6];
    float f2 = red[1] + red[3] + red[5] + red[7];
    out[b]        = -(f1 * rf[0] + f2 * rf[1]);
    out[512 + b]  = f1;
    out[1024 + b] = f2;
  }
}

extern "C" void kernel_launch(void* const* d_in, const int* in_sizes, int n_in,
                              void* d_out, int out_size, void* d_ws, size_t ws_size,
                              hipStream_t stream) {
  const float* x     = (const float*)d_in[0];
  const float* rf    = (const float*)d_in[1];
  const float* emb   = (const float*)d_in[2];
  const float* Wk1   = (const float*)d_in[4];
  const float* bk1   = (const float*)d_in[5];
  const float* Wv    = (const float*)d_in[6];
  const float* Wk2   = (const float*)d_in[7];
  const float* Wout  = (const float*)d_in[8];
  const float* Wq    = (const float*)d_in[9];
  const float* initn = (const float*)d_in[10];
  float* out = (float*)d_out;
  float* ws  = (float*)d_ws;

  if (ws_size < (size_t)WS_FLOATS * 4) return;

  float* OUTb = ws + OUT_F;
  float* Mb   = ws + M_F;
  float* QRb  = ws + QR_F;   // dead after gemm; first 4 bytes reused as counter
  float* QIb  = ws + QI_F;
  float* solb = ws + SOL_F;

  build_M<<<256, 256, 0, stream>>>(Wk1, Wv, Wk2, Wout, Wq, Mb);
  build_Q<<<256, 256, 0, stream>>>(rf, Wq, initn, QRb, QIb);
  gemm_static<<<12800, 256, 0, stream>>>(emb, Mb, bk1, QRb, OUTb);
  init_ctr<<<1, 1, 0, stream>>>((int*)QRb);

  // Spill detector: use the all-register decode512 only if it allocated no
  // scratch (localSizeBytes). Spilled 180-float state = round-4 disaster.
  hipFuncAttributes fa;
  bool big = false;
  if (hipFuncGetAttributes(&fa, (const void*)decode512) == hipSuccess)
    big = (fa.localSizeBytes <= 64);
  if (big)
    decode512<<<256, 512, 0, stream>>>(OUTb, QIb, (int*)QRb, solb, out);
  else
    decode<<<256, 1024, 0, stream>>>(OUTb, QIb, (int*)QRb, solb, out);

  cost_kernel<<<512, 256, 0, stream>>>(x, rf, solb, out);
}

// Round 15
// 1270.130 us; speedup vs baseline: 1.5423x; 1.0965x over previous
//
#include <hip/hip_runtime.h>
#include <math.h>

#define NEGV (-1e9f)

// ws layout (float offsets):
//   OUT [B*N][512] : cols 0..127 K1, 128..255 V, 256..383 U=K2@Wout,
//                    384..511 Qfull = QR + emb@Wq[:,2:]^T  (QR folded in GEMM)
//   M   [128][512], QR [B][128] (dead after gemm -> reused as work counter),
//   QI  [B][128], SOL [B][200]
#define OUT_F   0l
#define M_F     52428800l
#define QR_F    (M_F + 65536l)
#define QI_F    (QR_F + 65536l)
#define SOL_F   (QI_F + 65536l)
#define WS_FLOATS (SOL_F + 102400l)   // ~211 MB (known OK)

typedef float f32x4 __attribute__((ext_vector_type(4)));

// ---------------- DPP cross-lane helpers ----------------
#define DPPF(x, ctrl, oldv) __int_as_float(__builtin_amdgcn_update_dpp( \
      __float_as_int(oldv), __float_as_int(x), ctrl, 0xF, 0xF, false))

__device__ __forceinline__ float wave_max(float x) {
  x = fmaxf(x, DPPF(x, 0x111, -INFINITY));
  x = fmaxf(x, DPPF(x, 0x112, -INFINITY));
  x = fmaxf(x, DPPF(x, 0x114, -INFINITY));
  x = fmaxf(x, DPPF(x, 0x118, -INFINITY));
  x = fmaxf(x, DPPF(x, 0x142, -INFINITY));
  x = fmaxf(x, DPPF(x, 0x143, -INFINITY));
  return __int_as_float(__builtin_amdgcn_readlane(__float_as_int(x), 63));
}
__device__ __forceinline__ float wave_sum(float x) {
  x = x + DPPF(x, 0x111, 0.f);
  x = x + DPPF(x, 0x112, 0.f);
  x = x + DPPF(x, 0x114, 0.f);
  x = x + DPPF(x, 0x118, 0.f);
  x = x + DPPF(x, 0x142, 0.f);
  x = x + DPPF(x, 0x143, 0.f);
  return __int_as_float(__builtin_amdgcn_readlane(__float_as_int(x), 63));
}

// ---------------- static precompute ----------------
__global__ __launch_bounds__(256)
void build_M(const float* __restrict__ Wk1, const float* __restrict__ Wv,
             const float* __restrict__ Wk2, const float* __restrict__ Wout,
             const float* __restrict__ Wq, float* __restrict__ Mbuf) {
  int g = blockIdx.x * 256 + threadIdx.x;
  int j = g >> 9, c = g & 511;
  float val;
  if (c < 128) {
    val = Wk1[c * 128 + j];
  } else if (c < 256) {
    val = Wv[(c - 128) * 128 + j];
  } else if (c < 384) {
    int d = c - 256;
    float s = 0.f;
    for (int e = 0; e < 128; ++e) s += Wk2[e * 128 + j] * Wout[e * 128 + d];
    val = s;
  } else {
    val = Wq[(c - 384) * 130 + 2 + j];
  }
  Mbuf[j * 512 + c] = val;
}

__global__ __launch_bounds__(256)
void build_Q(const float* __restrict__ rf, const float* __restrict__ Wq,
             const float* __restrict__ initn, float* __restrict__ QR,
             float* __restrict__ QI) {
  int g = blockIdx.x * 256 + threadIdx.x;   // 65536 = 512*128
  int b = g >> 7, d = g & 127;
  float qr = Wq[d * 130 + 0] * rf[b * 2 + 0] + Wq[d * 130 + 1] * rf[b * 2 + 1];
  float qi = qr;
  for (int j = 0; j < 128; ++j) qi += Wq[d * 130 + 2 + j] * initn[j];
  QR[g] = qr;
  QI[g] = qi;
}

// XCD-aware remap: the 8 col-tile blocks sharing an A-row panel all land on
// the same XCD (bid%8 pinned), so A is fetched from L3 once per XCD.
__global__ __launch_bounds__(256)
void gemm_static(const float* __restrict__ emb, const float* __restrict__ Mbuf,
                 const float* __restrict__ bk1, const float* __restrict__ QR,
                 float* __restrict__ OUT) {
  int bid = blockIdx.x;                 // 12800
  int lo = bid & 7, hi = bid >> 3;      // hi in [0,1600)
  int rt = lo + 8 * (hi % 200);         // row-tile  [0,1600)
  int ct = hi / 200;                    // col-tile  [0,8)
  int r0 = rt * 64, c0 = ct * 64;
  int t = threadIdx.x, ty = t >> 4, tx = t & 15;
  int row0 = r0 + ty * 4;
  int col  = c0 + tx * 4;
  float acc[4][4] = {};
  const float* mp = Mbuf + col;
  for (int kb = 0; kb < 32; ++kb) {
    int k = kb * 4;
    float4 b0 = *(const float4*)(mp + (long)(k + 0) * 512);
    float4 b1 = *(const float4*)(mp + (long)(k + 1) * 512);
    float4 b2 = *(const float4*)(mp + (long)(k + 2) * 512);
    float4 b3 = *(const float4*)(mp + (long)(k + 3) * 512);
    float bm[4][4] = {{b0.x,b0.y,b0.z,b0.w},{b1.x,b1.y,b1.z,b1.w},
                      {b2.x,b2.y,b2.z,b2.w},{b3.x,b3.y,b3.z,b3.w}};
    #pragma unroll
    for (int rr = 0; rr < 4; ++rr) {
      float4 a4 = *(const float4*)(emb + (long)(row0 + rr) * 128 + k);
      float av[4] = {a4.x, a4.y, a4.z, a4.w};
      #pragma unroll
      for (int i = 0; i < 4; ++i)
        #pragma unroll
        for (int cc = 0; cc < 4; ++cc)
          acc[rr][cc] += av[i] * bm[i][cc];
    }
  }
  float badd[4] = {0.f, 0.f, 0.f, 0.f};
  if (c0 < 128) {
    #pragma unroll
    for (int cc = 0; cc < 4; ++cc) badd[cc] = bk1[col + cc];
  }
  #pragma unroll
  for (int rr = 0; rr < 4; ++rr) {
    int row = row0 + rr;
    float v[4];
    #pragma unroll
    for (int cc = 0; cc < 4; ++cc) v[cc] = acc[rr][cc] + badd[cc];
    if (col >= 384) {
      int bb = row / 200;
      #pragma unroll
      for (int cc = 0; cc < 4; ++cc) v[cc] += QR[bb * 128 + (col - 384) + cc];
    }
    float4 v4; v4.x = v[0]; v4.y = v[1]; v4.z = v[2]; v4.w = v[3];
    *(float4*)(OUT + (long)row * 512 + col) = v4;
  }
}

__global__ void init_ctr(int* __restrict__ c) { *c = 0; }

// ---------------- decode512: register K1/U/V + LDS Q rows, 4 barriers/step ----------------
// A2 (softmax, wave h = head h) and B (mha, wave h reads only attn row h) are
// fused without a barrier: per-wave DS ops execute in order, so wave-local
// LDS write->read is safe. D runs on wave 7 only (others wait at the barrier).
__global__ __attribute__((amdgpu_flat_work_group_size(512, 512), amdgpu_waves_per_eu(2, 2)))
void decode512(const float* __restrict__ OUT, const float* __restrict__ QI,
               int* __restrict__ ctr, float* __restrict__ sol,
               float* __restrict__ out) {
  __shared__ __align__(16) float qall[201 * 128];  // q rows (+row 200 = QI), 103 KB
  __shared__ float sc[1600];                       // scores -> attn [h][200]
  __shared__ __align__(16) float mhal[128];
  __shared__ float lg[200];
  __shared__ int bci, bsel;

  const int t = threadIdx.x;
  const int lane = t & 63, wave = t >> 6;
  const int o = t >> 2, r4 = t & 3;
  const int mn = t >> 1, half = t & 1;
  const int vst  = (r4 == 0) ? 0 : (r4 == 1 ? 48 : (r4 == 2 ? 100 : 152));
  const bool mid = (r4 == 1) || (r4 == 2);     // 52-row slices

  float kreg[64], ureg[64], vreg[52];

  for (;;) {
    if (t == 0) bsel = atomicAdd(ctr, 1);
    __syncthreads();
    const int b = bsel;
    if (b >= 512) break;
    const float* outb = OUT + (long)b * 200 * 512;

    // q rows -> LDS (row 200 = QI)
    for (int f = t; f < 25728; f += 512) {
      int row = f >> 7, d = f & 127;
      qall[f] = (row < 200) ? outb[row * 512 + 384 + d] : QI[b * 128 + d];
    }
    // K1, U rows -> regs (t < 400)
    if (t < 400) {
      const float* kp = outb + mn * 512 + 64 * half;
      const float* up = outb + mn * 512 + 256 + 64 * half;
      #pragma unroll
      for (int c = 0; c < 16; ++c)
        *(f32x4*)&kreg[c * 4] = *(const f32x4*)(kp + c * 4);
      #pragma unroll
      for (int c = 0; c < 16; ++c)
        *(f32x4*)&ureg[c * 4] = *(const f32x4*)(up + c * 4);
    }
    // V slice -> regs (all t)
    {
      const float* vp = outb + 128 + o;
      #pragma unroll
      for (int i = 0; i < 48; ++i) vreg[i] = vp[(vst + i) * 512];
      vreg[48] = mid ? vp[(vst + 48) * 512] : 0.f;
      vreg[49] = mid ? vp[(vst + 49) * 512] : 0.f;
      vreg[50] = mid ? vp[(vst + 50) * 512] : 0.f;
      vreg[51] = mid ? vp[(vst + 51) * 512] : 0.f;
    }

    int cur = 200;      // q row index (200 = step-0 / QI row)
    bool cmb = false;   // node mn visited (t < 400)
    bool live = true, picked0 = false;
    float llsum = 0.f, chose = 0.f;

    __syncthreads();

    for (int st = 0; st < 200; ++st) {
      // ---- A1: scores from registers (owner thread = (n, half)) ----
      if (t < 400) {
        const float* qb = qall + cur * 128 + 64 * half;
        #pragma unroll
        for (int hh = 0; hh < 4; ++hh) {
          float s = 0.f;
          #pragma unroll
          for (int c = 0; c < 4; ++c) {
            f32x4 q4 = *(const f32x4*)(qb + hh * 16 + c * 4);
            s += q4[0] * kreg[hh * 16 + c * 4 + 0];
            s += q4[1] * kreg[hh * 16 + c * 4 + 1];
            s += q4[2] * kreg[hh * 16 + c * 4 + 2];
            s += q4[3] * kreg[hh * 16 + c * 4 + 3];
          }
          sc[(4 * half + hh) * 200 + mn] = cmb ? NEGV : s * 0.25f;
        }
      }
      __syncthreads();

      // ---- A2: softmax per head (wave h), in place ----
      {
        float sv[4];
        float mx = -INFINITY;
        #pragma unroll
        for (int k = 0; k < 4; ++k) {
          int n = lane + 64 * k;
          float s = (n < 200) ? sc[wave * 200 + n] : -INFINITY;
          sv[k] = s;
          mx = fmaxf(mx, s);
        }
        float vmax = wave_max(mx);
        float ls = 0.f;
        #pragma unroll
        for (int k = 0; k < 4; ++k) { sv[k] = expf(sv[k] - vmax); ls += sv[k]; }
        ls = wave_sum(ls);
        #pragma unroll
        for (int k = 0; k < 4; ++k) {
          int n = lane + 64 * k;
          if (n < 200) sc[wave * 200 + n] = sv[k] / ls;
        }
      }
      // NO barrier: B's wave h reads only row h, written by itself (per-wave
      // DS ordering guarantees read-after-write).

      // ---- B: mha[o] = sum_n attn[h][n] * V[n][o]  (h = wave, 4 accs) ----
      {
        const float* ap = sc + wave * 200 + vst;
        float ac[4] = {0.f, 0.f, 0.f, 0.f};
        #pragma unroll
        for (int c = 0; c < 12; ++c) {
          f32x4 av = *(const f32x4*)(ap + c * 4);
          float s = av[0] * vreg[c * 4 + 0];
          s += av[1] * vreg[c * 4 + 1];
          s += av[2] * vreg[c * 4 + 2];
          s += av[3] * vreg[c * 4 + 3];
          ac[c & 3] += s;
        }
        if (mid) {
          f32x4 av = *(const f32x4*)(ap + 48);
          float s = av[0] * vreg[48];
          s += av[1] * vreg[49]; s += av[2] * vreg[50]; s += av[3] * vreg[51];
          ac[0] += s;
        }
        float a = (ac[0] + ac[1]) + (ac[2] + ac[3]);
        a += DPPF(a, 0xB1, 0.f);
        a += DPPF(a, 0x4E, 0.f);
        if (r4 == 0) mhal[o] = a;
      }
      __syncthreads();

      // ---- C: logits[m] = 10*tanh((mha . U[m]) / sqrt(128))  (4 accs) ----
      if (t < 400) {
        float ac[4] = {0.f, 0.f, 0.f, 0.f};
        #pragma unroll
        for (int c = 0; c < 16; ++c) {
          f32x4 mh = *(const f32x4*)&mhal[64 * half + c * 4];
          float s = mh[0] * ureg[c * 4 + 0];
          s += mh[1] * ureg[c * 4 + 1];
          s += mh[2] * ureg[c * 4 + 2];
          s += mh[3] * ureg[c * 4 + 3];
          ac[c & 3] += s;
        }
        float a = (ac[0] + ac[1]) + (ac[2] + ac[3]);
        a += DPPF(a, 0xB1, 0.f);   // (half 0) + (half 1)
        if (half == 0) {
          float l = 10.f * tanhf(a / 11.313708498984761f);
          lg[mn] = cmb ? NEGV : l;
        }
      }
      __syncthreads();

      // ---- D: argmax + lse (wave 7 only; others wait at barrier) ----
      if (wave == 7) {
        float lv[4];
        float mx = -INFINITY;
        #pragma unroll
        for (int k = 0; k < 4; ++k) {
          int n = lane + 64 * k;
          lv[k] = (n < 200) ? lg[n] : -INFINITY;
          mx = fmaxf(mx, lv[k]);
        }
        float vmax = wave_max(mx);
        int bidx = -1;
        #pragma unroll
        for (int k = 0; k < 4; ++k) {
          unsigned long long bm =
              __ballot((lane + 64 * k < 200) && (lv[k] == vmax));
          if (bidx < 0 && bm != 0ull) bidx = k * 64 + (int)__builtin_ctzll(bm);
        }
        int nxt = live ? bidx : 0;
        float e = 0.f;
        #pragma unroll
        for (int k = 0; k < 4; ++k) e += expf(lv[k] - vmax);
        float se_ = wave_sum(e);
        float lse = logf(se_);
        if (t == 448) {
          chose = live ? (-lse) : ((lv[0] - vmax) - lse);
          out[2048 + (long)b * 200 + st] = (float)nxt;
          bci = nxt;
        }
      }
      __syncthreads();

      int nxt = bci;
      if (!live) {
        if (t == 448) llsum += chose * (float)(200 - st);
        for (int s2 = st + 1 + t; s2 < 200; s2 += 512)
          out[2048 + (long)b * 200 + s2] = 0.f;
        break;
      }
      if (t == 448) llsum += chose;
      if (t < 400 && nxt == mn) cmb = true;
      cur = nxt;
      if (nxt == 0) { live = false; picked0 = true; }
    }

    if (t == 448) out[1536 + b] = picked0 ? llsum : 0.f;
    if (t < 400 && half == 0) {
      float s = (mn == 0) ? 1.f : ((picked0 && cmb) ? 1.f : 0.f);
      sol[(long)b * 200 + mn] = s;
    }
    __syncthreads();   // protect LDS reuse before next grab
  }
}

// ---------------- decode (round-12 fallback, unchanged) ----------------
__global__ __attribute__((amdgpu_flat_work_group_size(1024, 1024)))
void decode(const float* __restrict__ OUT, const float* __restrict__ QI,
            int* __restrict__ ctr, float* __restrict__ sol,
            float* __restrict__ out) {
  __shared__ __align__(16) float k1r[25600];   // [n][128] rot-4n, 102.4 KB
  __shared__ __align__(16) float at[1600];     // attn [h][200]  6.4 KB
  __shared__ __align__(16) float mhal[128];
  __shared__ float lg[200];
  __shared__ __align__(16) float qv[128];
  __shared__ __align__(16) float ul[12800];    // U-high [m][64] rot-4m, 51.2 KB
  __shared__ int   bci;
  __shared__ int   bsel;

  const int t = threadIdx.x;
  const int lane = t & 63, wave = t >> 6;
  const int o = t >> 3, q8 = t & 7;
  const int m4 = t >> 2, j4 = t & 3;
  const int stq = (q8 * 25) & ~3;
  const int cq  = ((((q8 + 1) * 25) & ~3) - stq) >> 2;   // 6 or 7 quads

  for (;;) {
    if (t == 0) bsel = atomicAdd(ctr, 1);
    __syncthreads();
    const int b = bsel;
    if (b >= 512) break;
    const float* outb = OUT + (long)b * 200 * 512;

    for (int p = 0; p < 25; ++p) {
      int f = p * 1024 + t;
      int n = f >> 7, d = f & 127;
      k1r[n * 128 + ((d + 4 * n) & 127)] = outb[n * 512 + d];
    }
    for (int f = t; f < 12800; f += 1024) {
      int m = f >> 6, c = f & 63;
      ul[m * 64 + ((c + 4 * m) & 63)] =
          outb[m * 512 + 256 + (c >> 4) * 32 + 16 + (c & 15)];
    }
    f32x4 vA = {}, vB = {}, vC = {}, vD = {}, vE = {}, vF = {}, vG = {};
    {
      const float* vp = outb + 128 + o;
      #pragma unroll
      for (int e = 0; e < 4; ++e) vA[e] = vp[(stq + 0 + e) * 512];
      #pragma unroll
      for (int e = 0; e < 4; ++e) vB[e] = vp[(stq + 4 + e) * 512];
      #pragma unroll
      for (int e = 0; e < 4; ++e) vC[e] = vp[(stq + 8 + e) * 512];
      #pragma unroll
      for (int e = 0; e < 4; ++e) vD[e] = vp[(stq + 12 + e) * 512];
      #pragma unroll
      for (int e = 0; e < 4; ++e) vE[e] = vp[(stq + 16 + e) * 512];
      #pragma unroll
      for (int e = 0; e < 4; ++e) vF[e] = vp[(stq + 20 + e) * 512];
      if (cq == 7) {
        #pragma unroll
        for (int e = 0; e < 4; ++e) vG[e] = vp[(stq + 24 + e) * 512];
      }
    }
    f32x4 urR0 = {}, urR1 = {}, urR2 = {}, urR3 = {};
    if (t < 800) {
      const float* up = outb + m4 * 512 + 256 + j4 * 32;
      urR0 = *(const f32x4*)(up + 4 * ((0 + j4) & 3));
      urR1 = *(const f32x4*)(up + 4 * ((1 + j4) & 3));
      urR2 = *(const f32x4*)(up + 4 * ((2 + j4) & 3));
      urR3 = *(const f32x4*)(up + 4 * ((3 + j4) & 3));
    }
    if (t < 128) qv[t] = QI[b * 128 + t];

    int mk = 0;
    bool cm = false;
    bool live = true, picked0 = false;
    float llsum = 0.f, chose = 0.f;

    __syncthreads();

    for (int st = 0; st < 200; ++st) {
      if (wave < 8) {
        const int hb = wave * 16;
        float acc[4] = {};
        #pragma unroll
        for (int hf = 0; hf < 2; ++hf) {
          f32x4 qa = *(const f32x4*)&qv[hb + hf * 8];
          f32x4 qb2 = *(const f32x4*)&qv[hb + hf * 8 + 4];
          #pragma unroll
          for (int k = 0; k < 4; ++k) {
            int n = lane + 64 * k;
            if (n < 200) {
              const float* kb = k1r + n * 128;
              int off  = (hb + hf * 8 + 4 * n) & 127;
              int off2 = (hb + hf * 8 + 4 + 4 * n) & 127;
              f32x4 kA = *(const f32x4*)(kb + off);
              f32x4 kB = *(const f32x4*)(kb + off2);
              float ah = qa[0] * kA[0];
              ah += qa[1] * kA[1]; ah += qa[2] * kA[2]; ah += qa[3] * kA[3];
              ah += qb2[0] * kB[0]; ah += qb2[1] * kB[1];
              ah += qb2[2] * kB[2]; ah += qb2[3] * kB[3];
              acc[k] += ah;
            }
          }
        }
        float sv[4];
        float mx = -INFINITY;
        #pragma unroll
        for (int k = 0; k < 4; ++k) {
          int n = lane + 64 * k;
          float s = -INFINITY;
          if (n < 200) {
            s = acc[k] * 0.25f;
            if (mk & (1 << k)) s = NEGV;
          }
          sv[k] = s;
          mx = fmaxf(mx, s);
        }
        float vmax = wave_max(mx);
        float ls = 0.f;
        #pragma unroll
        for (int k = 0; k < 4; ++k) { sv[k] = expf(sv[k] - vmax); ls += sv[k]; }
        ls = wave_sum(ls);
        #pragma unroll
        for (int k = 0; k < 4; ++k) {
          int n = lane + 64 * k;
          if (n < 200) at[wave * 200 + n] = sv[k] / ls;
        }
      }
      __syncthreads();

      {
        const int h2 = t >> 7;
        const float* ap = at + h2 * 200 + stq;
        float a = 0.f;
        f32x4 av;
        av = *(const f32x4*)(ap + 0);
        a += av[0]*vA[0]; a += av[1]*vA[1]; a += av[2]*vA[2]; a += av[3]*vA[3];
        av = *(const f32x4*)(ap + 4);
        a += av[0]*vB[0]; a += av[1]*vB[1]; a += av[2]*vB[2]; a += av[3]*vB[3];
        av = *(const f32x4*)(ap + 8);
        a += av[0]*vC[0]; a += av[1]*vC[1]; a += av[2]*vC[2]; a += av[3]*vC[3];
        av = *(const f32x4*)(ap + 12);
        a += av[0]*vD[0]; a += av[1]*vD[1]; a += av[2]*vD[2]; a += av[3]*vD[3];
        av = *(const f32x4*)(ap + 16);
        a += av[0]*vE[0]; a += av[1]*vE[1]; a += av[2]*vE[2]; a += av[3]*vE[3];
        av = *(const f32x4*)(ap + 20);
        a += av[0]*vF[0]; a += av[1]*vF[1]; a += av[2]*vF[2]; a += av[3]*vF[3];
        if (cq == 7) {
          av = *(const f32x4*)(ap + 24);
          a += av[0]*vG[0]; a += av[1]*vG[1]; a += av[2]*vG[2]; a += av[3]*vG[3];
        }
        a += DPPF(a, 0xB1, 0.f);
        a += DPPF(a, 0x4E, 0.f);
        a += DPPF(a, 0x141, 0.f);
        if (q8 == 0) mhal[o] = a;
      }
      __syncthreads();

      if (t < 800) {
        float a = 0.f;
        {
          f32x4 ml;
          ml = *(const f32x4*)&mhal[j4 * 32 + ((0 + j4) & 3) * 4];
          a += ml[0]*urR0[0]; a += ml[1]*urR0[1]; a += ml[2]*urR0[2]; a += ml[3]*urR0[3];
          ml = *(const f32x4*)&mhal[j4 * 32 + ((1 + j4) & 3) * 4];
          a += ml[0]*urR1[0]; a += ml[1]*urR1[1]; a += ml[2]*urR1[2]; a += ml[3]*urR1[3];
          ml = *(const f32x4*)&mhal[j4 * 32 + ((2 + j4) & 3) * 4];
          a += ml[0]*urR2[0]; a += ml[1]*urR2[1]; a += ml[2]*urR2[2]; a += ml[3]*urR2[3];
          ml = *(const f32x4*)&mhal[j4 * 32 + ((3 + j4) & 3) * 4];
          a += ml[0]*urR3[0]; a += ml[1]*urR3[1]; a += ml[2]*urR3[2]; a += ml[3]*urR3[3];
        }
        const int ubase = m4 * 64;
        #pragma unroll
        for (int c = 0; c < 4; ++c) {
          int ci = (c + j4) & 3;
          f32x4 mh = *(const f32x4*)&mhal[j4 * 32 + 16 + ci * 4];
          f32x4 uu = *(const f32x4*)&ul[ubase + ((j4 * 16 + ci * 4 + 4 * m4) & 63)];
          a += mh[0]*uu[0]; a += mh[1]*uu[1]; a += mh[2]*uu[2]; a += mh[3]*uu[3];
        }
        a += DPPF(a, 0xB1, 0.f);
        a += DPPF(a, 0x4E, 0.f);
        if (j4 == 0) {
          float l = 10.f * tanhf(a / 11.313708498984761f);
          lg[m4] = cm ? NEGV : l;
        }
      }
      __syncthreads();

      if (wave < 8) {
        float lv[4];
        float mx = -INFINITY;
        #pragma unroll
        for (int k = 0; k < 4; ++k) {
          int n = lane + 64 * k;
          lv[k] = (n < 200) ? lg[n] : -INFINITY;
          mx = fmaxf(mx, lv[k]);
        }
        float vmax = wave_max(mx);
        int bidx = -1;
        #pragma unroll
        for (int k = 0; k < 4; ++k) {
          unsigned long long bm =
              __ballot((lane + 64 * k < 200) && (lv[k] == vmax));
          if (bidx < 0 && bm != 0ull) bidx = k * 64 + (int)__builtin_ctzll(bm);
        }
        int nxt = live ? bidx : 0;
        if (t < 128) qv[t] = outb[(long)nxt * 512 + 384 + t];
        float e = 0.f;
        #pragma unroll
        for (int k = 0; k < 4; ++k) e += expf(lv[k] - vmax);
        float se_ = wave_sum(e);
        float lse = logf(se_);
        if (t == 0) {
          chose = live ? (-lse) : ((lv[0] - vmax) - lse);
          out[2048 + (long)b * 200 + st] = (float)nxt;
          bci = nxt;
        }
      }
      __syncthreads();

      int nxt = bci;
      if (!live) {
        if (t == 0) llsum += chose * (float)(200 - st);
        for (int s2 = st + 1 + t; s2 < 200; s2 += 1024)
          out[2048 + (long)b * 200 + s2] = 0.f;
        break;
      }
      if (t == 0) llsum += chose;
      if (wave < 8 && (nxt & 63) == lane) mk |= 1 << (nxt >> 6);
      if (t < 800 && nxt == m4) cm = true;
      if (nxt == 0) { live = false; picked0 = true; }
    }

    if (t == 0) out[1536 + b] = picked0 ? llsum : 0.f;
    if (t < 800 && j4 == 0) {
      float s = (m4 == 0) ? 1.f : ((picked0 && cm) ? 1.f : 0.f);
      sol[(long)b * 200 + m4] = s;
    }
    __syncthreads();
  }
}

// ---------------- cost: predicated (branch-free, pipelined loads) ----------------
__global__ __launch_bounds__(256)
void cost_kernel(const float* __restrict__ x, const float* __restrict__ rf,
                 const float* __restrict__ sol, float* __restrict__ out) {
  __shared__ float solL[256];
  __shared__ float red[8];
  const int b = blockIdx.x, t = threadIdx.x;
  solL[t] = (t < 200) ? sol[b * 200 + t] : 0.f;
  __syncthreads();
  const float* x0 = x + (long)b * 40000;
  const float* x1 = x + 20480000l + (long)b * 40000;
  float a1 = 0.f, a2 = 0.f;
  if (t < 200) {
    #pragma unroll 4
    for (int i = 0; i < 200; ++i) {
      float w2 = solL[i];
      a1 += x0[i * 200 + t] * w2;   // w2 in {0,1}: x*1 exact, x*0 adds +-0
      a2 += x1[i * 200 + t] * w2;
    }
    float w = solL[t];
    a1 *= w; a2 *= w;
  }
  #pragma unroll
  for (int off = 32; off > 0; off >>= 1) {
    a1 += __shfl_xor(a1, off);
    a2 += __shfl_xor(a2, off);
  }
  if ((t & 63) == 0) { red[(t >> 6) * 2] = a1; red[(t >> 6) * 2 + 1] = a2; }
  __syncthreads();
  if (t == 0) {
    float f1 = red[0] + red[2] + red[4] + red[6];
    float f2 = red[1] + red[3] + red[5] + red[7];
    out[b]        = -(f1 * rf[0] + f2 * rf[1]);
    out[512 + b]  = f1;
    out[1024 + b] = f2;
  }
}

extern "C" void kernel_launch(void* const* d_in, const int* in_sizes, int n_in,
                              void* d_out, int out_size, void* d_ws, size_t ws_size,
                              hipStream_t stream) {
  const float* x     = (const float*)d_in[0];
  const float* rf    = (const float*)d_in[1];
  const float* emb   = (const float*)d_in[2];
  const float* Wk1   = (const float*)d_in[4];
  const float* bk1   = (const float*)d_in[5];
  const float* Wv    = (const float*)d_in[6];
  const float* Wk2   = (const float*)d_in[7];
  const float* Wout  = (const float*)d_in[8];
  const float* Wq    = (const float*)d_in[9];
  const float* initn = (const float*)d_in[10];
  float* out = (float*)d_out;
  float* ws  = (float*)d_ws;

  if (ws_size < (size_t)WS_FLOATS * 4) return;

  float* OUTb = ws + OUT_F;
  float* Mb   = ws + M_F;
  float* QRb  = ws + QR_F;   // dead after gemm; first 4 bytes reused as counter
  float* QIb  = ws + QI_F;
  float* solb = ws + SOL_F;

  build_M<<<256, 256, 0, stream>>>(Wk1, Wv, Wk2, Wout, Wq, Mb);
  build_Q<<<256, 256, 0, stream>>>(rf, Wq, initn, QRb, QIb);
  gemm_static<<<12800, 256, 0, stream>>>(emb, Mb, bk1, QRb, OUTb);
  init_ctr<<<1, 1, 0, stream>>>((int*)QRb);

  // Spill detector: use the all-register decode512 only if it allocated no
  // scratch (localSizeBytes). Spilled 180-float state = round-4 disaster.
  hipFuncAttributes fa;
  bool big = false;
  if (hipFuncGetAttributes(&fa, (const void*)decode512) == hipSuccess)
    big = (fa.localSizeBytes <= 64);
  if (big)
    decode512<<<256, 512, 0, stream>>>(OUTb, QIb, (int*)QRb, solb, out);
  else
    decode<<<256, 1024, 0, stream>>>(OUTb, QIb, (int*)QRb, solb, out);

  cost_kernel<<<512, 256, 0, stream>>>(x, rf, solb, out);
}

// Round 16
// 1215.382 us; speedup vs baseline: 1.6118x; 1.0450x over previous
//
#include <hip/hip_runtime.h>
#include <math.h>

#define NEGV (-1e9f)

// ws layout (float offsets):
//   OUT [B*N][512] : cols 0..127 K1, 128..255 V, 256..383 U=K2@Wout,
//                    384..511 Qfull = QR + emb@Wq[:,2:]^T  (QR folded in GEMM)
//   M   [128][512], QR [B][128] (dead after gemm -> reused as work counter),
//   QI  [B][128], SOL [B][200]
#define OUT_F   0l
#define M_F     52428800l
#define QR_F    (M_F + 65536l)
#define QI_F    (QR_F + 65536l)
#define SOL_F   (QI_F + 65536l)
#define WS_FLOATS (SOL_F + 102400l)   // ~211 MB (known OK)

typedef float f32x4 __attribute__((ext_vector_type(4)));

// ---------------- DPP cross-lane helpers ----------------
#define DPPF(x, ctrl, oldv) __int_as_float(__builtin_amdgcn_update_dpp( \
      __float_as_int(oldv), __float_as_int(x), ctrl, 0xF, 0xF, false))

__device__ __forceinline__ float wave_max(float x) {
  x = fmaxf(x, DPPF(x, 0x111, -INFINITY));
  x = fmaxf(x, DPPF(x, 0x112, -INFINITY));
  x = fmaxf(x, DPPF(x, 0x114, -INFINITY));
  x = fmaxf(x, DPPF(x, 0x118, -INFINITY));
  x = fmaxf(x, DPPF(x, 0x142, -INFINITY));
  x = fmaxf(x, DPPF(x, 0x143, -INFINITY));
  return __int_as_float(__builtin_amdgcn_readlane(__float_as_int(x), 63));
}
__device__ __forceinline__ float wave_sum(float x) {
  x = x + DPPF(x, 0x111, 0.f);
  x = x + DPPF(x, 0x112, 0.f);
  x = x + DPPF(x, 0x114, 0.f);
  x = x + DPPF(x, 0x118, 0.f);
  x = x + DPPF(x, 0x142, 0.f);
  x = x + DPPF(x, 0x143, 0.f);
  return __int_as_float(__builtin_amdgcn_readlane(__float_as_int(x), 63));
}

// ---------------- static precompute ----------------
__global__ __launch_bounds__(256)
void build_M(const float* __restrict__ Wk1, const float* __restrict__ Wv,
             const float* __restrict__ Wk2, const float* __restrict__ Wout,
             const float* __restrict__ Wq, float* __restrict__ Mbuf) {
  int g = blockIdx.x * 256 + threadIdx.x;
  int j = g >> 9, c = g & 511;
  float val;
  if (c < 128) {
    val = Wk1[c * 128 + j];
  } else if (c < 256) {
    val = Wv[(c - 128) * 128 + j];
  } else if (c < 384) {
    int d = c - 256;
    float s = 0.f;
    for (int e = 0; e < 128; ++e) s += Wk2[e * 128 + j] * Wout[e * 128 + d];
    val = s;
  } else {
    val = Wq[(c - 384) * 130 + 2 + j];
  }
  Mbuf[j * 512 + c] = val;
}

__global__ __launch_bounds__(256)
void build_Q(const float* __restrict__ rf, const float* __restrict__ Wq,
             const float* __restrict__ initn, float* __restrict__ QR,
             float* __restrict__ QI) {
  int g = blockIdx.x * 256 + threadIdx.x;   // 65536 = 512*128
  int b = g >> 7, d = g & 127;
  float qr = Wq[d * 130 + 0] * rf[b * 2 + 0] + Wq[d * 130 + 1] * rf[b * 2 + 1];
  float qi = qr;
  for (int j = 0; j < 128; ++j) qi += Wq[d * 130 + 2 + j] * initn[j];
  QR[g] = qr;
  QI[g] = qi;
}

// XCD-aware remap: the 8 col-tile blocks sharing an A-row panel all land on
// the same XCD (bid%8 pinned), so A is fetched from L3 once per XCD.
__global__ __launch_bounds__(256)
void gemm_static(const float* __restrict__ emb, const float* __restrict__ Mbuf,
                 const float* __restrict__ bk1, const float* __restrict__ QR,
                 float* __restrict__ OUT) {
  int bid = blockIdx.x;                 // 12800
  int lo = bid & 7, hi = bid >> 3;      // hi in [0,1600)
  int rt = lo + 8 * (hi % 200);         // row-tile  [0,1600)
  int ct = hi / 200;                    // col-tile  [0,8)
  int r0 = rt * 64, c0 = ct * 64;
  int t = threadIdx.x, ty = t >> 4, tx = t & 15;
  int row0 = r0 + ty * 4;
  int col  = c0 + tx * 4;
  float acc[4][4] = {};
  const float* mp = Mbuf + col;
  for (int kb = 0; kb < 32; ++kb) {
    int k = kb * 4;
    float4 b0 = *(const float4*)(mp + (long)(k + 0) * 512);
    float4 b1 = *(const float4*)(mp + (long)(k + 1) * 512);
    float4 b2 = *(const float4*)(mp + (long)(k + 2) * 512);
    float4 b3 = *(const float4*)(mp + (long)(k + 3) * 512);
    float bm[4][4] = {{b0.x,b0.y,b0.z,b0.w},{b1.x,b1.y,b1.z,b1.w},
                      {b2.x,b2.y,b2.z,b2.w},{b3.x,b3.y,b3.z,b3.w}};
    #pragma unroll
    for (int rr = 0; rr < 4; ++rr) {
      float4 a4 = *(const float4*)(emb + (long)(row0 + rr) * 128 + k);
      float av[4] = {a4.x, a4.y, a4.z, a4.w};
      #pragma unroll
      for (int i = 0; i < 4; ++i)
        #pragma unroll
        for (int cc = 0; cc < 4; ++cc)
          acc[rr][cc] += av[i] * bm[i][cc];
    }
  }
  float badd[4] = {0.f, 0.f, 0.f, 0.f};
  if (c0 < 128) {
    #pragma unroll
    for (int cc = 0; cc < 4; ++cc) badd[cc] = bk1[col + cc];
  }
  #pragma unroll
  for (int rr = 0; rr < 4; ++rr) {
    int row = row0 + rr;
    float v[4];
    #pragma unroll
    for (int cc = 0; cc < 4; ++cc) v[cc] = acc[rr][cc] + badd[cc];
    if (col >= 384) {
      int bb = row / 200;
      #pragma unroll
      for (int cc = 0; cc < 4; ++cc) v[cc] += QR[bb * 128 + (col - 384) + cc];
    }
    float4 v4; v4.x = v[0]; v4.y = v[1]; v4.z = v[2]; v4.w = v[3];
    *(float4*)(OUT + (long)row * 512 + col) = v4;
  }
}

__global__ void init_ctr(int* __restrict__ c) { *c = 0; }

// ---------------- decode512: fused scores+softmax+mha, 3 barriers/step ----------------
// K1 redistributed: wave h, lane l owns K1[l+64k][h*16..+15] (kreg) -> wave h
// computes its head's scores IN the softmax lanes (no LDS round trip, no
// barrier). at write -> B read is intra-wave (per-wave DS ordering). C and D
// as round 15. Masking via per-lane mk bitmask (all waves maintain it).
__global__ __attribute__((amdgpu_flat_work_group_size(512, 512), amdgpu_waves_per_eu(2, 2)))
void decode512(const float* __restrict__ OUT, const float* __restrict__ QI,
               int* __restrict__ ctr, float* __restrict__ sol,
               float* __restrict__ out) {
  __shared__ __align__(16) float qall[201 * 128];  // q rows (+row 200 = QI), 103 KB
  __shared__ float sc[1600];                       // attn [h][200]
  __shared__ __align__(16) float mhal[128];
  __shared__ float lg[200];
  __shared__ int bci, bsel;

  const int t = threadIdx.x;
  const int lane = t & 63, wave = t >> 6;
  const int o = t >> 2, r4 = t & 3;
  const int mn = t >> 1, half = t & 1;
  const int vst  = (r4 == 0) ? 0 : (r4 == 1 ? 48 : (r4 == 2 ? 100 : 152));
  const bool mid = (r4 == 1) || (r4 == 2);     // 52-row slices

  float kreg[64], ureg[64], vreg[52];

  for (;;) {
    if (t == 0) bsel = atomicAdd(ctr, 1);
    __syncthreads();
    const int b = bsel;
    if (b >= 512) break;
    const float* outb = OUT + (long)b * 200 * 512;

    // q rows -> LDS (row 200 = QI)
    for (int f = t; f < 25728; f += 512) {
      int row = f >> 7, d = f & 127;
      qall[f] = (row < 200) ? outb[row * 512 + 384 + d] : QI[b * 128 + d];
    }
    // K1 -> regs, wave-head layout: kreg[k*16+d] = K1[lane+64k][wave*16+d]
    #pragma unroll
    for (int k = 0; k < 4; ++k) {
      int n = lane + 64 * k;
      if (n < 200) {
        const float* kp = outb + n * 512 + wave * 16;
        #pragma unroll
        for (int c = 0; c < 4; ++c)
          *(f32x4*)&kreg[k * 16 + c * 4] = *(const f32x4*)(kp + c * 4);
      } else {
        #pragma unroll
        for (int c = 0; c < 16; ++c) kreg[k * 16 + c] = 0.f;
      }
    }
    // U rows -> regs (t < 400): ureg = U[mn][64*half ..]
    if (t < 400) {
      const float* up = outb + mn * 512 + 256 + 64 * half;
      #pragma unroll
      for (int c = 0; c < 16; ++c)
        *(f32x4*)&ureg[c * 4] = *(const f32x4*)(up + c * 4);
    }
    // V slice -> regs (all t)
    {
      const float* vp = outb + 128 + o;
      #pragma unroll
      for (int i = 0; i < 48; ++i) vreg[i] = vp[(vst + i) * 512];
      vreg[48] = mid ? vp[(vst + 48) * 512] : 0.f;
      vreg[49] = mid ? vp[(vst + 49) * 512] : 0.f;
      vreg[50] = mid ? vp[(vst + 50) * 512] : 0.f;
      vreg[51] = mid ? vp[(vst + 51) * 512] : 0.f;
    }

    int cur = 200;      // q row index (200 = step-0 / QI row)
    int mk = 0;         // per-lane visited bits (node = lane + 64k)
    bool cmb = false;   // node mn visited (t < 400, for C's lg masking)
    bool live = true, picked0 = false;
    float llsum = 0.f, chose = 0.f;

    __syncthreads();

    for (int st = 0; st < 200; ++st) {
      // ---- A: scores + softmax + attn write (wave h = head h, fused) ----
      {
        const float* qb = qall + cur * 128 + wave * 16;
        f32x4 q0 = *(const f32x4*)(qb + 0);
        f32x4 q1 = *(const f32x4*)(qb + 4);
        f32x4 q2 = *(const f32x4*)(qb + 8);
        f32x4 q3 = *(const f32x4*)(qb + 12);
        float sv[4];
        float mx = -INFINITY;
        #pragma unroll
        for (int k = 0; k < 4; ++k) {
          int n = lane + 64 * k;
          float s = -INFINITY;
          if (n < 200) {
            float a = q0[0] * kreg[k * 16 + 0];
            a += q0[1] * kreg[k * 16 + 1];
            a += q0[2] * kreg[k * 16 + 2];
            a += q0[3] * kreg[k * 16 + 3];
            a += q1[0] * kreg[k * 16 + 4];
            a += q1[1] * kreg[k * 16 + 5];
            a += q1[2] * kreg[k * 16 + 6];
            a += q1[3] * kreg[k * 16 + 7];
            a += q2[0] * kreg[k * 16 + 8];
            a += q2[1] * kreg[k * 16 + 9];
            a += q2[2] * kreg[k * 16 + 10];
            a += q2[3] * kreg[k * 16 + 11];
            a += q3[0] * kreg[k * 16 + 12];
            a += q3[1] * kreg[k * 16 + 13];
            a += q3[2] * kreg[k * 16 + 14];
            a += q3[3] * kreg[k * 16 + 15];
            s = a * 0.25f;
            if (mk & (1 << k)) s = NEGV;
          }
          sv[k] = s;
          mx = fmaxf(mx, s);
        }
        float vmax = wave_max(mx);
        float ls = 0.f;
        #pragma unroll
        for (int k = 0; k < 4; ++k) { sv[k] = expf(sv[k] - vmax); ls += sv[k]; }
        ls = wave_sum(ls);
        #pragma unroll
        for (int k = 0; k < 4; ++k) {
          int n = lane + 64 * k;
          if (n < 200) sc[wave * 200 + n] = sv[k] / ls;
        }
      }
      // no barrier: B's wave h reads only row h, written by itself above.

      // ---- B: mha[o] = sum_n attn[h][n] * V[n][o]  (h = wave, 4 accs) ----
      {
        const float* ap = sc + wave * 200 + vst;
        float ac[4] = {0.f, 0.f, 0.f, 0.f};
        #pragma unroll
        for (int c = 0; c < 12; ++c) {
          f32x4 av = *(const f32x4*)(ap + c * 4);
          float s = av[0] * vreg[c * 4 + 0];
          s += av[1] * vreg[c * 4 + 1];
          s += av[2] * vreg[c * 4 + 2];
          s += av[3] * vreg[c * 4 + 3];
          ac[c & 3] += s;
        }
        if (mid) {
          f32x4 av = *(const f32x4*)(ap + 48);
          float s = av[0] * vreg[48];
          s += av[1] * vreg[49]; s += av[2] * vreg[50]; s += av[3] * vreg[51];
          ac[0] += s;
        }
        float a = (ac[0] + ac[1]) + (ac[2] + ac[3]);
        a += DPPF(a, 0xB1, 0.f);
        a += DPPF(a, 0x4E, 0.f);
        if (r4 == 0) mhal[o] = a;
      }
      __syncthreads();

      // ---- C: logits[m] = 10*tanh((mha . U[m]) / sqrt(128))  (4 accs) ----
      if (t < 400) {
        float ac[4] = {0.f, 0.f, 0.f, 0.f};
        #pragma unroll
        for (int c = 0; c < 16; ++c) {
          f32x4 mh = *(const f32x4*)&mhal[64 * half + c * 4];
          float s = mh[0] * ureg[c * 4 + 0];
          s += mh[1] * ureg[c * 4 + 1];
          s += mh[2] * ureg[c * 4 + 2];
          s += mh[3] * ureg[c * 4 + 3];
          ac[c & 3] += s;
        }
        float a = (ac[0] + ac[1]) + (ac[2] + ac[3]);
        a += DPPF(a, 0xB1, 0.f);   // (half 0) + (half 1)
        if (half == 0) {
          float l = 10.f * tanhf(a / 11.313708498984761f);
          lg[mn] = cmb ? NEGV : l;
        }
      }
      __syncthreads();

      // ---- D: argmax + lse (wave 7 only; others wait at barrier) ----
      if (wave == 7) {
        float lv[4];
        float mx = -INFINITY;
        #pragma unroll
        for (int k = 0; k < 4; ++k) {
          int n = lane + 64 * k;
          lv[k] = (n < 200) ? lg[n] : -INFINITY;
          mx = fmaxf(mx, lv[k]);
        }
        float vmax = wave_max(mx);
        int bidx = -1;
        #pragma unroll
        for (int k = 0; k < 4; ++k) {
          unsigned long long bm =
              __ballot((lane + 64 * k < 200) && (lv[k] == vmax));
          if (bidx < 0 && bm != 0ull) bidx = k * 64 + (int)__builtin_ctzll(bm);
        }
        int nxt = live ? bidx : 0;
        float e = 0.f;
        #pragma unroll
        for (int k = 0; k < 4; ++k) e += expf(lv[k] - vmax);
        float se_ = wave_sum(e);
        float lse = logf(se_);
        if (t == 448) {
          chose = live ? (-lse) : ((lv[0] - vmax) - lse);
          out[2048 + (long)b * 200 + st] = (float)nxt;
          bci = nxt;
        }
      }
      __syncthreads();

      int nxt = bci;
      if (!live) {
        if (t == 448) llsum += chose * (float)(200 - st);
        for (int s2 = st + 1 + t; s2 < 200; s2 += 512)
          out[2048 + (long)b * 200 + s2] = 0.f;
        break;
      }
      if (t == 448) llsum += chose;
      if ((nxt & 63) == lane) mk |= 1 << (nxt >> 6);
      if (t < 400 && nxt == mn) cmb = true;
      cur = nxt;
      if (nxt == 0) { live = false; picked0 = true; }
    }

    if (t == 448) out[1536 + b] = picked0 ? llsum : 0.f;
    if (t < 400 && half == 0) {
      float s = (mn == 0) ? 1.f : ((picked0 && cmb) ? 1.f : 0.f);
      sol[(long)b * 200 + mn] = s;
    }
    __syncthreads();   // protect LDS reuse before next grab
  }
}

// ---------------- decode (round-12 fallback, unchanged) ----------------
__global__ __attribute__((amdgpu_flat_work_group_size(1024, 1024)))
void decode(const float* __restrict__ OUT, const float* __restrict__ QI,
            int* __restrict__ ctr, float* __restrict__ sol,
            float* __restrict__ out) {
  __shared__ __align__(16) float k1r[25600];   // [n][128] rot-4n, 102.4 KB
  __shared__ __align__(16) float at[1600];     // attn [h][200]  6.4 KB
  __shared__ __align__(16) float mhal[128];
  __shared__ float lg[200];
  __shared__ __align__(16) float qv[128];
  __shared__ __align__(16) float ul[12800];    // U-high [m][64] rot-4m, 51.2 KB
  __shared__ int   bci;
  __shared__ int   bsel;

  const int t = threadIdx.x;
  const int lane = t & 63, wave = t >> 6;
  const int o = t >> 3, q8 = t & 7;
  const int m4 = t >> 2, j4 = t & 3;
  const int stq = (q8 * 25) & ~3;
  const int cq  = ((((q8 + 1) * 25) & ~3) - stq) >> 2;   // 6 or 7 quads

  for (;;) {
    if (t == 0) bsel = atomicAdd(ctr, 1);
    __syncthreads();
    const int b = bsel;
    if (b >= 512) break;
    const float* outb = OUT + (long)b * 200 * 512;

    for (int p = 0; p < 25; ++p) {
      int f = p * 1024 + t;
      int n = f >> 7, d = f & 127;
      k1r[n * 128 + ((d + 4 * n) & 127)] = outb[n * 512 + d];
    }
    for (int f = t; f < 12800; f += 1024) {
      int m = f >> 6, c = f & 63;
      ul[m * 64 + ((c + 4 * m) & 63)] =
          outb[m * 512 + 256 + (c >> 4) * 32 + 16 + (c & 15)];
    }
    f32x4 vA = {}, vB = {}, vC = {}, vD = {}, vE = {}, vF = {}, vG = {};
    {
      const float* vp = outb + 128 + o;
      #pragma unroll
      for (int e = 0; e < 4; ++e) vA[e] = vp[(stq + 0 + e) * 512];
      #pragma unroll
      for (int e = 0; e < 4; ++e) vB[e] = vp[(stq + 4 + e) * 512];
      #pragma unroll
      for (int e = 0; e < 4; ++e) vC[e] = vp[(stq + 8 + e) * 512];
      #pragma unroll
      for (int e = 0; e < 4; ++e) vD[e] = vp[(stq + 12 + e) * 512];
      #pragma unroll
      for (int e = 0; e < 4; ++e) vE[e] = vp[(stq + 16 + e) * 512];
      #pragma unroll
      for (int e = 0; e < 4; ++e) vF[e] = vp[(stq + 20 + e) * 512];
      if (cq == 7) {
        #pragma unroll
        for (int e = 0; e < 4; ++e) vG[e] = vp[(stq + 24 + e) * 512];
      }
    }
    f32x4 urR0 = {}, urR1 = {}, urR2 = {}, urR3 = {};
    if (t < 800) {
      const float* up = outb + m4 * 512 + 256 + j4 * 32;
      urR0 = *(const f32x4*)(up + 4 * ((0 + j4) & 3));
      urR1 = *(const f32x4*)(up + 4 * ((1 + j4) & 3));
      urR2 = *(const f32x4*)(up + 4 * ((2 + j4) & 3));
      urR3 = *(const f32x4*)(up + 4 * ((3 + j4) & 3));
    }
    if (t < 128) qv[t] = QI[b * 128 + t];

    int mk = 0;
    bool cm = false;
    bool live = true, picked0 = false;
    float llsum = 0.f, chose = 0.f;

    __syncthreads();

    for (int st = 0; st < 200; ++st) {
      if (wave < 8) {
        const int hb = wave * 16;
        float acc[4] = {};
        #pragma unroll
        for (int hf = 0; hf < 2; ++hf) {
          f32x4 qa = *(const f32x4*)&qv[hb + hf * 8];
          f32x4 qb2 = *(const f32x4*)&qv[hb + hf * 8 + 4];
          #pragma unroll
          for (int k = 0; k < 4; ++k) {
            int n = lane + 64 * k;
            if (n < 200) {
              const float* kb = k1r + n * 128;
              int off  = (hb + hf * 8 + 4 * n) & 127;
              int off2 = (hb + hf * 8 + 4 + 4 * n) & 127;
              f32x4 kA = *(const f32x4*)(kb + off);
              f32x4 kB = *(const f32x4*)(kb + off2);
              float ah = qa[0] * kA[0];
              ah += qa[1] * kA[1]; ah += qa[2] * kA[2]; ah += qa[3] * kA[3];
              ah += qb2[0] * kB[0]; ah += qb2[1] * kB[1];
              ah += qb2[2] * kB[2]; ah += qb2[3] * kB[3];
              acc[k] += ah;
            }
          }
        }
        float sv[4];
        float mx = -INFINITY;
        #pragma unroll
        for (int k = 0; k < 4; ++k) {
          int n = lane + 64 * k;
          float s = -INFINITY;
          if (n < 200) {
            s = acc[k] * 0.25f;
            if (mk & (1 << k)) s = NEGV;
          }
          sv[k] = s;
          mx = fmaxf(mx, s);
        }
        float vmax = wave_max(mx);
        float ls = 0.f;
        #pragma unroll
        for (int k = 0; k < 4; ++k) { sv[k] = expf(sv[k] - vmax); ls += sv[k]; }
        ls = wave_sum(ls);
        #pragma unroll
        for (int k = 0; k < 4; ++k) {
          int n = lane + 64 * k;
          if (n < 200) at[wave * 200 + n] = sv[k] / ls;
        }
      }
      __syncthreads();

      {
        const int h2 = t >> 7;
        const float* ap = at + h2 * 200 + stq;
        float a = 0.f;
        f32x4 av;
        av = *(const f32x4*)(ap + 0);
        a += av[0]*vA[0]; a += av[1]*vA[1]; a += av[2]*vA[2]; a += av[3]*vA[3];
        av = *(const f32x4*)(ap + 4);
        a += av[0]*vB[0]; a += av[1]*vB[1]; a += av[2]*vB[2]; a += av[3]*vB[3];
        av = *(const f32x4*)(ap + 8);
        a += av[0]*vC[0]; a += av[1]*vC[1]; a += av[2]*vC[2]; a += av[3]*vC[3];
        av = *(const f32x4*)(ap + 12);
        a += av[0]*vD[0]; a += av[1]*vD[1]; a += av[2]*vD[2]; a += av[3]*vD[3];
        av = *(const f32x4*)(ap + 16);
        a += av[0]*vE[0]; a += av[1]*vE[1]; a += av[2]*vE[2]; a += av[3]*vE[3];
        av = *(const f32x4*)(ap + 20);
        a += av[0]*vF[0]; a += av[1]*vF[1]; a += av[2]*vF[2]; a += av[3]*vF[3];
        if (cq == 7) {
          av = *(const f32x4*)(ap + 24);
          a += av[0]*vG[0]; a += av[1]*vG[1]; a += av[2]*vG[2]; a += av[3]*vG[3];
        }
        a += DPPF(a, 0xB1, 0.f);
        a += DPPF(a, 0x4E, 0.f);
        a += DPPF(a, 0x141, 0.f);
        if (q8 == 0) mhal[o] = a;
      }
      __syncthreads();

      if (t < 800) {
        float a = 0.f;
        {
          f32x4 ml;
          ml = *(const f32x4*)&mhal[j4 * 32 + ((0 + j4) & 3) * 4];
          a += ml[0]*urR0[0]; a += ml[1]*urR0[1]; a += ml[2]*urR0[2]; a += ml[3]*urR0[3];
          ml = *(const f32x4*)&mhal[j4 * 32 + ((1 + j4) & 3) * 4];
          a += ml[0]*urR1[0]; a += ml[1]*urR1[1]; a += ml[2]*urR1[2]; a += ml[3]*urR1[3];
          ml = *(const f32x4*)&mhal[j4 * 32 + ((2 + j4) & 3) * 4];
          a += ml[0]*urR2[0]; a += ml[1]*urR2[1]; a += ml[2]*urR2[2]; a += ml[3]*urR2[3];
          ml = *(const f32x4*)&mhal[j4 * 32 + ((3 + j4) & 3) * 4];
          a += ml[0]*urR3[0]; a += ml[1]*urR3[1]; a += ml[2]*urR3[2]; a += ml[3]*urR3[3];
        }
        const int ubase = m4 * 64;
        #pragma unroll
        for (int c = 0; c < 4; ++c) {
          int ci = (c + j4) & 3;
          f32x4 mh = *(const f32x4*)&mhal[j4 * 32 + 16 + ci * 4];
          f32x4 uu = *(const f32x4*)&ul[ubase + ((j4 * 16 + ci * 4 + 4 * m4) & 63)];
          a += mh[0]*uu[0]; a += mh[1]*uu[1]; a += mh[2]*uu[2]; a += mh[3]*uu[3];
        }
        a += DPPF(a, 0xB1, 0.f);
        a += DPPF(a, 0x4E, 0.f);
        if (j4 == 0) {
          float l = 10.f * tanhf(a / 11.313708498984761f);
          lg[m4] = cm ? NEGV : l;
        }
      }
      __syncthreads();

      if (wave < 8) {
        float lv[4];
        float mx = -INFINITY;
        #pragma unroll
        for (int k = 0; k < 4; ++k) {
          int n = lane + 64 * k;
          lv[k] = (n < 200) ? lg[n] : -INFINITY;
          mx = fmaxf(mx, lv[k]);
        }
        float vmax = wave_max(mx);
        int bidx = -1;
        #pragma unroll
        for (int k = 0; k < 4; ++k) {
          unsigned long long bm =
              __ballot((lane + 64 * k < 200) && (lv[k] == vmax));
          if (bidx < 0 && bm != 0ull) bidx = k * 64 + (int)__builtin_ctzll(bm);
        }
        int nxt = live ? bidx : 0;
        if (t < 128) qv[t] = outb[(long)nxt * 512 + 384 + t];
        float e = 0.f;
        #pragma unroll
        for (int k = 0; k < 4; ++k) e += expf(lv[k] - vmax);
        float se_ = wave_sum(e);
        float lse = logf(se_);
        if (t == 0) {
          chose = live ? (-lse) : ((lv[0] - vmax) - lse);
          out[2048 + (long)b * 200 + st] = (float)nxt;
          bci = nxt;
        }
      }
      __syncthreads();

      int nxt = bci;
      if (!live) {
        if (t == 0) llsum += chose * (float)(200 - st);
        for (int s2 = st + 1 + t; s2 < 200; s2 += 1024)
          out[2048 + (long)b * 200 + s2] = 0.f;
        break;
      }
      if (t == 0) llsum += chose;
      if (wave < 8 && (nxt & 63) == lane) mk |= 1 << (nxt >> 6);
      if (t < 800 && nxt == m4) cm = true;
      if (nxt == 0) { live = false; picked0 = true; }
    }

    if (t == 0) out[1536 + b] = picked0 ? llsum : 0.f;
    if (t < 800 && j4 == 0) {
      float s = (m4 == 0) ? 1.f : ((picked0 && cm) ? 1.f : 0.f);
      sol[(long)b * 200 + m4] = s;
    }
    __syncthreads();
  }
}

// ---------------- cost: predicated (branch-free, pipelined loads) ----------------
__global__ __launch_bounds__(256)
void cost_kernel(const float* __restrict__ x, const float* __restrict__ rf,
                 const float* __restrict__ sol, float* __restrict__ out) {
  __shared__ float solL[256];
  __shared__ float red[8];
  const int b = blockIdx.x, t = threadIdx.x;
  solL[t] = (t < 200) ? sol[b * 200 + t] : 0.f;
  __syncthreads();
  const float* x0 = x + (long)b * 40000;
  const float* x1 = x + 20480000l + (long)b * 40000;
  float a1 = 0.f, a2 = 0.f;
  if (t < 200) {
    #pragma unroll 4
    for (int i = 0; i < 200; ++i) {
      float w2 = solL[i];
      a1 += x0[i * 200 + t] * w2;   // w2 in {0,1}: x*1 exact, x*0 adds +-0
      a2 += x1[i * 200 + t] * w2;
    }
    float w = solL[t];
    a1 *= w; a2 *= w;
  }
  #pragma unroll
  for (int off = 32; off > 0; off >>= 1) {
    a1 += __shfl_xor(a1, off);
    a2 += __shfl_xor(a2, off);
  }
  if ((t & 63) == 0) { red[(t >> 6) * 2] = a1; red[(t >> 6) * 2 + 1] = a2; }
  __syncthreads();
  if (t == 0) {
    float f1 = red[0] + red[2] + red[4] + red[6];
    float f2 = red[1] + red[3] + red[5] + red[7];
    out[b]        = -(f1 * rf[0] + f2 * rf[1]);
    out[512 + b]  = f1;
    out[1024 + b] = f2;
  }
}

extern "C" void kernel_launch(void* const* d_in, const int* in_sizes, int n_in,
                              void* d_out, int out_size, void* d_ws, size_t ws_size,
                              hipStream_t stream) {
  const float* x     = (const float*)d_in[0];
  const float* rf    = (const float*)d_in[1];
  const float* emb   = (const float*)d_in[2];
  const float* Wk1   = (const float*)d_in[4];
  const float* bk1   = (const float*)d_in[5];
  const float* Wv    = (const float*)d_in[6];
  const float* Wk2   = (const float*)d_in[7];
  const float* Wout  = (const float*)d_in[8];
  const float* Wq    = (const float*)d_in[9];
  const float* initn = (const float*)d_in[10];
  float* out = (float*)d_out;
  float* ws  = (float*)d_ws;

  if (ws_size < (size_t)WS_FLOATS * 4) return;

  float* OUTb = ws + OUT_F;
  float* Mb   = ws + M_F;
  float* QRb  = ws + QR_F;   // dead after gemm; first 4 bytes reused as counter
  float* QIb  = ws + QI_F;
  float* solb = ws + SOL_F;

  build_M<<<256, 256, 0, stream>>>(Wk1, Wv, Wk2, Wout, Wq, Mb);
  build_Q<<<256, 256, 0, stream>>>(rf, Wq, initn, QRb, QIb);
  gemm_static<<<12800, 256, 0, stream>>>(emb, Mb, bk1, QRb, OUTb);
  init_ctr<<<1, 1, 0, stream>>>((int*)QRb);

  // Spill detector: use the all-register decode512 only if it allocated no
  // scratch (localSizeBytes). Spilled state = round-4 disaster -> fallback.
  hipFuncAttributes fa;
  bool big = false;
  if (hipFuncGetAttributes(&fa, (const void*)decode512) == hipSuccess)
    big = (fa.localSizeBytes <= 64);
  if (big)
    decode512<<<256, 512, 0, stream>>>(OUTb, QIb, (int*)QRb, solb, out);
  else
    decode<<<256, 1024, 0, stream>>>(OUTb, QIb, (int*)QRb, solb, out);

  cost_kernel<<<512, 256, 0, stream>>>(x, rf, solb, out);
}

// Round 17
// 1197.782 us; speedup vs baseline: 1.6355x; 1.0147x over previous
//
#include <hip/hip_runtime.h>
#include <math.h>

#define NEGV (-1e9f)

// ws layout (float offsets):
//   OUT [B*N][512] : cols 0..127 K1, 128..255 V, 256..383 U=K2@Wout,
//                    384..511 Qfull = QR + emb@Wq[:,2:]^T  (QR folded in GEMM)
//   M   [128][512], QR [B][128] (dead after gemm -> reused as work counter),
//   QI  [B][128], SOL [B][200]
#define OUT_F   0l
#define M_F     52428800l
#define QR_F    (M_F + 65536l)
#define QI_F    (QR_F + 65536l)
#define SOL_F   (QI_F + 65536l)
#define WS_FLOATS (SOL_F + 102400l)   // ~211 MB (known OK)

typedef float f32x4 __attribute__((ext_vector_type(4)));

// ---------------- DPP cross-lane helpers ----------------
#define DPPF(x, ctrl, oldv) __int_as_float(__builtin_amdgcn_update_dpp( \
      __float_as_int(oldv), __float_as_int(x), ctrl, 0xF, 0xF, false))

__device__ __forceinline__ float wave_max(float x) {
  x = fmaxf(x, DPPF(x, 0x111, -INFINITY));
  x = fmaxf(x, DPPF(x, 0x112, -INFINITY));
  x = fmaxf(x, DPPF(x, 0x114, -INFINITY));
  x = fmaxf(x, DPPF(x, 0x118, -INFINITY));
  x = fmaxf(x, DPPF(x, 0x142, -INFINITY));
  x = fmaxf(x, DPPF(x, 0x143, -INFINITY));
  return __int_as_float(__builtin_amdgcn_readlane(__float_as_int(x), 63));
}
__device__ __forceinline__ float wave_sum(float x) {
  x = x + DPPF(x, 0x111, 0.f);
  x = x + DPPF(x, 0x112, 0.f);
  x = x + DPPF(x, 0x114, 0.f);
  x = x + DPPF(x, 0x118, 0.f);
  x = x + DPPF(x, 0x142, 0.f);
  x = x + DPPF(x, 0x143, 0.f);
  return __int_as_float(__builtin_amdgcn_readlane(__float_as_int(x), 63));
}

// ---------------- static precompute ----------------
__global__ __launch_bounds__(256)
void build_M(const float* __restrict__ Wk1, const float* __restrict__ Wv,
             const float* __restrict__ Wk2, const float* __restrict__ Wout,
             const float* __restrict__ Wq, float* __restrict__ Mbuf) {
  int g = blockIdx.x * 256 + threadIdx.x;
  int j = g >> 9, c = g & 511;
  float val;
  if (c < 128) {
    val = Wk1[c * 128 + j];
  } else if (c < 256) {
    val = Wv[(c - 128) * 128 + j];
  } else if (c < 384) {
    int d = c - 256;
    float s = 0.f;
    for (int e = 0; e < 128; ++e) s += Wk2[e * 128 + j] * Wout[e * 128 + d];
    val = s;
  } else {
    val = Wq[(c - 384) * 130 + 2 + j];
  }
  Mbuf[j * 512 + c] = val;
}

__global__ __launch_bounds__(256)
void build_Q(const float* __restrict__ rf, const float* __restrict__ Wq,
             const float* __restrict__ initn, float* __restrict__ QR,
             float* __restrict__ QI, int* __restrict__ ctr) {
  int g = blockIdx.x * 256 + threadIdx.x;   // 65536 = 512*128
  if (g == 0) *ctr = 0;                     // fold counter init (pre-decode)
  int b = g >> 7, d = g & 127;
  float qr = Wq[d * 130 + 0] * rf[b * 2 + 0] + Wq[d * 130 + 1] * rf[b * 2 + 1];
  float qi = qr;
  for (int j = 0; j < 128; ++j) qi += Wq[d * 130 + 2 + j] * initn[j];
  QR[g] = qr;
  QI[g] = qi;
}

// XCD-aware remap: the 8 col-tile blocks sharing an A-row panel all land on
// the same XCD (bid%8 pinned), so A is fetched from L3 once per XCD.
__global__ __launch_bounds__(256)
void gemm_static(const float* __restrict__ emb, const float* __restrict__ Mbuf,
                 const float* __restrict__ bk1, const float* __restrict__ QR,
                 float* __restrict__ OUT) {
  int bid = blockIdx.x;                 // 12800
  int lo = bid & 7, hi = bid >> 3;      // hi in [0,1600)
  int rt = lo + 8 * (hi % 200);         // row-tile  [0,1600)
  int ct = hi / 200;                    // col-tile  [0,8)
  int r0 = rt * 64, c0 = ct * 64;
  int t = threadIdx.x, ty = t >> 4, tx = t & 15;
  int row0 = r0 + ty * 4;
  int col  = c0 + tx * 4;
  float acc[4][4] = {};
  const float* mp = Mbuf + col;
  for (int kb = 0; kb < 32; ++kb) {
    int k = kb * 4;
    float4 b0 = *(const float4*)(mp + (long)(k + 0) * 512);
    float4 b1 = *(const float4*)(mp + (long)(k + 1) * 512);
    float4 b2 = *(const float4*)(mp + (long)(k + 2) * 512);
    float4 b3 = *(const float4*)(mp + (long)(k + 3) * 512);
    float bm[4][4] = {{b0.x,b0.y,b0.z,b0.w},{b1.x,b1.y,b1.z,b1.w},
                      {b2.x,b2.y,b2.z,b2.w},{b3.x,b3.y,b3.z,b3.w}};
    #pragma unroll
    for (int rr = 0; rr < 4; ++rr) {
      float4 a4 = *(const float4*)(emb + (long)(row0 + rr) * 128 + k);
      float av[4] = {a4.x, a4.y, a4.z, a4.w};
      #pragma unroll
      for (int i = 0; i < 4; ++i)
        #pragma unroll
        for (int cc = 0; cc < 4; ++cc)
          acc[rr][cc] += av[i] * bm[i][cc];
    }
  }
  float badd[4] = {0.f, 0.f, 0.f, 0.f};
  if (c0 < 128) {
    #pragma unroll
    for (int cc = 0; cc < 4; ++cc) badd[cc] = bk1[col + cc];
  }
  #pragma unroll
  for (int rr = 0; rr < 4; ++rr) {
    int row = row0 + rr;
    float v[4];
    #pragma unroll
    for (int cc = 0; cc < 4; ++cc) v[cc] = acc[rr][cc] + badd[cc];
    if (col >= 384) {
      int bb = row / 200;
      #pragma unroll
      for (int cc = 0; cc < 4; ++cc) v[cc] += QR[bb * 128 + (col - 384) + cc];
    }
    float4 v4; v4.x = v[0]; v4.y = v[1]; v4.z = v[2]; v4.w = v[3];
    *(float4*)(OUT + (long)row * 512 + col) = v4;
  }
}

__global__ void init_ctr(int* __restrict__ c) { *c = 0; }

// ---------------- decode512: 2 barriers/step, redundant-D, fused cost ----------------
// A: fused scores+softmax per wave-head (kreg wave-head layout, round 16).
// B: intra-wave (no barrier from A). C after barrier. D after barrier,
// REDUNDANT on all 8 waves (same lg -> same nxt deterministically) so no
// bci broadcast / third barrier. Cost for the batch computed inline at the
// claim tail (x reads overlap other CUs' decode).
__global__ __attribute__((amdgpu_flat_work_group_size(512, 512), amdgpu_waves_per_eu(2, 2)))
void decode512(const float* __restrict__ OUT, const float* __restrict__ QI,
               const float* __restrict__ x, const float* __restrict__ rf,
               int* __restrict__ ctr, float* __restrict__ out) {
  __shared__ __align__(16) float qall[201 * 128];  // q rows (+row 200 = QI), 103 KB
  __shared__ float sc[1600];                       // attn [h][200]
  __shared__ __align__(16) float mhal[128];
  __shared__ float lg[200];
  __shared__ float sb[200];                        // sol for fused cost
  __shared__ float redc[16];
  __shared__ int bsel;

  const int t = threadIdx.x;
  const int lane = t & 63, wave = t >> 6;
  const int o = t >> 2, r4 = t & 3;
  const int mn = t >> 1, half = t & 1;
  const int vst  = (r4 == 0) ? 0 : (r4 == 1 ? 48 : (r4 == 2 ? 100 : 152));
  const bool mid = (r4 == 1) || (r4 == 2);     // 52-row slices

  float kreg[64], ureg[64], vreg[52];

  for (;;) {
    if (t == 0) bsel = atomicAdd(ctr, 1);
    __syncthreads();
    const int b = bsel;
    if (b >= 512) break;
    const float* outb = OUT + (long)b * 200 * 512;

    // q rows -> LDS (row 200 = QI)
    for (int f = t; f < 25728; f += 512) {
      int row = f >> 7, d = f & 127;
      qall[f] = (row < 200) ? outb[row * 512 + 384 + d] : QI[b * 128 + d];
    }
    // K1 -> regs, wave-head layout: kreg[k*16+d] = K1[lane+64k][wave*16+d]
    #pragma unroll
    for (int k = 0; k < 4; ++k) {
      int n = lane + 64 * k;
      if (n < 200) {
        const float* kp = outb + n * 512 + wave * 16;
        #pragma unroll
        for (int c = 0; c < 4; ++c)
          *(f32x4*)&kreg[k * 16 + c * 4] = *(const f32x4*)(kp + c * 4);
      } else {
        #pragma unroll
        for (int c = 0; c < 16; ++c) kreg[k * 16 + c] = 0.f;
      }
    }
    // U rows -> regs (t < 400): ureg = U[mn][64*half ..]
    if (t < 400) {
      const float* up = outb + mn * 512 + 256 + 64 * half;
      #pragma unroll
      for (int c = 0; c < 16; ++c)
        *(f32x4*)&ureg[c * 4] = *(const f32x4*)(up + c * 4);
    }
    // V slice -> regs (all t)
    {
      const float* vp = outb + 128 + o;
      #pragma unroll
      for (int i = 0; i < 48; ++i) vreg[i] = vp[(vst + i) * 512];
      vreg[48] = mid ? vp[(vst + 48) * 512] : 0.f;
      vreg[49] = mid ? vp[(vst + 49) * 512] : 0.f;
      vreg[50] = mid ? vp[(vst + 50) * 512] : 0.f;
      vreg[51] = mid ? vp[(vst + 51) * 512] : 0.f;
    }

    int cur = 200;      // q row index (200 = step-0 / QI row)
    int mk = 0;         // per-lane visited bits (node = lane + 64k)
    bool cmb = false;   // node mn visited (t < 400, for C's lg masking)
    bool live = true, picked0 = false;
    float llsum = 0.f, chose = 0.f;

    __syncthreads();

    for (int st = 0; st < 200; ++st) {
      // ---- A: scores + softmax + attn write (wave h = head h, fused) ----
      {
        const float* qb = qall + cur * 128 + wave * 16;
        f32x4 q0 = *(const f32x4*)(qb + 0);
        f32x4 q1 = *(const f32x4*)(qb + 4);
        f32x4 q2 = *(const f32x4*)(qb + 8);
        f32x4 q3 = *(const f32x4*)(qb + 12);
        float sv[4];
        float mx = -INFINITY;
        #pragma unroll
        for (int k = 0; k < 4; ++k) {
          int n = lane + 64 * k;
          float s = -INFINITY;
          if (n < 200) {
            float a = q0[0] * kreg[k * 16 + 0];
            a += q0[1] * kreg[k * 16 + 1];
            a += q0[2] * kreg[k * 16 + 2];
            a += q0[3] * kreg[k * 16 + 3];
            a += q1[0] * kreg[k * 16 + 4];
            a += q1[1] * kreg[k * 16 + 5];
            a += q1[2] * kreg[k * 16 + 6];
            a += q1[3] * kreg[k * 16 + 7];
            a += q2[0] * kreg[k * 16 + 8];
            a += q2[1] * kreg[k * 16 + 9];
            a += q2[2] * kreg[k * 16 + 10];
            a += q2[3] * kreg[k * 16 + 11];
            a += q3[0] * kreg[k * 16 + 12];
            a += q3[1] * kreg[k * 16 + 13];
            a += q3[2] * kreg[k * 16 + 14];
            a += q3[3] * kreg[k * 16 + 15];
            s = a * 0.25f;
            if (mk & (1 << k)) s = NEGV;
          }
          sv[k] = s;
          mx = fmaxf(mx, s);
        }
        float vmax = wave_max(mx);
        float ls = 0.f;
        #pragma unroll
        for (int k = 0; k < 4; ++k) { sv[k] = expf(sv[k] - vmax); ls += sv[k]; }
        ls = wave_sum(ls);
        #pragma unroll
        for (int k = 0; k < 4; ++k) {
          int n = lane + 64 * k;
          if (n < 200) sc[wave * 200 + n] = sv[k] / ls;
        }
      }
      // no barrier: B's wave h reads only row h, written by itself above.

      // ---- B: mha[o] = sum_n attn[h][n] * V[n][o]  (h = wave, 4 accs) ----
      {
        const float* ap = sc + wave * 200 + vst;
        float ac[4] = {0.f, 0.f, 0.f, 0.f};
        #pragma unroll
        for (int c = 0; c < 12; ++c) {
          f32x4 av = *(const f32x4*)(ap + c * 4);
          float s = av[0] * vreg[c * 4 + 0];
          s += av[1] * vreg[c * 4 + 1];
          s += av[2] * vreg[c * 4 + 2];
          s += av[3] * vreg[c * 4 + 3];
          ac[c & 3] += s;
        }
        if (mid) {
          f32x4 av = *(const f32x4*)(ap + 48);
          float s = av[0] * vreg[48];
          s += av[1] * vreg[49]; s += av[2] * vreg[50]; s += av[3] * vreg[51];
          ac[0] += s;
        }
        float a = (ac[0] + ac[1]) + (ac[2] + ac[3]);
        a += DPPF(a, 0xB1, 0.f);
        a += DPPF(a, 0x4E, 0.f);
        if (r4 == 0) mhal[o] = a;
      }
      __syncthreads();

      // ---- C: logits[m] = 10*tanh((mha . U[m]) / sqrt(128))  (4 accs) ----
      if (t < 400) {
        float ac[4] = {0.f, 0.f, 0.f, 0.f};
        #pragma unroll
        for (int c = 0; c < 16; ++c) {
          f32x4 mh = *(const f32x4*)&mhal[64 * half + c * 4];
          float s = mh[0] * ureg[c * 4 + 0];
          s += mh[1] * ureg[c * 4 + 1];
          s += mh[2] * ureg[c * 4 + 2];
          s += mh[3] * ureg[c * 4 + 3];
          ac[c & 3] += s;
        }
        float a = (ac[0] + ac[1]) + (ac[2] + ac[3]);
        a += DPPF(a, 0xB1, 0.f);   // (half 0) + (half 1)
        if (half == 0) {
          float l = 10.f * tanhf(a / 11.313708498984761f);
          lg[mn] = cmb ? NEGV : l;
        }
      }
      __syncthreads();

      // ---- D: argmax REDUNDANT on all waves (same data -> same nxt);
      //         lse/chose on wave 7 only. No barrier, no broadcast. ----
      int nxt;
      {
        float lv[4];
        float mx = -INFINITY;
        #pragma unroll
        for (int k = 0; k < 4; ++k) {
          int n = lane + 64 * k;
          lv[k] = (n < 200) ? lg[n] : -INFINITY;
          mx = fmaxf(mx, lv[k]);
        }
        float vmax = wave_max(mx);
        int bidx = -1;
        #pragma unroll
        for (int k = 0; k < 4; ++k) {
          unsigned long long bm =
              __ballot((lane + 64 * k < 200) && (lv[k] == vmax));
          if (bidx < 0 && bm != 0ull) bidx = k * 64 + (int)__builtin_ctzll(bm);
        }
        nxt = live ? bidx : 0;
        if (wave == 7) {
          float e = 0.f;
          #pragma unroll
          for (int k = 0; k < 4; ++k) e += expf(lv[k] - vmax);
          float se_ = wave_sum(e);
          float lse = logf(se_);
          if (t == 448) {
            chose = live ? (-lse) : ((lv[0] - vmax) - lse);
            out[2048 + (long)b * 200 + st] = (float)nxt;
          }
        }
      }

      if (!live) {
        if (t == 448) llsum += chose * (float)(200 - st);
        for (int s2 = st + 1 + t; s2 < 200; s2 += 512)
          out[2048 + (long)b * 200 + s2] = 0.f;
        break;
      }
      if (t == 448) llsum += chose;
      if ((nxt & 63) == lane) mk |= 1 << (nxt >> 6);
      if (t < 400 && nxt == mn) cmb = true;
      cur = nxt;
      if (nxt == 0) { live = false; picked0 = true; }
    }

    if (t == 448) out[1536 + b] = picked0 ? llsum : 0.f;
    if (t < 400 && half == 0) {
      float s = (mn == 0) ? 1.f : ((picked0 && cmb) ? 1.f : 0.f);
      sb[mn] = s;
    }
    __syncthreads();

    // ---- fused cost for batch b: f = sum_{i} sol_i * (sum_j x[i][j] sol_j) ----
    {
      const int c2 = t >> 1, hf = t & 1;
      float a1 = 0.f, a2 = 0.f;
      if (c2 < 200) {
        const float* xp0 = x + (long)b * 40000 + hf * 20000 + c2;
        const float* xp1 = x + 20480000l + (long)b * 40000 + hf * 20000 + c2;
        #pragma unroll 4
        for (int i = 0; i < 100; ++i) {
          float w2 = sb[hf * 100 + i];
          a1 += xp0[i * 200] * w2;
          a2 += xp1[i * 200] * w2;
        }
      }
      a1 += DPPF(a1, 0xB1, 0.f);   // combine halves (lanes 2c, 2c+1)
      a2 += DPPF(a2, 0xB1, 0.f);
      if (hf == 0 && c2 < 200) {
        float w = sb[c2];
        a1 *= w; a2 *= w;
      } else {
        a1 = 0.f; a2 = 0.f;
      }
      a1 = wave_sum(a1);
      a2 = wave_sum(a2);
      if (lane == 0) { redc[wave * 2] = a1; redc[wave * 2 + 1] = a2; }
      __syncthreads();
      if (t == 0) {
        float f1 = ((redc[0] + redc[2]) + (redc[4] + redc[6])) +
                   ((redc[8] + redc[10]) + (redc[12] + redc[14]));
        float f2 = ((redc[1] + redc[3]) + (redc[5] + redc[7])) +
                   ((redc[9] + redc[11]) + (redc[13] + redc[15]));
        out[b]        = -(f1 * rf[0] + f2 * rf[1]);
        out[512 + b]  = f1;
        out[1024 + b] = f2;
      }
    }
    __syncthreads();   // protect LDS reuse before next grab
  }
}

// ---------------- decode (round-12 fallback, unchanged) ----------------
__global__ __attribute__((amdgpu_flat_work_group_size(1024, 1024)))
void decode(const float* __restrict__ OUT, const float* __restrict__ QI,
            int* __restrict__ ctr, float* __restrict__ sol,
            float* __restrict__ out) {
  __shared__ __align__(16) float k1r[25600];
  __shared__ __align__(16) float at[1600];
  __shared__ __align__(16) float mhal[128];
  __shared__ float lg[200];
  __shared__ __align__(16) float qv[128];
  __shared__ __align__(16) float ul[12800];
  __shared__ int   bci;
  __shared__ int   bsel;

  const int t = threadIdx.x;
  const int lane = t & 63, wave = t >> 6;
  const int o = t >> 3, q8 = t & 7;
  const int m4 = t >> 2, j4 = t & 3;
  const int stq = (q8 * 25) & ~3;
  const int cq  = ((((q8 + 1) * 25) & ~3) - stq) >> 2;

  for (;;) {
    if (t == 0) bsel = atomicAdd(ctr, 1);
    __syncthreads();
    const int b = bsel;
    if (b >= 512) break;
    const float* outb = OUT + (long)b * 200 * 512;

    for (int p = 0; p < 25; ++p) {
      int f = p * 1024 + t;
      int n = f >> 7, d = f & 127;
      k1r[n * 128 + ((d + 4 * n) & 127)] = outb[n * 512 + d];
    }
    for (int f = t; f < 12800; f += 1024) {
      int m = f >> 6, c = f & 63;
      ul[m * 64 + ((c + 4 * m) & 63)] =
          outb[m * 512 + 256 + (c >> 4) * 32 + 16 + (c & 15)];
    }
    f32x4 vA = {}, vB = {}, vC = {}, vD = {}, vE = {}, vF = {}, vG = {};
    {
      const float* vp = outb + 128 + o;
      #pragma unroll
      for (int e = 0; e < 4; ++e) vA[e] = vp[(stq + 0 + e) * 512];
      #pragma unroll
      for (int e = 0; e < 4; ++e) vB[e] = vp[(stq + 4 + e) * 512];
      #pragma unroll
      for (int e = 0; e < 4; ++e) vC[e] = vp[(stq + 8 + e) * 512];
      #pragma unroll
      for (int e = 0; e < 4; ++e) vD[e] = vp[(stq + 12 + e) * 512];
      #pragma unroll
      for (int e = 0; e < 4; ++e) vE[e] = vp[(stq + 16 + e) * 512];
      #pragma unroll
      for (int e = 0; e < 4; ++e) vF[e] = vp[(stq + 20 + e) * 512];
      if (cq == 7) {
        #pragma unroll
        for (int e = 0; e < 4; ++e) vG[e] = vp[(stq + 24 + e) * 512];
      }
    }
    f32x4 urR0 = {}, urR1 = {}, urR2 = {}, urR3 = {};
    if (t < 800) {
      const float* up = outb + m4 * 512 + 256 + j4 * 32;
      urR0 = *(const f32x4*)(up + 4 * ((0 + j4) & 3));
      urR1 = *(const f32x4*)(up + 4 * ((1 + j4) & 3));
      urR2 = *(const f32x4*)(up + 4 * ((2 + j4) & 3));
      urR3 = *(const f32x4*)(up + 4 * ((3 + j4) & 3));
    }
    if (t < 128) qv[t] = QI[b * 128 + t];

    int mk = 0;
    bool cm = false;
    bool live = true, picked0 = false;
    float llsum = 0.f, chose = 0.f;

    __syncthreads();

    for (int st = 0; st < 200; ++st) {
      if (wave < 8) {
        const int hb = wave * 16;
        float acc[4] = {};
        #pragma unroll
        for (int hf = 0; hf < 2; ++hf) {
          f32x4 qa = *(const f32x4*)&qv[hb + hf * 8];
          f32x4 qb2 = *(const f32x4*)&qv[hb + hf * 8 + 4];
          #pragma unroll
          for (int k = 0; k < 4; ++k) {
            int n = lane + 64 * k;
            if (n < 200) {
              const float* kb = k1r + n * 128;
              int off  = (hb + hf * 8 + 4 * n) & 127;
              int off2 = (hb + hf * 8 + 4 + 4 * n) & 127;
              f32x4 kA = *(const f32x4*)(kb + off);
              f32x4 kB = *(const f32x4*)(kb + off2);
              float ah = qa[0] * kA[0];
              ah += qa[1] * kA[1]; ah += qa[2] * kA[2]; ah += qa[3] * kA[3];
              ah += qb2[0] * kB[0]; ah += qb2[1] * kB[1];
              ah += qb2[2] * kB[2]; ah += qb2[3] * kB[3];
              acc[k] += ah;
            }
          }
        }
        float sv[4];
        float mx = -INFINITY;
        #pragma unroll
        for (int k = 0; k < 4; ++k) {
          int n = lane + 64 * k;
          float s = -INFINITY;
          if (n < 200) {
            s = acc[k] * 0.25f;
            if (mk & (1 << k)) s = NEGV;
          }
          sv[k] = s;
          mx = fmaxf(mx, s);
        }
        float vmax = wave_max(mx);
        float ls = 0.f;
        #pragma unroll
        for (int k = 0; k < 4; ++k) { sv[k] = expf(sv[k] - vmax); ls += sv[k]; }
        ls = wave_sum(ls);
        #pragma unroll
        for (int k = 0; k < 4; ++k) {
          int n = lane + 64 * k;
          if (n < 200) at[wave * 200 + n] = sv[k] / ls;
        }
      }
      __syncthreads();

      {
        const int h2 = t >> 7;
        const float* ap = at + h2 * 200 + stq;
        float a = 0.f;
        f32x4 av;
        av = *(const f32x4*)(ap + 0);
        a += av[0]*vA[0]; a += av[1]*vA[1]; a += av[2]*vA[2]; a += av[3]*vA[3];
        av = *(const f32x4*)(ap + 4);
        a += av[0]*vB[0]; a += av[1]*vB[1]; a += av[2]*vB[2]; a += av[3]*vB[3];
        av = *(const f32x4*)(ap + 8);
        a += av[0]*vC[0]; a += av[1]*vC[1]; a += av[2]*vC[2]; a += av[3]*vC[3];
        av = *(const f32x4*)(ap + 12);
        a += av[0]*vD[0]; a += av[1]*vD[1]; a += av[2]*vD[2]; a += av[3]*vD[3];
        av = *(const f32x4*)(ap + 16);
        a += av[0]*vE[0]; a += av[1]*vE[1]; a += av[2]*vE[2]; a += av[3]*vE[3];
        av = *(const f32x4*)(ap + 20);
        a += av[0]*vF[0]; a += av[1]*vF[1]; a += av[2]*vF[2]; a += av[3]*vF[3];
        if (cq == 7) {
          av = *(const f32x4*)(ap + 24);
          a += av[0]*vG[0]; a += av[1]*vG[1]; a += av[2]*vG[2]; a += av[3]*vG[3];
        }
        a += DPPF(a, 0xB1, 0.f);
        a += DPPF(a, 0x4E, 0.f);
        a += DPPF(a, 0x141, 0.f);
        if (q8 == 0) mhal[o] = a;
      }
      __syncthreads();

      if (t < 800) {
        float a = 0.f;
        {
          f32x4 ml;
          ml = *(const f32x4*)&mhal[j4 * 32 + ((0 + j4) & 3) * 4];
          a += ml[0]*urR0[0]; a += ml[1]*urR0[1]; a += ml[2]*urR0[2]; a += ml[3]*urR0[3];
          ml = *(const f32x4*)&mhal[j4 * 32 + ((1 + j4) & 3) * 4];
          a += ml[0]*urR1[0]; a += ml[1]*urR1[1]; a += ml[2]*urR1[2]; a += ml[3]*urR1[3];
          ml = *(const f32x4*)&mhal[j4 * 32 + ((2 + j4) & 3) * 4];
          a += ml[0]*urR2[0]; a += ml[1]*urR2[1]; a += ml[2]*urR2[2]; a += ml[3]*urR2[3];
          ml = *(const f32x4*)&mhal[j4 * 32 + ((3 + j4) & 3) * 4];
          a += ml[0]*urR3[0]; a += ml[1]*urR3[1]; a += ml[2]*urR3[2]; a += ml[3]*urR3[3];
        }
        const int ubase = m4 * 64;
        #pragma unroll
        for (int c = 0; c < 4; ++c) {
          int ci = (c + j4) & 3;
          f32x4 mh = *(const f32x4*)&mhal[j4 * 32 + 16 + ci * 4];
          f32x4 uu = *(const f32x4*)&ul[ubase + ((j4 * 16 + ci * 4 + 4 * m4) & 63)];
          a += mh[0]*uu[0]; a += mh[1]*uu[1]; a += mh[2]*uu[2]; a += mh[3]*uu[3];
        }
        a += DPPF(a, 0xB1, 0.f);
        a += DPPF(a, 0x4E, 0.f);
        if (j4 == 0) {
          float l = 10.f * tanhf(a / 11.313708498984761f);
          lg[m4] = cm ? NEGV : l;
        }
      }
      __syncthreads();

      if (wave < 8) {
        float lv[4];
        float mx = -INFINITY;
        #pragma unroll
        for (int k = 0; k < 4; ++k) {
          int n = lane + 64 * k;
          lv[k] = (n < 200) ? lg[n] : -INFINITY;
          mx = fmaxf(mx, lv[k]);
        }
        float vmax = wave_max(mx);
        int bidx = -1;
        #pragma unroll
        for (int k = 0; k < 4; ++k) {
          unsigned long long bm =
              __ballot((lane + 64 * k < 200) && (lv[k] == vmax));
          if (bidx < 0 && bm != 0ull) bidx = k * 64 + (int)__builtin_ctzll(bm);
        }
        int nxt = live ? bidx : 0;
        if (t < 128) qv[t] = outb[(long)nxt * 512 + 384 + t];
        float e = 0.f;
        #pragma unroll
        for (int k = 0; k < 4; ++k) e += expf(lv[k] - vmax);
        float se_ = wave_sum(e);
        float lse = logf(se_);
        if (t == 0) {
          chose = live ? (-lse) : ((lv[0] - vmax) - lse);
          out[2048 + (long)b * 200 + st] = (float)nxt;
          bci = nxt;
        }
      }
      __syncthreads();

      int nxt = bci;
      if (!live) {
        if (t == 0) llsum += chose * (float)(200 - st);
        for (int s2 = st + 1 + t; s2 < 200; s2 += 1024)
          out[2048 + (long)b * 200 + s2] = 0.f;
        break;
      }
      if (t == 0) llsum += chose;
      if (wave < 8 && (nxt & 63) == lane) mk |= 1 << (nxt >> 6);
      if (t < 800 && nxt == m4) cm = true;
      if (nxt == 0) { live = false; picked0 = true; }
    }

    if (t == 0) out[1536 + b] = picked0 ? llsum : 0.f;
    if (t < 800 && j4 == 0) {
      float s = (m4 == 0) ? 1.f : ((picked0 && cm) ? 1.f : 0.f);
      sol[(long)b * 200 + m4] = s;
    }
    __syncthreads();
  }
}

// ---------------- cost (fallback path only) ----------------
__global__ __launch_bounds__(256)
void cost_kernel(const float* __restrict__ x, const float* __restrict__ rf,
                 const float* __restrict__ sol, float* __restrict__ out) {
  __shared__ float solL[256];
  __shared__ float red[8];
  const int b = blockIdx.x, t = threadIdx.x;
  solL[t] = (t < 200) ? sol[b * 200 + t] : 0.f;
  __syncthreads();
  const float* x0 = x + (long)b * 40000;
  const float* x1 = x + 20480000l + (long)b * 40000;
  float a1 = 0.f, a2 = 0.f;
  if (t < 200) {
    #pragma unroll 4
    for (int i = 0; i < 200; ++i) {
      float w2 = solL[i];
      a1 += x0[i * 200 + t] * w2;
      a2 += x1[i * 200 + t] * w2;
    }
    float w = solL[t];
    a1 *= w; a2 *= w;
  }
  #pragma unroll
  for (int off = 32; off > 0; off >>= 1) {
    a1 += __shfl_xor(a1, off);
    a2 += __shfl_xor(a2, off);
  }
  if ((t & 63) == 0) { red[(t >> 6) * 2] = a1; red[(t >> 6) * 2 + 1] = a2; }
  __syncthreads();
  if (t == 0) {
    float f1 = red[0] + red[2] + red[4] + red[6];
    float f2 = red[1] + red[3] + red[5] + red[7];
    out[b]        = -(f1 * rf[0] + f2 * rf[1]);
    out[512 + b]  = f1;
    out[1024 + b] = f2;
  }
}

extern "C" void kernel_launch(void* const* d_in, const int* in_sizes, int n_in,
                              void* d_out, int out_size, void* d_ws, size_t ws_size,
                              hipStream_t stream) {
  const float* x     = (const float*)d_in[0];
  const float* rf    = (const float*)d_in[1];
  const float* emb   = (const float*)d_in[2];
  const float* Wk1   = (const float*)d_in[4];
  const float* bk1   = (const float*)d_in[5];
  const float* Wv    = (const float*)d_in[6];
  const float* Wk2   = (const float*)d_in[7];
  const float* Wout  = (const float*)d_in[8];
  const float* Wq    = (const float*)d_in[9];
  const float* initn = (const float*)d_in[10];
  float* out = (float*)d_out;
  float* ws  = (float*)d_ws;

  if (ws_size < (size_t)WS_FLOATS * 4) return;

  float* OUTb = ws + OUT_F;
  float* Mb   = ws + M_F;
  float* QRb  = ws + QR_F;   // dead after gemm; first 4 bytes reused as counter
  float* QIb  = ws + QI_F;
  float* solb = ws + SOL_F;
  int*   ctrb = (int*)(ws + QR_F);   // counter aliases QR (QR consumed by gemm)

  // NOTE: ctr aliases QR[0]. build_Q writes QR (including elem 0) and gemm
  // reads it, so init the counter in a tiny kernel AFTER gemm instead when
  // aliased. Use a dedicated slot at end of SOL region to avoid aliasing:
  ctrb = (int*)(ws + SOL_F + 102400l - 4l);  // last float of ws (unused by sol[512][200]? sol uses full region)
  // sol occupies SOL_F..SOL_F+102400. Use M region instead (dead after gemm):
  ctrb = (int*)(ws + M_F);   // M dead after gemm_static

  build_M<<<256, 256, 0, stream>>>(Wk1, Wv, Wk2, Wout, Wq, Mb);
  build_Q<<<256, 256, 0, stream>>>(rf, Wq, initn, QRb, QIb, (int*)(ws + QI_F + 65536l - 4l));
  gemm_static<<<12800, 256, 0, stream>>>(emb, Mb, bk1, QRb, OUTb);
  init_ctr<<<1, 1, 0, stream>>>(ctrb);

  hipFuncAttributes fa;
  bool big = false;
  if (hipFuncGetAttributes(&fa, (const void*)decode512) == hipSuccess)
    big = (fa.localSizeBytes <= 64);
  if (big) {
    decode512<<<256, 512, 0, stream>>>(OUTb, QIb, x, rf, ctrb, out);
  } else {
    decode<<<256, 1024, 0, stream>>>(OUTb, QIb, ctrb, solb, out);
    cost_kernel<<<512, 256, 0, stream>>>(x, rf, solb, out);
  }
}